// Round 15
// baseline (551.441 us; speedup 1.0000x reference)
//
#include <hip/hip_runtime.h>

// ---------------------------------------------------------------------------
// Conformer block, MI355X gfx950. Inputs/outputs fp32; internal activations
// bf16 with fp32 accumulation via bf16 MFMA 16x16x32.
// Round 15: conv 4-way tap split (taps 8/8/8/7+pad) -> grid 1024 = 4
// blocks/CU (was 2; occupancy was the binding constraint at 21.5%).
// Slab 136 rows x 32 i-ch staged once per i-chunk; 8 taps run against it.
// B weight-direct in regs. reduce_bn sums 4 partials. Rest = round 14.
// ---------------------------------------------------------------------------

typedef __attribute__((ext_vector_type(4))) float f32x4;
typedef __attribute__((ext_vector_type(8))) short short8;
typedef __attribute__((ext_vector_type(4))) short s16x4;

__device__ __forceinline__ float bfs2f(short s) {
  unsigned u = ((unsigned)(unsigned short)s) << 16;
  float f; __builtin_memcpy(&f, &u, 4); return f;
}
__device__ __forceinline__ short f2bfs(float f) {
  unsigned u; __builtin_memcpy(&u, &f, 4);
  u = (u + 0x7FFFu + ((u >> 16) & 1u)) >> 16;   // RNE
  return (short)u;
}
__device__ __forceinline__ float sigmoidf_(float x) { return 1.f / (1.f + __expf(-x)); }

#define GLOADLDS(gsrc, ldst) \
  __builtin_amdgcn_global_load_lds((__attribute__((address_space(1))) void*)(gsrc), \
                                   (__attribute__((address_space(3))) void*)(ldst), 16, 0, 0)

#define VMCNT_ASM(n) asm volatile("s_waitcnt vmcnt(" #n ")" ::: "memory")
template<int N> __device__ __forceinline__ void vmcnt_wait() {
  if      constexpr (N == 0)  VMCNT_ASM(0);
  else if constexpr (N == 2)  VMCNT_ASM(2);
  else if constexpr (N == 3)  VMCNT_ASM(3);
  else if constexpr (N == 4)  VMCNT_ASM(4);
  else if constexpr (N == 6)  VMCNT_ASM(6);
  else if constexpr (N == 8)  VMCNT_ASM(8);
  else                        VMCNT_ASM(0);
}
#define MEMFENCE asm volatile("" ::: "memory")

enum { EPI_SILU = 0, EPI_F32BIAS = 1, EPI_RES = 2, EPI_QKV = 3, EPI_F32 = 6 };

// ---------------------------------------------------------------------------
// Generic GEMM: C[M,N] = A[M,K] * BT[N,K]^T, bf16 in, fp32 accum. BK=32.
// Triple-buffered; counted vmcnt(L) + RAW s_barrier. Last-z K decrement.
// ---------------------------------------------------------------------------
template<int BM, int BN, int WM, int WN, int EPI>
__global__ __launch_bounds__(256) void gemm_bt(
    const short* __restrict__ A, int lda, long zAh, long zAl,
    const short* __restrict__ BT, int ldbt, long zBh, long zBl,
    int K, int Kdec,
    void* C, int ldc, long zCh, long zCl, int zdiv,
    const float* bias, const float* bias2, const float* bias3,
    const float* resid, float alpha, float beta)
{
  constexpr int FM = BM / (WM * 16), FN = BN / (WN * 16);
  constexpr int AIT = (BM * 4) / 256, BIT = (BN * 4) / 256;
  constexpr int L = AIT + BIT;
  __shared__ short sA[3][BM * 32];
  __shared__ short sB[3][BN * 32];
  const int tid = threadIdx.x;
  const int zmask = (1 << zdiv) - 1;
  const int zhi = (int)(blockIdx.z >> zdiv);
  const int zlo = (int)(blockIdx.z & zmask);
  A  += (long)zhi * zAh + (long)zlo * zAl;
  BT += (long)zhi * zBh + (long)zlo * zBl;
  char* cbase = (char*)C + (long)zhi * zCh + (long)zlo * zCl;
  const int m0 = blockIdx.x * BM, n0 = blockIdx.y * BN;
  const int Keff = K - (zlo == zmask ? Kdec : 0);

  auto stage = [&](int buf, int k0) {
#pragma unroll
    for (int it = 0; it < AIT; ++it) {
      int idx = it * 256 + tid;
      GLOADLDS(A + (long)(m0 + (idx >> 2)) * lda + k0 + (idx & 3) * 8, &sA[buf][idx * 8]);
    }
#pragma unroll
    for (int it = 0; it < BIT; ++it) {
      int idx = it * 256 + tid;
      GLOADLDS(BT + (long)(n0 + (idx >> 2)) * ldbt + k0 + (idx & 3) * 8, &sB[buf][idx * 8]);
    }
  };

  f32x4 acc[FM][FN];
#pragma unroll
  for (int i = 0; i < FM; ++i) {
#pragma unroll
    for (int j = 0; j < FN; ++j) acc[i][j] = (f32x4){0.f, 0.f, 0.f, 0.f};
  }
  const int lane = tid & 63, wid = tid >> 6;
  const int wm = wid / WN, wn = wid % WN;
  const int lr = lane & 15, kg = lane >> 4;
  const int aRow = wm * (BM / WM), bRow = wn * (BN / WN);

  const int nt = Keff >> 5;
  stage(0, 0);
  stage(1, 32);
  vmcnt_wait<L>();
  __builtin_amdgcn_s_barrier();

  int cur = 0, sbuf = 2;
  for (int t = 0; t < nt; ++t) {
    const bool st = (t + 2 < nt);
    if (st) stage(sbuf, (t + 2) * 32);
    short8 af[FM], bfr[FN];
#pragma unroll
    for (int mi = 0; mi < FM; ++mi)
      af[mi] = *(const short8*)&sA[cur][(aRow + mi * 16 + lr) * 32 + kg * 8];
#pragma unroll
    for (int ni = 0; ni < FN; ++ni)
      bfr[ni] = *(const short8*)&sB[cur][(bRow + ni * 16 + lr) * 32 + kg * 8];
#pragma unroll
    for (int mi = 0; mi < FM; ++mi) {
#pragma unroll
      for (int ni = 0; ni < FN; ++ni)
        acc[mi][ni] = __builtin_amdgcn_mfma_f32_16x16x32_bf16(af[mi], bfr[ni], acc[mi][ni], 0, 0, 0);
    }
    if (st) vmcnt_wait<L>(); else vmcnt_wait<0>();
    __builtin_amdgcn_s_barrier();
    cur = (cur == 2) ? 0 : cur + 1;
    sbuf = (sbuf == 2) ? 0 : sbuf + 1;
  }

  const int baseRow = m0 + aRow, baseCol = n0 + bRow;
#pragma unroll
  for (int mi = 0; mi < FM; ++mi) {
#pragma unroll
    for (int ni = 0; ni < FN; ++ni) {
      const int col = baseCol + ni * 16 + lr;
#pragma unroll
      for (int r = 0; r < 4; ++r) {
        const int row = baseRow + mi * 16 + kg * 4 + r;
        float v = acc[mi][ni][r];
        if (EPI == EPI_SILU) {
          v += bias[col];
          v = v * sigmoidf_(v);
          ((short*)cbase)[(long)row * ldc + col] = f2bfs(v);
        } else if (EPI == EPI_F32BIAS) {
          v += bias[col];
          ((float*)cbase)[(long)row * ldc + col] = v;
        } else if (EPI == EPI_RES) {
          v += bias[col];
          float rv = resid[(long)row * ldc + col];
          ((float*)cbase)[(long)row * ldc + col] = alpha * rv + beta * v;
        } else if (EPI == EPI_QKV) {
          if (col < 512)       v = (v + bias[col]) * 0.125f;   // fold 1/sqrt(64) into q
          else if (col < 1024) v += bias2[col - 512];
          else                 v += bias3[col - 1024];
          ((short*)cbase)[(long)row * ldc + col] = f2bfs(v);
        } else if (EPI == EPI_F32) {
          ((float*)cbase)[(long)row * ldc + col] = v;
        }
      }
    }
  }
}

// ---------------------------------------------------------------------------
// Conv, tap-tiled 4-way: kg in 0..3 owns taps [8kg, 8kg+8) (tap 31 zeroed).
// Per i-chunk (32 ch), stage 136-row glu slab once, run 8 taps against it.
// B weight-direct (fragment-packed wdP), ping-pong reg prefetch, unrolled.
// Flat grid 1024, XCD-pinned: cc = bid&15 -> (y,kg); bid>>4 -> (x,b);
// XCD = bid&7 serves combos {r, r+8} -> 2MB B working set, L2-resident.
// ---------------------------------------------------------------------------
__global__ __launch_bounds__(256) void conv_tap(
    const short* __restrict__ glu,    // glu_pad base (b stride 1056*512)
    const short* __restrict__ wdP,    // [(e>>4)*512 + chunk][512]
    float* __restrict__ parts)
{
  __shared__ short sA[2][136 * 32];
  const int tid = threadIdx.x;
  const int bid = blockIdx.x;
  const int cc = bid & 15, j = bid >> 4;
  const int y = cc >> 2, kg = cc & 3;
  const int x = j & 7, b = j >> 3;
  const int m0 = x * 128, n0 = y * 128;
  const short* Arow0 = glu + ((long)b * 1056 + m0 + 1 + kg * 8) * 512;
  float* cbase = parts + (long)kg * (8192L * 512) + (long)b * (1024L * 512);

  const int lane = tid & 63, wid = tid >> 6;
  const int wm = wid >> 1, wn = wid & 1;
  const int lr = lane & 15, kgr = lane >> 4;
  const int aRow = wm * 64, bRow = wn * 64;

  const short* Bp = wdP + (long)((n0 + bRow) >> 4) * (512L * 512)
                  + (long)(kg * 128) * 512 + lane * 8;
  const long NSTR = 512L * 512;   // per-16e-rowtile stride

  auto stageA = [&](int buf, int ib) {
#pragma unroll
    for (int it = 0; it < 3; ++it) {
      int idx = it * 256 + tid;
      if (idx < 544) {
        GLOADLDS(Arow0 + (long)(idx >> 2) * 512 + ib * 32 + (idx & 3) * 8,
                 &sA[buf][idx * 8]);
      }
    }
  };

  f32x4 acc[4][4];
#pragma unroll
  for (int i = 0; i < 4; ++i) {
#pragma unroll
    for (int jj = 0; jj < 4; ++jj) acc[i][jj] = (f32x4){0.f, 0.f, 0.f, 0.f};
  }
  short8 b0[4], b1[4];

  stageA(0, 0);
  MEMFENCE;
#pragma unroll
  for (int ni = 0; ni < 4; ++ni)
    b0[ni] = *(const short8*)(Bp + ni * NSTR);
  MEMFENCE;
  vmcnt_wait<4>();              // stage(0) done; b0 may be in flight
  __builtin_amdgcn_s_barrier();

  int cur = 0;
  for (int ib = 0; ib < 16; ++ib) {
    if (ib + 1 < 16) stageA(cur ^ 1, ib + 1);
    MEMFENCE;
#pragma unroll
    for (int kk = 0; kk < 8; ++kk) {
      // prefetch next frag: (kk+1, ib) or (0, ib+1)
      const long noff = (kk + 1 < 8) ? (long)((kk + 1) * 16 + ib) * 512
                                     : (long)(ib + 1) * 512;
      if ((kk & 1) == 0) {
#pragma unroll
        for (int ni = 0; ni < 4; ++ni)
          b1[ni] = *(const short8*)(Bp + noff + ni * NSTR);
      } else {
#pragma unroll
        for (int ni = 0; ni < 4; ++ni)
          b0[ni] = *(const short8*)(Bp + noff + ni * NSTR);
      }
      short8 af[4];
#pragma unroll
      for (int mi = 0; mi < 4; ++mi)
        af[mi] = *(const short8*)&sA[cur][(kk + aRow + mi * 16 + lr) * 32 + kgr * 8];
      if ((kk & 1) == 0) {
#pragma unroll
        for (int mi = 0; mi < 4; ++mi) {
#pragma unroll
          for (int ni = 0; ni < 4; ++ni)
            acc[mi][ni] = __builtin_amdgcn_mfma_f32_16x16x32_bf16(af[mi], b0[ni], acc[mi][ni], 0, 0, 0);
        }
      } else {
#pragma unroll
        for (int mi = 0; mi < 4; ++mi) {
#pragma unroll
          for (int ni = 0; ni < 4; ++ni)
            acc[mi][ni] = __builtin_amdgcn_mfma_f32_16x16x32_bf16(af[mi], b1[ni], acc[mi][ni], 0, 0, 0);
        }
      }
    }
    vmcnt_wait<4>();            // only newest 4 (unconsumed B prefetch) in flight
    __builtin_amdgcn_s_barrier();
    cur ^= 1;
  }
  vmcnt_wait<0>();

  const int baseRow = m0 + aRow, baseCol = n0 + bRow;
#pragma unroll
  for (int mi = 0; mi < 4; ++mi) {
#pragma unroll
    for (int ni = 0; ni < 4; ++ni) {
      const int col = baseCol + ni * 16 + lr;
#pragma unroll
      for (int r = 0; r < 4; ++r) {
        const int row = baseRow + mi * 16 + kgr * 4 + r;
        cbase[(long)row * 512 + col] = acc[mi][ni][r];
      }
    }
  }
}

// ---------------------------------------------------------------------------
// Flash attention (round 10). Block = 64 q-rows of one (b,h); 4 waves.
// ---------------------------------------------------------------------------
__global__ __launch_bounds__(256) void flash_attn(
    const short* __restrict__ qkv,   // [b][t][1536], q pre-scaled by 1/8
    const short* __restrict__ vt,    // [(b*8+h)][e=64][t=1024]
    short* __restrict__ out)         // scrambled: [b][n>>3][(n&7)*64+e]
{
  __shared__ short sQ[64 * 64];
  __shared__ short sK[64 * 64];
  __shared__ short sV[64 * 64];
  __shared__ short sP[4][16 * 64];
  const int tid = threadIdx.x;
  const int lane = tid & 63, w = tid >> 6;
  const int lr = lane & 15, kg = lane >> 4;
  const int bh = (int)blockIdx.z;
  const int b = bh >> 3, h = bh & 7;
  const int q0 = blockIdx.x * 64;
  const short* qbase = qkv + (long)b * 1024 * 1536 + h * 64;
  const short* kbase = qbase + 512;
  const short* vtb = vt + (long)bh * 65536;

#pragma unroll
  for (int it = 0; it < 2; ++it) {
    int idx = it * 256 + tid;
    int row = idx >> 3, c = (idx & 7) ^ (row & 7);
    GLOADLDS(qbase + (long)(q0 + row) * 1536 + c * 8, &sQ[idx * 8]);
  }
  __syncthreads();
  short8 bq[2];
#pragma unroll
  for (int ks = 0; ks < 2; ++ks)
    bq[ks] = *(const short8*)&sQ[(w * 16 + lr) * 64 + ((ks * 4 + kg) ^ (lr & 7)) * 8];

  f32x4 po[4];
#pragma unroll
  for (int mi = 0; mi < 4; ++mi) po[mi] = (f32x4){0.f, 0.f, 0.f, 0.f};
  float m = -3.0e38f, l = 0.f;

  for (int s0 = 0; s0 < 1024; s0 += 64) {
#pragma unroll
    for (int it = 0; it < 2; ++it) {
      int idx = it * 256 + tid;
      int row = idx >> 3, c = (idx & 7) ^ (row & 7);
      GLOADLDS(kbase + (long)(s0 + row) * 1536 + c * 8, &sK[idx * 8]);
    }
#pragma unroll
    for (int it = 0; it < 2; ++it) {
      int idx = it * 256 + tid;
      int row = idx >> 3, c = (idx & 7) ^ (row & 7);
      GLOADLDS(vtb + (long)row * 1024 + s0 + c * 8, &sV[idx * 8]);
    }
    __syncthreads();

    f32x4 as[4];
#pragma unroll
    for (int mi = 0; mi < 4; ++mi) as[mi] = (f32x4){0.f, 0.f, 0.f, 0.f};
#pragma unroll
    for (int ks = 0; ks < 2; ++ks) {
#pragma unroll
      for (int mi = 0; mi < 4; ++mi) {
        short8 ak = *(const short8*)&sK[(mi * 16 + lr) * 64 + ((ks * 4 + kg) ^ (lr & 7)) * 8];
        as[mi] = __builtin_amdgcn_mfma_f32_16x16x32_bf16(ak, bq[ks], as[mi], 0, 0, 0);
      }
    }

    float rmax = as[0][0];
#pragma unroll
    for (int mi = 0; mi < 4; ++mi) {
#pragma unroll
      for (int r = 0; r < 4; ++r) rmax = fmaxf(rmax, as[mi][r]);
    }
    rmax = fmaxf(rmax, __shfl_xor(rmax, 16));
    rmax = fmaxf(rmax, __shfl_xor(rmax, 32));
    const float mn = fmaxf(m, rmax);
    const float sc = __expf(m - mn);
    float p[4][4];
    float rsum = 0.f;
#pragma unroll
    for (int mi = 0; mi < 4; ++mi) {
#pragma unroll
      for (int r = 0; r < 4; ++r) { p[mi][r] = __expf(as[mi][r] - mn); rsum += p[mi][r]; }
    }
    rsum += __shfl_xor(rsum, 16);
    rsum += __shfl_xor(rsum, 32);
    l = l * sc + rsum;
    m = mn;
#pragma unroll
    for (int mi = 0; mi < 4; ++mi) {
#pragma unroll
      for (int r = 0; r < 4; ++r) po[mi][r] *= sc;
    }
#pragma unroll
    for (int mi = 0; mi < 4; ++mi) {
      s16x4 pk;
#pragma unroll
      for (int r = 0; r < 4; ++r) pk[r] = f2bfs(p[mi][r]);
      *(s16x4*)&sP[w][lr * 64 + ((mi ^ (lr & 3)) * 16 + kg * 4)] = pk;
    }
#pragma unroll
    for (int ks = 0; ks < 2; ++ks) {
      short8 bp = *(const short8*)&sP[w][lr * 64 + (((ks * 2 + (kg >> 1)) ^ (lr & 3)) * 16 + (kg & 1) * 8)];
#pragma unroll
      for (int mi = 0; mi < 4; ++mi) {
        short8 av = *(const short8*)&sV[(mi * 16 + lr) * 64 + ((ks * 4 + kg) ^ (lr & 7)) * 8];
        po[mi] = __builtin_amdgcn_mfma_f32_16x16x32_bf16(av, bp, po[mi], 0, 0, 0);
      }
    }
    __syncthreads();
  }

  const float inv = 1.f / l;
  const int t2 = q0 + w * 16 + lr;
  const int n = h * 1024 + t2;
  short* ob = out + ((long)b * 1024 + (n >> 3)) * 512 + (n & 7) * 64;
#pragma unroll
  for (int mi = 0; mi < 4; ++mi) {
    s16x4 o;
#pragma unroll
    for (int r = 0; r < 4; ++r) o[r] = f2bfs(po[mi][r] * inv);
    *(s16x4*)&ob[mi * 16 + kg * 4] = o;
  }
}

// ---------------------------------------------------------------------------
// Sum FOUR conv split-K partials -> z bf16, accumulate BN sum/sumsq stats.
// ---------------------------------------------------------------------------
__global__ __launch_bounds__(256) void reduce_bn(
    const float* __restrict__ parts, long pstride,
    short* __restrict__ z, float* stats)
{
  const int r0 = blockIdx.x * 16;
  const int c = threadIdx.x * 2;
  float s0 = 0.f, s1 = 0.f, q0 = 0.f, q1 = 0.f;
#pragma unroll 4
  for (int r = 0; r < 16; ++r) {
    const long idx = (long)(r0 + r) * 512 + c;
    float a0 = parts[idx] + parts[idx + pstride] + parts[idx + 2 * pstride] + parts[idx + 3 * pstride];
    float a1 = parts[idx + 1] + parts[idx + 1 + pstride] + parts[idx + 1 + 2 * pstride] + parts[idx + 1 + 3 * pstride];
    z[idx] = f2bfs(a0); z[idx + 1] = f2bfs(a1);
    s0 += a0; s1 += a1; q0 += a0 * a0; q1 += a1 * a1;
  }
  atomicAdd(&stats[c], s0);
  atomicAdd(&stats[c + 1], s1);
  atomicAdd(&stats[512 + c], q0);
  atomicAdd(&stats[512 + c + 1], q1);
}

// ---------------------------------------------------------------------------
// LayerNorm rows of 512 (fp32 in), one wave per row (4 rows/block).
// ---------------------------------------------------------------------------
template<int ADDPE, int OUTF32>
__global__ __launch_bounds__(256) void ln_rows(
    const float* __restrict__ X, const float* __restrict__ g, const float* __restrict__ b,
    const float* __restrict__ pe, void* __restrict__ Y)
{
  const int row = blockIdx.x * 4 + (threadIdx.x >> 6);
  const int lane = threadIdx.x & 63;
  const int c0 = lane * 8;
  const float* src = X + (long)row * 512 + c0;
  f32x4 a = *(const f32x4*)src, c = *(const f32x4*)(src + 4);
  float x[8] = {a[0], a[1], a[2], a[3], c[0], c[1], c[2], c[3]};
  float s = 0.f, q = 0.f;
#pragma unroll
  for (int j = 0; j < 8; ++j) { s += x[j]; q += x[j] * x[j]; }
#pragma unroll
  for (int off = 32; off > 0; off >>= 1) { s += __shfl_xor(s, off); q += __shfl_xor(q, off); }
  const float mean = s * (1.f / 512.f);
  const float var = q * (1.f / 512.f) - mean * mean;
  const float rstd = rsqrtf(var + 1e-5f);
  f32x4 g0 = *(const f32x4*)(g + c0), g1 = *(const f32x4*)(g + c0 + 4);
  f32x4 b0 = *(const f32x4*)(b + c0), b1 = *(const f32x4*)(b + c0 + 4);
  float gg[8] = {g0[0], g0[1], g0[2], g0[3], g1[0], g1[1], g1[2], g1[3]};
  float bb[8] = {b0[0], b0[1], b0[2], b0[3], b1[0], b1[1], b1[2], b1[3]};
  float y[8];
#pragma unroll
  for (int j = 0; j < 8; ++j) {
    y[j] = (x[j] - mean) * rstd * gg[j] + bb[j];
    if (ADDPE) y[j] += pe[(long)(row & 1023) * 512 + c0 + j];
  }
  if (OUTF32) {
    float* dst = (float*)Y + (long)row * 512 + c0;
    *(f32x4*)dst = (f32x4){y[0], y[1], y[2], y[3]};
    *(f32x4*)(dst + 4) = (f32x4){y[4], y[5], y[6], y[7]};
  } else {
    short8 o;
#pragma unroll
    for (int j = 0; j < 8; ++j) o[j] = f2bfs(y[j]);
    *(short8*)((short*)Y + (long)row * 512 + c0) = o;
  }
}

// ---------------------------------------------------------------------------
// 64x64-tile transpose -> bf16 out. INF32: fp32 input (weights) or bf16 input.
// ---------------------------------------------------------------------------
template<int INF32>
__global__ __launch_bounds__(256) void transpose64(
    const void* __restrict__ in_, int ldin, short* __restrict__ out, int ldout,
    int ctiles, int zshift, long zh_in, long zl_in, long z_out)
{
  __shared__ short t[64][72];
  const int z = blockIdx.z;
  const long inoff = (long)(z >> zshift) * zh_in + (long)(z & ((1 << zshift) - 1)) * zl_in;
  const int tr = blockIdx.x / ctiles, tc = blockIdx.x % ctiles;
  short* dst = out + (long)z * z_out + (long)(tc * 64) * ldout + tr * 64;
  const int tid = threadIdx.x;
#pragma unroll
  for (int p = 0; p < 2; ++p) {
    int idx = p * 256 + tid;
    int r = idx >> 3, c8 = (idx & 7) * 8;
    if (INF32) {
      const float* src = (const float*)in_ + inoff + (long)(tr * 64 + r) * ldin + tc * 64 + c8;
      f32x4 v0 = *(const f32x4*)src, v1 = *(const f32x4*)(src + 4);
#pragma unroll
      for (int j = 0; j < 4; ++j) { t[r][c8 + j] = f2bfs(v0[j]); t[r][c8 + 4 + j] = f2bfs(v1[j]); }
    } else {
      const short* src = (const short*)in_ + inoff + (long)(tr * 64 + r) * ldin + tc * 64 + c8;
      short8 v = *(const short8*)src;
#pragma unroll
      for (int j = 0; j < 8; ++j) t[r][c8 + j] = v[j];
    }
  }
  __syncthreads();
#pragma unroll
  for (int p = 0; p < 2; ++p) {
    int idx = p * 256 + tid;
    int c = idx >> 3, r8 = (idx & 7) * 8;
    short8 v;
#pragma unroll
    for (int j = 0; j < 8; ++j) v[j] = t[r8 + j][c];
    *(short8*)(dst + (long)c * ldout + r8) = v;
  }
}

// wdP fragment-packed, 32 taps (tap 31 pre-zeroed): value wd[e][i][KK] ->
// wdP[((e>>4)*512 + KK*16 + (i>>5))*512 + ((i>>3)&3)*128 + (e&15)*8 + (i&7)]
__global__ __launch_bounds__(256) void wd_pack(const float* __restrict__ wd, short* __restrict__ wdP)
{
  const int gid = blockIdx.x * 256 + threadIdx.x;  // 262144 = 512*512
  const int e = gid >> 9, i = gid & 511;
  const float* src = wd + ((long)e * 512 + i) * 31;
  const long rowtile = (long)(e >> 4) * (512L * 512);
  const int inner = ((i >> 3) & 3) * 128 + (e & 15) * 8 + (i & 7);
#pragma unroll
  for (int KK = 0; KK < 31; ++KK)
    wdP[rowtile + (long)(KK * 16 + (i >> 5)) * 512 + inner] = f2bfs(src[KK]);
}

// pe[t][2p] = sin(t * 10000^(-p/256)), pe[t][2p+1] = cos(...)
__global__ __launch_bounds__(256) void pe_init(float* __restrict__ pe)
{
  const int gid = blockIdx.x * 256 + threadIdx.x;  // 262144 = 1024*256
  const int t = gid >> 8, p = gid & 255;
  const float freq = __expf(-(float)p * (9.210340371976184f / 256.f));
  const float ang = (float)t * freq;
  pe[(long)t * 512 + 2 * p]     = sinf(ang);
  pe[(long)t * 512 + 2 * p + 1] = cosf(ang);
}

// glu = a * sigmoid(g) from y1[N][1024] fp32 -> glu_pad[b][16+t][512] bf16
__global__ __launch_bounds__(256) void glu_kernel(const float* __restrict__ y1, short* __restrict__ gp)
{
  const int gid = blockIdx.x * 256 + threadIdx.x;  // 1048576
  const int row = gid >> 7;
  const int ci = (gid & 127) * 4;
  const float* base = y1 + (long)row * 1024;
  f32x4 a = *(const f32x4*)(base + ci);
  f32x4 g = *(const f32x4*)(base + 512 + ci);
  const int b = row >> 10, t = row & 1023;
  s16x4 o;
#pragma unroll
  for (int j = 0; j < 4; ++j) o[j] = f2bfs(a[j] * sigmoidf_(g[j]));
  *(s16x4*)(gp + ((long)b * 1056 + 16 + t) * 512 + ci) = o;
}

__global__ void bn_stats(float* stats, const float* __restrict__ bn_g, const float* __restrict__ bn_b)
{
  const int c = blockIdx.x * 256 + threadIdx.x;
  if (c < 512) {
    float mean = stats[c] * (1.f / 8192.f);
    float var = stats[512 + c] * (1.f / 8192.f) - mean * mean;
    float sc = bn_g[c] * rsqrtf(var + 1e-5f);
    stats[1024 + c] = sc;
    stats[1536 + c] = bn_b[c] - mean * sc;
  }
}

__global__ __launch_bounds__(256) void bn_silu(const short* __restrict__ z, const float* __restrict__ stats,
                                               short* __restrict__ out)
{
  const long base = ((long)blockIdx.x * 256 + threadIdx.x) * 8;
  const int c0 = (int)(base & 511);
  short8 v = *(const short8*)(z + base);
  short8 o;
#pragma unroll
  for (int j = 0; j < 8; ++j) {
    const int c = c0 + j;
    float y = bfs2f(v[j]) * stats[1024 + c] + stats[1536 + c];
    o[j] = f2bfs(y * sigmoidf_(y));
  }
  *(short8*)(out + base) = o;
}

// plain elementwise fp32 -> bf16 cast (grid-stride)
__global__ __launch_bounds__(256) void cast_bf16(const float* __restrict__ in, short* __restrict__ out, long n)
{
  for (long i = (long)blockIdx.x * 256 + threadIdx.x; i < n; i += (long)gridDim.x * 256)
    out[i] = f2bfs(in[i]);
}

// ---------------------------------------------------------------------------
extern "C" void kernel_launch(void* const* d_in, const int* in_sizes, int n_in,
                              void* d_out, int out_size, void* d_ws, size_t ws_size,
                              hipStream_t stream)
{
  (void)in_sizes; (void)n_in; (void)out_size; (void)ws_size;
  const float* x_in   = (const float*)d_in[0];
  const float* ff1_g  = (const float*)d_in[1];
  const float* ff1_bb = (const float*)d_in[2];
  const float* ff1_w1 = (const float*)d_in[3];
  const float* ff1_b1 = (const float*)d_in[4];
  const float* ff1_w2 = (const float*)d_in[5];
  const float* ff1_b2 = (const float*)d_in[6];
  const float* mha_g  = (const float*)d_in[7];
  const float* mha_b  = (const float*)d_in[8];
  const float* wq     = (const float*)d_in[9];
  const float* bq     = (const float*)d_in[10];
  const float* wk     = (const float*)d_in[11];
  const float* bk     = (const float*)d_in[12];
  const float* wv     = (const float*)d_in[13];
  const float* bv     = (const float*)d_in[14];
  const float* wo     = (const float*)d_in[15];
  const float* bo     = (const float*)d_in[16];
  const float* cv_g   = (const float*)d_in[17];
  const float* cv_b   = (const float*)d_in[18];
  const float* cv_w1  = (const float*)d_in[19];
  const float* cv_b1  = (const float*)d_in[20];
  const float* cv_wd  = (const float*)d_in[21];
  const float* bn_g   = (const float*)d_in[22];
  const float* bn_b   = (const float*)d_in[23];
  const float* cv_w2  = (const float*)d_in[24];
  const float* cv_b2  = (const float*)d_in[25];
  const float* ff2_g  = (const float*)d_in[26];
  const float* ff2_b  = (const float*)d_in[27];
  const float* ff2_w1 = (const float*)d_in[28];
  const float* ff2_b1 = (const float*)d_in[29];
  const float* ff2_w2 = (const float*)d_in[30];
  const float* ff2_b2 = (const float*)d_in[31];
  const float* fin_g  = (const float*)d_in[32];
  const float* fin_b  = (const float*)d_in[33];

  size_t off = 0;
  char* wsb = (char*)d_ws;
  auto take = [&](size_t n) { char* p = wsb + off; off += (n + 255) & ~(size_t)255; return p; };
  short* ff1w1T = (short*)take(2048L * 512 * 2);
  short* ff1w2T = (short*)take(512L * 2048 * 2);
  short* qkvT   = (short*)take(1536L * 512 * 2);
  short* woT    = (short*)take(512L * 512 * 2);
  short* cw1b   = (short*)take(1024L * 512 * 2);
  short* cw2b   = (short*)take(512L * 512 * 2);
  short* wdP    = (short*)take(32L * 512 * 512 * 2);   // 32 taps (tap 31 zero)
  short* ff2w1T = (short*)take(2048L * 512 * 2);
  short* ff2w2T = (short*)take(512L * 2048 * 2);
  float* xcur   = (float*)take(8192L * 512 * 4);
  char*  Ra     = take(8192L * 2048 * 2);              // hid bf16 / qkv bf16 / y1 fp32
  short* Rb     = (short*)take(8192L * 512 * 2);       // ln out / att_o / conv z
  short* Rg     = (short*)take((8L * 1056 + 2) * 512 * 2); // glu_pad (+slack rows)
  char*  Rshare = take(4L * 8192 * 512 * 4);           // conv partials x4 (64MB)
  short* vt     = (short*)take(64L * 64 * 1024 * 2);   // V^T per (b,h)
  float* pe     = (float*)take(1024L * 512 * 4);
  float* stats  = (float*)take(2048L * 4);

  short* hid = (short*)Ra;
  short* qkv = (short*)Ra;
  float* y1  = (float*)Ra;
  float* part0 = (float*)Rshare;

  // ---- weight packs (fp32 -> bf16; per call) ----
  transpose64<1><<<dim3(256, 1, 1), 256, 0, stream>>>(ff1_w1, 2048, ff1w1T, 512, 32, 0, 0, 0, 0);
  transpose64<1><<<dim3(256, 1, 1), 256, 0, stream>>>(ff1_w2, 512, ff1w2T, 2048, 8, 0, 0, 0, 0);
  transpose64<1><<<dim3(8, 1, 8), 256, 0, stream>>>(wq, 64, qkvT, 512, 1, 0, 32768, 0, 32768);
  transpose64<1><<<dim3(8, 1, 8), 256, 0, stream>>>(wk, 64, qkvT + 512 * 512, 512, 1, 0, 32768, 0, 32768);
  transpose64<1><<<dim3(8, 1, 8), 256, 0, stream>>>(wv, 64, qkvT + 1024 * 512, 512, 1, 0, 32768, 0, 32768);
  transpose64<1><<<dim3(64, 1, 1), 256, 0, stream>>>(wo, 512, woT, 512, 8, 0, 0, 0, 0);
  transpose64<1><<<dim3(256, 1, 1), 256, 0, stream>>>(ff2_w1, 2048, ff2w1T, 512, 32, 0, 0, 0, 0);
  transpose64<1><<<dim3(256, 1, 1), 256, 0, stream>>>(ff2_w2, 512, ff2w2T, 2048, 8, 0, 0, 0, 0);
  (void)hipMemsetAsync(wdP, 0, 32L * 512 * 512 * 2, stream);   // zero tap 31
  wd_pack<<<1024, 256, 0, stream>>>(cv_wd, wdP);
  pe_init<<<1024, 256, 0, stream>>>(pe);
  cast_bf16<<<2048, 256, 0, stream>>>(cv_w1, cw1b, 524288L);
  cast_bf16<<<1024, 256, 0, stream>>>(cv_w2, cw2b, 262144L);

  // ---- FF1: x1 = 1.5 x + 0.5 (silu(ln(x) W1 + b1) W2 + b2) ----
  ln_rows<0, 0><<<2048, 256, 0, stream>>>(x_in, ff1_g, ff1_bb, nullptr, Rb);
  gemm_bt<128, 128, 2, 2, EPI_SILU><<<dim3(64, 16, 1), 256, 0, stream>>>(
      Rb, 512, 0, 0, ff1w1T, 512, 0, 0, 512, 0,
      hid, 2048, 0, 0, 0, ff1_b1, nullptr, nullptr, nullptr, 0.f, 0.f);
  gemm_bt<64, 64, 2, 2, EPI_RES><<<dim3(128, 8, 1), 256, 0, stream>>>(
      hid, 2048, 0, 0, ff1w2T, 2048, 0, 0, 2048, 0,
      xcur, 512, 0, 0, 0, ff1_b2, nullptr, nullptr, x_in, 1.5f, 0.5f);

  // ---- MHSA: x2 = 2 x1 + (scramble(attn) Wo + bo) ----
  ln_rows<1, 0><<<2048, 256, 0, stream>>>(xcur, mha_g, mha_b, pe, Rb);
  gemm_bt<128, 128, 2, 2, EPI_QKV><<<dim3(64, 12, 1), 256, 0, stream>>>(
      Rb, 512, 0, 0, qkvT, 512, 0, 0, 512, 0,
      qkv, 1536, 0, 0, 0, bq, bk, bv, nullptr, 0.f, 0.f);
  transpose64<0><<<dim3(16, 1, 64), 256, 0, stream>>>(qkv + 1024, 1536, vt, 1024, 1, 3,
                                                      1024L * 1536, 64, 65536);
  flash_attn<<<dim3(16, 1, 64), 256, 0, stream>>>(qkv, vt, Rb);
  gemm_bt<64, 64, 2, 2, EPI_RES><<<dim3(128, 8, 1), 256, 0, stream>>>(
      Rb, 512, 0, 0, woT, 512, 0, 0, 512, 0,
      xcur, 512, 0, 0, 0, bo, nullptr, nullptr, xcur, 2.f, 1.f);

  // ---- Conv module: x3 = 2 x2 + (W2 silu(BN(conv(glu(W1 ln(x2) + b1)))) + b2) ----
  ln_rows<0, 0><<<2048, 256, 0, stream>>>(xcur, cv_g, cv_b, nullptr, Rb);
  gemm_bt<128, 128, 2, 2, EPI_F32BIAS><<<dim3(64, 8, 1), 256, 0, stream>>>(
      Rb, 512, 0, 0, cw1b, 512, 0, 0, 512, 0,
      y1, 1024, 0, 0, 0, cv_b1, nullptr, nullptr, nullptr, 0.f, 0.f);
  (void)hipMemsetAsync(Rg, 0, (8L * 1056 + 2) * 512 * 2, stream);
  glu_kernel<<<4096, 256, 0, stream>>>(y1, Rg);
  (void)hipMemsetAsync(stats, 0, 1024 * sizeof(float), stream);
  conv_tap<<<1024, 256, 0, stream>>>(Rg, wdP, part0);
  reduce_bn<<<512, 256, 0, stream>>>(part0, 8192L * 512, Rb, stats);
  bn_stats<<<2, 256, 0, stream>>>(stats, bn_g, bn_b);
  bn_silu<<<2048, 256, 0, stream>>>(Rb, stats, (short*)Rg);
  gemm_bt<64, 64, 2, 2, EPI_RES><<<dim3(128, 8, 1), 256, 0, stream>>>(
      (short*)Rg, 512, 0, 0, cw2b, 512, 0, 0, 512, 0,
      xcur, 512, 0, 0, 0, cv_b2, nullptr, nullptr, xcur, 2.f, 1.f);

  // ---- FF2: x4 = 1.5 x3 + 0.5 (...) ----
  ln_rows<0, 0><<<2048, 256, 0, stream>>>(xcur, ff2_g, ff2_b, nullptr, Rb);
  gemm_bt<128, 128, 2, 2, EPI_SILU><<<dim3(64, 16, 1), 256, 0, stream>>>(
      Rb, 512, 0, 0, ff2w1T, 512, 0, 0, 512, 0,
      hid, 2048, 0, 0, 0, ff2_b1, nullptr, nullptr, nullptr, 0.f, 0.f);
  gemm_bt<64, 64, 2, 2, EPI_RES><<<dim3(128, 8, 1), 256, 0, stream>>>(
      hid, 2048, 0, 0, ff2w2T, 2048, 0, 0, 2048, 0,
      xcur, 512, 0, 0, 0, ff2_b2, nullptr, nullptr, xcur, 1.5f, 0.5f);

  // ---- final LN -> d_out (fp32) ----
  ln_rows<0, 1><<<2048, 256, 0, stream>>>(xcur, fin_g, fin_b, nullptr, (float*)d_out);
}

// Round 16
// 548.656 us; speedup vs baseline: 1.0051x; 1.0051x over previous
//
#include <hip/hip_runtime.h>

// ---------------------------------------------------------------------------
// Conformer block, MI355X gfx950. Inputs/outputs fp32; internal activations
// bf16 with fp32 accumulation via bf16 MFMA 16x16x32.
// Round 16: revert to round-14 conv (2-way tap split, proven best 547us).
// Round-15's 4-way split was null (conv is per-CU LDS-BW + B-latency bound;
// occupancy/duration invariant to blocks/CU) and its 4-partial reduce added
// 32MB traffic. Tap-tiled conv: stage 144-row glu slab once per i-chunk, run
// 16 taps against it; B weight-direct in regs; 2 fp32 partials + reduce_bn.
// ---------------------------------------------------------------------------

typedef __attribute__((ext_vector_type(4))) float f32x4;
typedef __attribute__((ext_vector_type(8))) short short8;
typedef __attribute__((ext_vector_type(4))) short s16x4;

__device__ __forceinline__ float bfs2f(short s) {
  unsigned u = ((unsigned)(unsigned short)s) << 16;
  float f; __builtin_memcpy(&f, &u, 4); return f;
}
__device__ __forceinline__ short f2bfs(float f) {
  unsigned u; __builtin_memcpy(&u, &f, 4);
  u = (u + 0x7FFFu + ((u >> 16) & 1u)) >> 16;   // RNE
  return (short)u;
}
__device__ __forceinline__ float sigmoidf_(float x) { return 1.f / (1.f + __expf(-x)); }

#define GLOADLDS(gsrc, ldst) \
  __builtin_amdgcn_global_load_lds((__attribute__((address_space(1))) void*)(gsrc), \
                                   (__attribute__((address_space(3))) void*)(ldst), 16, 0, 0)

#define VMCNT_ASM(n) asm volatile("s_waitcnt vmcnt(" #n ")" ::: "memory")
template<int N> __device__ __forceinline__ void vmcnt_wait() {
  if      constexpr (N == 0)  VMCNT_ASM(0);
  else if constexpr (N == 2)  VMCNT_ASM(2);
  else if constexpr (N == 3)  VMCNT_ASM(3);
  else if constexpr (N == 4)  VMCNT_ASM(4);
  else if constexpr (N == 6)  VMCNT_ASM(6);
  else if constexpr (N == 8)  VMCNT_ASM(8);
  else                        VMCNT_ASM(0);
}
#define MEMFENCE asm volatile("" ::: "memory")

enum { EPI_SILU = 0, EPI_F32BIAS = 1, EPI_RES = 2, EPI_QKV = 3, EPI_F32 = 6 };

// ---------------------------------------------------------------------------
// Generic GEMM: C[M,N] = A[M,K] * BT[N,K]^T, bf16 in, fp32 accum. BK=32.
// Triple-buffered; counted vmcnt(L) + RAW s_barrier. Last-z K decrement.
// ---------------------------------------------------------------------------
template<int BM, int BN, int WM, int WN, int EPI>
__global__ __launch_bounds__(256) void gemm_bt(
    const short* __restrict__ A, int lda, long zAh, long zAl,
    const short* __restrict__ BT, int ldbt, long zBh, long zBl,
    int K, int Kdec,
    void* C, int ldc, long zCh, long zCl, int zdiv,
    const float* bias, const float* bias2, const float* bias3,
    const float* resid, float alpha, float beta)
{
  constexpr int FM = BM / (WM * 16), FN = BN / (WN * 16);
  constexpr int AIT = (BM * 4) / 256, BIT = (BN * 4) / 256;
  constexpr int L = AIT + BIT;
  __shared__ short sA[3][BM * 32];
  __shared__ short sB[3][BN * 32];
  const int tid = threadIdx.x;
  const int zmask = (1 << zdiv) - 1;
  const int zhi = (int)(blockIdx.z >> zdiv);
  const int zlo = (int)(blockIdx.z & zmask);
  A  += (long)zhi * zAh + (long)zlo * zAl;
  BT += (long)zhi * zBh + (long)zlo * zBl;
  char* cbase = (char*)C + (long)zhi * zCh + (long)zlo * zCl;
  const int m0 = blockIdx.x * BM, n0 = blockIdx.y * BN;
  const int Keff = K - (zlo == zmask ? Kdec : 0);

  auto stage = [&](int buf, int k0) {
#pragma unroll
    for (int it = 0; it < AIT; ++it) {
      int idx = it * 256 + tid;
      GLOADLDS(A + (long)(m0 + (idx >> 2)) * lda + k0 + (idx & 3) * 8, &sA[buf][idx * 8]);
    }
#pragma unroll
    for (int it = 0; it < BIT; ++it) {
      int idx = it * 256 + tid;
      GLOADLDS(BT + (long)(n0 + (idx >> 2)) * ldbt + k0 + (idx & 3) * 8, &sB[buf][idx * 8]);
    }
  };

  f32x4 acc[FM][FN];
#pragma unroll
  for (int i = 0; i < FM; ++i) {
#pragma unroll
    for (int j = 0; j < FN; ++j) acc[i][j] = (f32x4){0.f, 0.f, 0.f, 0.f};
  }
  const int lane = tid & 63, wid = tid >> 6;
  const int wm = wid / WN, wn = wid % WN;
  const int lr = lane & 15, kg = lane >> 4;
  const int aRow = wm * (BM / WM), bRow = wn * (BN / WN);

  const int nt = Keff >> 5;
  stage(0, 0);
  stage(1, 32);
  vmcnt_wait<L>();
  __builtin_amdgcn_s_barrier();

  int cur = 0, sbuf = 2;
  for (int t = 0; t < nt; ++t) {
    const bool st = (t + 2 < nt);
    if (st) stage(sbuf, (t + 2) * 32);
    short8 af[FM], bfr[FN];
#pragma unroll
    for (int mi = 0; mi < FM; ++mi)
      af[mi] = *(const short8*)&sA[cur][(aRow + mi * 16 + lr) * 32 + kg * 8];
#pragma unroll
    for (int ni = 0; ni < FN; ++ni)
      bfr[ni] = *(const short8*)&sB[cur][(bRow + ni * 16 + lr) * 32 + kg * 8];
#pragma unroll
    for (int mi = 0; mi < FM; ++mi) {
#pragma unroll
      for (int ni = 0; ni < FN; ++ni)
        acc[mi][ni] = __builtin_amdgcn_mfma_f32_16x16x32_bf16(af[mi], bfr[ni], acc[mi][ni], 0, 0, 0);
    }
    if (st) vmcnt_wait<L>(); else vmcnt_wait<0>();
    __builtin_amdgcn_s_barrier();
    cur = (cur == 2) ? 0 : cur + 1;
    sbuf = (sbuf == 2) ? 0 : sbuf + 1;
  }

  const int baseRow = m0 + aRow, baseCol = n0 + bRow;
#pragma unroll
  for (int mi = 0; mi < FM; ++mi) {
#pragma unroll
    for (int ni = 0; ni < FN; ++ni) {
      const int col = baseCol + ni * 16 + lr;
#pragma unroll
      for (int r = 0; r < 4; ++r) {
        const int row = baseRow + mi * 16 + kg * 4 + r;
        float v = acc[mi][ni][r];
        if (EPI == EPI_SILU) {
          v += bias[col];
          v = v * sigmoidf_(v);
          ((short*)cbase)[(long)row * ldc + col] = f2bfs(v);
        } else if (EPI == EPI_F32BIAS) {
          v += bias[col];
          ((float*)cbase)[(long)row * ldc + col] = v;
        } else if (EPI == EPI_RES) {
          v += bias[col];
          float rv = resid[(long)row * ldc + col];
          ((float*)cbase)[(long)row * ldc + col] = alpha * rv + beta * v;
        } else if (EPI == EPI_QKV) {
          if (col < 512)       v = (v + bias[col]) * 0.125f;   // fold 1/sqrt(64) into q
          else if (col < 1024) v += bias2[col - 512];
          else                 v += bias3[col - 1024];
          ((short*)cbase)[(long)row * ldc + col] = f2bfs(v);
        } else if (EPI == EPI_F32) {
          ((float*)cbase)[(long)row * ldc + col] = v;
        }
      }
    }
  }
}

// ---------------------------------------------------------------------------
// Conv, tap-tiled (round 14): per i-chunk (32 ch), stage 144-row glu slab in
// LDS once, run 16 taps against it (frag row = tap + t-row). B weight-direct
// (fragment-packed wdP, 32 taps with tap 31 zeroed), ping-pong reg prefetch
// in fully-unrolled kk loop. 2-way split-K, XCD-pinned flat grid 512
// (bid&7 -> (y,kg); bid>>3 -> (x=j&7, b=j>>3)).
// ---------------------------------------------------------------------------
__global__ __launch_bounds__(256) void conv_tap(
    const short* __restrict__ glu,    // glu_pad base (b stride 1056*512)
    const short* __restrict__ wdP,    // [(e>>4)*512 + chunk][512]
    float* __restrict__ parts)
{
  __shared__ short sA[2][144 * 32];
  const int tid = threadIdx.x;
  const int bid = blockIdx.x;
  const int cc = bid & 7, j = bid >> 3;
  const int y = cc >> 1, kg = cc & 1;
  const int x = j & 7, b = j >> 3;
  const int m0 = x * 128, n0 = y * 128;
  const short* Arow0 = glu + ((long)b * 1056 + m0 + 1 + kg * 16) * 512;
  float* cbase = parts + (long)kg * (8192L * 512) + (long)b * (1024L * 512);

  const int lane = tid & 63, wid = tid >> 6;
  const int wm = wid >> 1, wn = wid & 1;
  const int lr = lane & 15, kgr = lane >> 4;
  const int aRow = wm * 64, bRow = wn * 64;

  const short* Bp = wdP + (long)((n0 + bRow) >> 4) * (512L * 512)
                  + (long)(kg * 256) * 512 + lane * 8;
  const long NSTR = 512L * 512;   // per-16e-rowtile stride

  auto stageA = [&](int buf, int ib) {
#pragma unroll
    for (int it = 0; it < 3; ++it) {
      int idx = it * 256 + tid;
      if (idx < 576) {
        GLOADLDS(Arow0 + (long)(idx >> 2) * 512 + ib * 32 + (idx & 3) * 8,
                 &sA[buf][idx * 8]);
      }
    }
  };

  f32x4 acc[4][4];
#pragma unroll
  for (int i = 0; i < 4; ++i) {
#pragma unroll
    for (int jj = 0; jj < 4; ++jj) acc[i][jj] = (f32x4){0.f, 0.f, 0.f, 0.f};
  }
  short8 b0[4], b1[4];

  stageA(0, 0);
  MEMFENCE;
#pragma unroll
  for (int ni = 0; ni < 4; ++ni)
    b0[ni] = *(const short8*)(Bp + ni * NSTR);
  MEMFENCE;
  vmcnt_wait<4>();              // stage(0) done; b0 may be in flight
  __builtin_amdgcn_s_barrier();

  int cur = 0;
  for (int ib = 0; ib < 16; ++ib) {
    if (ib + 1 < 16) stageA(cur ^ 1, ib + 1);
    MEMFENCE;
#pragma unroll
    for (int kk = 0; kk < 16; ++kk) {
      // prefetch next frag: (kk+1, ib) or (0, ib+1)
      const long noff = (kk + 1 < 16) ? (long)((kk + 1) * 16 + ib) * 512
                                      : (long)(ib + 1) * 512;
      if ((kk & 1) == 0) {
#pragma unroll
        for (int ni = 0; ni < 4; ++ni)
          b1[ni] = *(const short8*)(Bp + noff + ni * NSTR);
      } else {
#pragma unroll
        for (int ni = 0; ni < 4; ++ni)
          b0[ni] = *(const short8*)(Bp + noff + ni * NSTR);
      }
      short8 af[4];
#pragma unroll
      for (int mi = 0; mi < 4; ++mi)
        af[mi] = *(const short8*)&sA[cur][(kk + aRow + mi * 16 + lr) * 32 + kgr * 8];
      if ((kk & 1) == 0) {
#pragma unroll
        for (int mi = 0; mi < 4; ++mi) {
#pragma unroll
          for (int ni = 0; ni < 4; ++ni)
            acc[mi][ni] = __builtin_amdgcn_mfma_f32_16x16x32_bf16(af[mi], b0[ni], acc[mi][ni], 0, 0, 0);
        }
      } else {
#pragma unroll
        for (int mi = 0; mi < 4; ++mi) {
#pragma unroll
          for (int ni = 0; ni < 4; ++ni)
            acc[mi][ni] = __builtin_amdgcn_mfma_f32_16x16x32_bf16(af[mi], b1[ni], acc[mi][ni], 0, 0, 0);
        }
      }
    }
    vmcnt_wait<4>();            // only newest 4 (unconsumed B prefetch) in flight
    __builtin_amdgcn_s_barrier();
    cur ^= 1;
  }
  vmcnt_wait<0>();

  const int baseRow = m0 + aRow, baseCol = n0 + bRow;
#pragma unroll
  for (int mi = 0; mi < 4; ++mi) {
#pragma unroll
    for (int ni = 0; ni < 4; ++ni) {
      const int col = baseCol + ni * 16 + lr;
#pragma unroll
      for (int r = 0; r < 4; ++r) {
        const int row = baseRow + mi * 16 + kgr * 4 + r;
        cbase[(long)row * 512 + col] = acc[mi][ni][r];
      }
    }
  }
}

// ---------------------------------------------------------------------------
// Flash attention (round 10). Block = 64 q-rows of one (b,h); 4 waves.
// ---------------------------------------------------------------------------
__global__ __launch_bounds__(256) void flash_attn(
    const short* __restrict__ qkv,   // [b][t][1536], q pre-scaled by 1/8
    const short* __restrict__ vt,    // [(b*8+h)][e=64][t=1024]
    short* __restrict__ out)         // scrambled: [b][n>>3][(n&7)*64+e]
{
  __shared__ short sQ[64 * 64];
  __shared__ short sK[64 * 64];
  __shared__ short sV[64 * 64];
  __shared__ short sP[4][16 * 64];
  const int tid = threadIdx.x;
  const int lane = tid & 63, w = tid >> 6;
  const int lr = lane & 15, kg = lane >> 4;
  const int bh = (int)blockIdx.z;
  const int b = bh >> 3, h = bh & 7;
  const int q0 = blockIdx.x * 64;
  const short* qbase = qkv + (long)b * 1024 * 1536 + h * 64;
  const short* kbase = qbase + 512;
  const short* vtb = vt + (long)bh * 65536;

#pragma unroll
  for (int it = 0; it < 2; ++it) {
    int idx = it * 256 + tid;
    int row = idx >> 3, c = (idx & 7) ^ (row & 7);
    GLOADLDS(qbase + (long)(q0 + row) * 1536 + c * 8, &sQ[idx * 8]);
  }
  __syncthreads();
  short8 bq[2];
#pragma unroll
  for (int ks = 0; ks < 2; ++ks)
    bq[ks] = *(const short8*)&sQ[(w * 16 + lr) * 64 + ((ks * 4 + kg) ^ (lr & 7)) * 8];

  f32x4 po[4];
#pragma unroll
  for (int mi = 0; mi < 4; ++mi) po[mi] = (f32x4){0.f, 0.f, 0.f, 0.f};
  float m = -3.0e38f, l = 0.f;

  for (int s0 = 0; s0 < 1024; s0 += 64) {
#pragma unroll
    for (int it = 0; it < 2; ++it) {
      int idx = it * 256 + tid;
      int row = idx >> 3, c = (idx & 7) ^ (row & 7);
      GLOADLDS(kbase + (long)(s0 + row) * 1536 + c * 8, &sK[idx * 8]);
    }
#pragma unroll
    for (int it = 0; it < 2; ++it) {
      int idx = it * 256 + tid;
      int row = idx >> 3, c = (idx & 7) ^ (row & 7);
      GLOADLDS(vtb + (long)row * 1024 + s0 + c * 8, &sV[idx * 8]);
    }
    __syncthreads();

    f32x4 as[4];
#pragma unroll
    for (int mi = 0; mi < 4; ++mi) as[mi] = (f32x4){0.f, 0.f, 0.f, 0.f};
#pragma unroll
    for (int ks = 0; ks < 2; ++ks) {
#pragma unroll
      for (int mi = 0; mi < 4; ++mi) {
        short8 ak = *(const short8*)&sK[(mi * 16 + lr) * 64 + ((ks * 4 + kg) ^ (lr & 7)) * 8];
        as[mi] = __builtin_amdgcn_mfma_f32_16x16x32_bf16(ak, bq[ks], as[mi], 0, 0, 0);
      }
    }

    float rmax = as[0][0];
#pragma unroll
    for (int mi = 0; mi < 4; ++mi) {
#pragma unroll
      for (int r = 0; r < 4; ++r) rmax = fmaxf(rmax, as[mi][r]);
    }
    rmax = fmaxf(rmax, __shfl_xor(rmax, 16));
    rmax = fmaxf(rmax, __shfl_xor(rmax, 32));
    const float mn = fmaxf(m, rmax);
    const float sc = __expf(m - mn);
    float p[4][4];
    float rsum = 0.f;
#pragma unroll
    for (int mi = 0; mi < 4; ++mi) {
#pragma unroll
      for (int r = 0; r < 4; ++r) { p[mi][r] = __expf(as[mi][r] - mn); rsum += p[mi][r]; }
    }
    rsum += __shfl_xor(rsum, 16);
    rsum += __shfl_xor(rsum, 32);
    l = l * sc + rsum;
    m = mn;
#pragma unroll
    for (int mi = 0; mi < 4; ++mi) {
#pragma unroll
      for (int r = 0; r < 4; ++r) po[mi][r] *= sc;
    }
#pragma unroll
    for (int mi = 0; mi < 4; ++mi) {
      s16x4 pk;
#pragma unroll
      for (int r = 0; r < 4; ++r) pk[r] = f2bfs(p[mi][r]);
      *(s16x4*)&sP[w][lr * 64 + ((mi ^ (lr & 3)) * 16 + kg * 4)] = pk;
    }
#pragma unroll
    for (int ks = 0; ks < 2; ++ks) {
      short8 bp = *(const short8*)&sP[w][lr * 64 + (((ks * 2 + (kg >> 1)) ^ (lr & 3)) * 16 + (kg & 1) * 8)];
#pragma unroll
      for (int mi = 0; mi < 4; ++mi) {
        short8 av = *(const short8*)&sV[(mi * 16 + lr) * 64 + ((ks * 4 + kg) ^ (lr & 7)) * 8];
        po[mi] = __builtin_amdgcn_mfma_f32_16x16x32_bf16(av, bp, po[mi], 0, 0, 0);
      }
    }
    __syncthreads();
  }

  const float inv = 1.f / l;
  const int t2 = q0 + w * 16 + lr;
  const int n = h * 1024 + t2;
  short* ob = out + ((long)b * 1024 + (n >> 3)) * 512 + (n & 7) * 64;
#pragma unroll
  for (int mi = 0; mi < 4; ++mi) {
    s16x4 o;
#pragma unroll
    for (int r = 0; r < 4; ++r) o[r] = f2bfs(po[mi][r] * inv);
    *(s16x4*)&ob[mi * 16 + kg * 4] = o;
  }
}

// ---------------------------------------------------------------------------
// Sum TWO conv split-K partials -> z bf16, accumulate BN sum/sumsq stats.
// ---------------------------------------------------------------------------
__global__ __launch_bounds__(256) void reduce_bn(
    const float* __restrict__ parts, long pstride,
    short* __restrict__ z, float* stats)
{
  const int r0 = blockIdx.x * 16;
  const int c = threadIdx.x * 2;
  float s0 = 0.f, s1 = 0.f, q0 = 0.f, q1 = 0.f;
#pragma unroll 4
  for (int r = 0; r < 16; ++r) {
    const long idx = (long)(r0 + r) * 512 + c;
    float a0 = parts[idx] + parts[idx + pstride];
    float a1 = parts[idx + 1] + parts[idx + 1 + pstride];
    z[idx] = f2bfs(a0); z[idx + 1] = f2bfs(a1);
    s0 += a0; s1 += a1; q0 += a0 * a0; q1 += a1 * a1;
  }
  atomicAdd(&stats[c], s0);
  atomicAdd(&stats[c + 1], s1);
  atomicAdd(&stats[512 + c], q0);
  atomicAdd(&stats[512 + c + 1], q1);
}

// ---------------------------------------------------------------------------
// LayerNorm rows of 512 (fp32 in), one wave per row (4 rows/block).
// ---------------------------------------------------------------------------
template<int ADDPE, int OUTF32>
__global__ __launch_bounds__(256) void ln_rows(
    const float* __restrict__ X, const float* __restrict__ g, const float* __restrict__ b,
    const float* __restrict__ pe, void* __restrict__ Y)
{
  const int row = blockIdx.x * 4 + (threadIdx.x >> 6);
  const int lane = threadIdx.x & 63;
  const int c0 = lane * 8;
  const float* src = X + (long)row * 512 + c0;
  f32x4 a = *(const f32x4*)src, c = *(const f32x4*)(src + 4);
  float x[8] = {a[0], a[1], a[2], a[3], c[0], c[1], c[2], c[3]};
  float s = 0.f, q = 0.f;
#pragma unroll
  for (int j = 0; j < 8; ++j) { s += x[j]; q += x[j] * x[j]; }
#pragma unroll
  for (int off = 32; off > 0; off >>= 1) { s += __shfl_xor(s, off); q += __shfl_xor(q, off); }
  const float mean = s * (1.f / 512.f);
  const float var = q * (1.f / 512.f) - mean * mean;
  const float rstd = rsqrtf(var + 1e-5f);
  f32x4 g0 = *(const f32x4*)(g + c0), g1 = *(const f32x4*)(g + c0 + 4);
  f32x4 b0 = *(const f32x4*)(b + c0), b1 = *(const f32x4*)(b + c0 + 4);
  float gg[8] = {g0[0], g0[1], g0[2], g0[3], g1[0], g1[1], g1[2], g1[3]};
  float bb[8] = {b0[0], b0[1], b0[2], b0[3], b1[0], b1[1], b1[2], b1[3]};
  float y[8];
#pragma unroll
  for (int j = 0; j < 8; ++j) {
    y[j] = (x[j] - mean) * rstd * gg[j] + bb[j];
    if (ADDPE) y[j] += pe[(long)(row & 1023) * 512 + c0 + j];
  }
  if (OUTF32) {
    float* dst = (float*)Y + (long)row * 512 + c0;
    *(f32x4*)dst = (f32x4){y[0], y[1], y[2], y[3]};
    *(f32x4*)(dst + 4) = (f32x4){y[4], y[5], y[6], y[7]};
  } else {
    short8 o;
#pragma unroll
    for (int j = 0; j < 8; ++j) o[j] = f2bfs(y[j]);
    *(short8*)((short*)Y + (long)row * 512 + c0) = o;
  }
}

// ---------------------------------------------------------------------------
// 64x64-tile transpose -> bf16 out. INF32: fp32 input (weights) or bf16 input.
// ---------------------------------------------------------------------------
template<int INF32>
__global__ __launch_bounds__(256) void transpose64(
    const void* __restrict__ in_, int ldin, short* __restrict__ out, int ldout,
    int ctiles, int zshift, long zh_in, long zl_in, long z_out)
{
  __shared__ short t[64][72];
  const int z = blockIdx.z;
  const long inoff = (long)(z >> zshift) * zh_in + (long)(z & ((1 << zshift) - 1)) * zl_in;
  const int tr = blockIdx.x / ctiles, tc = blockIdx.x % ctiles;
  short* dst = out + (long)z * z_out + (long)(tc * 64) * ldout + tr * 64;
  const int tid = threadIdx.x;
#pragma unroll
  for (int p = 0; p < 2; ++p) {
    int idx = p * 256 + tid;
    int r = idx >> 3, c8 = (idx & 7) * 8;
    if (INF32) {
      const float* src = (const float*)in_ + inoff + (long)(tr * 64 + r) * ldin + tc * 64 + c8;
      f32x4 v0 = *(const f32x4*)src, v1 = *(const f32x4*)(src + 4);
#pragma unroll
      for (int j = 0; j < 4; ++j) { t[r][c8 + j] = f2bfs(v0[j]); t[r][c8 + 4 + j] = f2bfs(v1[j]); }
    } else {
      const short* src = (const short*)in_ + inoff + (long)(tr * 64 + r) * ldin + tc * 64 + c8;
      short8 v = *(const short8*)src;
#pragma unroll
      for (int j = 0; j < 8; ++j) t[r][c8 + j] = v[j];
    }
  }
  __syncthreads();
#pragma unroll
  for (int p = 0; p < 2; ++p) {
    int idx = p * 256 + tid;
    int c = idx >> 3, r8 = (idx & 7) * 8;
    short8 v;
#pragma unroll
    for (int j = 0; j < 8; ++j) v[j] = t[r8 + j][c];
    *(short8*)(dst + (long)c * ldout + r8) = v;
  }
}

// wdP fragment-packed, 32 taps (tap 31 pre-zeroed): value wd[e][i][KK] ->
// wdP[((e>>4)*512 + KK*16 + (i>>5))*512 + ((i>>3)&3)*128 + (e&15)*8 + (i&7)]
__global__ __launch_bounds__(256) void wd_pack(const float* __restrict__ wd, short* __restrict__ wdP)
{
  const int gid = blockIdx.x * 256 + threadIdx.x;  // 262144 = 512*512
  const int e = gid >> 9, i = gid & 511;
  const float* src = wd + ((long)e * 512 + i) * 31;
  const long rowtile = (long)(e >> 4) * (512L * 512);
  const int inner = ((i >> 3) & 3) * 128 + (e & 15) * 8 + (i & 7);
#pragma unroll
  for (int KK = 0; KK < 31; ++KK)
    wdP[rowtile + (long)(KK * 16 + (i >> 5)) * 512 + inner] = f2bfs(src[KK]);
}

// pe[t][2p] = sin(t * 10000^(-p/256)), pe[t][2p+1] = cos(...)
__global__ __launch_bounds__(256) void pe_init(float* __restrict__ pe)
{
  const int gid = blockIdx.x * 256 + threadIdx.x;  // 262144 = 1024*256
  const int t = gid >> 8, p = gid & 255;
  const float freq = __expf(-(float)p * (9.210340371976184f / 256.f));
  const float ang = (float)t * freq;
  pe[(long)t * 512 + 2 * p]     = sinf(ang);
  pe[(long)t * 512 + 2 * p + 1] = cosf(ang);
}

// glu = a * sigmoid(g) from y1[N][1024] fp32 -> glu_pad[b][16+t][512] bf16
__global__ __launch_bounds__(256) void glu_kernel(const float* __restrict__ y1, short* __restrict__ gp)
{
  const int gid = blockIdx.x * 256 + threadIdx.x;  // 1048576
  const int row = gid >> 7;
  const int ci = (gid & 127) * 4;
  const float* base = y1 + (long)row * 1024;
  f32x4 a = *(const f32x4*)(base + ci);
  f32x4 g = *(const f32x4*)(base + 512 + ci);
  const int b = row >> 10, t = row & 1023;
  s16x4 o;
#pragma unroll
  for (int j = 0; j < 4; ++j) o[j] = f2bfs(a[j] * sigmoidf_(g[j]));
  *(s16x4*)(gp + ((long)b * 1056 + 16 + t) * 512 + ci) = o;
}

__global__ void bn_stats(float* stats, const float* __restrict__ bn_g, const float* __restrict__ bn_b)
{
  const int c = blockIdx.x * 256 + threadIdx.x;
  if (c < 512) {
    float mean = stats[c] * (1.f / 8192.f);
    float var = stats[512 + c] * (1.f / 8192.f) - mean * mean;
    float sc = bn_g[c] * rsqrtf(var + 1e-5f);
    stats[1024 + c] = sc;
    stats[1536 + c] = bn_b[c] - mean * sc;
  }
}

__global__ __launch_bounds__(256) void bn_silu(const short* __restrict__ z, const float* __restrict__ stats,
                                               short* __restrict__ out)
{
  const long base = ((long)blockIdx.x * 256 + threadIdx.x) * 8;
  const int c0 = (int)(base & 511);
  short8 v = *(const short8*)(z + base);
  short8 o;
#pragma unroll
  for (int j = 0; j < 8; ++j) {
    const int c = c0 + j;
    float y = bfs2f(v[j]) * stats[1024 + c] + stats[1536 + c];
    o[j] = f2bfs(y * sigmoidf_(y));
  }
  *(short8*)(out + base) = o;
}

// plain elementwise fp32 -> bf16 cast (grid-stride)
__global__ __launch_bounds__(256) void cast_bf16(const float* __restrict__ in, short* __restrict__ out, long n)
{
  for (long i = (long)blockIdx.x * 256 + threadIdx.x; i < n; i += (long)gridDim.x * 256)
    out[i] = f2bfs(in[i]);
}

// ---------------------------------------------------------------------------
extern "C" void kernel_launch(void* const* d_in, const int* in_sizes, int n_in,
                              void* d_out, int out_size, void* d_ws, size_t ws_size,
                              hipStream_t stream)
{
  (void)in_sizes; (void)n_in; (void)out_size; (void)ws_size;
  const float* x_in   = (const float*)d_in[0];
  const float* ff1_g  = (const float*)d_in[1];
  const float* ff1_bb = (const float*)d_in[2];
  const float* ff1_w1 = (const float*)d_in[3];
  const float* ff1_b1 = (const float*)d_in[4];
  const float* ff1_w2 = (const float*)d_in[5];
  const float* ff1_b2 = (const float*)d_in[6];
  const float* mha_g  = (const float*)d_in[7];
  const float* mha_b  = (const float*)d_in[8];
  const float* wq     = (const float*)d_in[9];
  const float* bq     = (const float*)d_in[10];
  const float* wk     = (const float*)d_in[11];
  const float* bk     = (const float*)d_in[12];
  const float* wv     = (const float*)d_in[13];
  const float* bv     = (const float*)d_in[14];
  const float* wo     = (const float*)d_in[15];
  const float* bo     = (const float*)d_in[16];
  const float* cv_g   = (const float*)d_in[17];
  const float* cv_b   = (const float*)d_in[18];
  const float* cv_w1  = (const float*)d_in[19];
  const float* cv_b1  = (const float*)d_in[20];
  const float* cv_wd  = (const float*)d_in[21];
  const float* bn_g   = (const float*)d_in[22];
  const float* bn_b   = (const float*)d_in[23];
  const float* cv_w2  = (const float*)d_in[24];
  const float* cv_b2  = (const float*)d_in[25];
  const float* ff2_g  = (const float*)d_in[26];
  const float* ff2_b  = (const float*)d_in[27];
  const float* ff2_w1 = (const float*)d_in[28];
  const float* ff2_b1 = (const float*)d_in[29];
  const float* ff2_w2 = (const float*)d_in[30];
  const float* ff2_b2 = (const float*)d_in[31];
  const float* fin_g  = (const float*)d_in[32];
  const float* fin_b  = (const float*)d_in[33];

  size_t off = 0;
  char* wsb = (char*)d_ws;
  auto take = [&](size_t n) { char* p = wsb + off; off += (n + 255) & ~(size_t)255; return p; };
  short* ff1w1T = (short*)take(2048L * 512 * 2);
  short* ff1w2T = (short*)take(512L * 2048 * 2);
  short* qkvT   = (short*)take(1536L * 512 * 2);
  short* woT    = (short*)take(512L * 512 * 2);
  short* cw1b   = (short*)take(1024L * 512 * 2);
  short* cw2b   = (short*)take(512L * 512 * 2);
  short* wdP    = (short*)take(32L * 512 * 512 * 2);   // 32 taps (tap 31 zero)
  short* ff2w1T = (short*)take(2048L * 512 * 2);
  short* ff2w2T = (short*)take(512L * 2048 * 2);
  float* xcur   = (float*)take(8192L * 512 * 4);
  char*  Ra     = take(8192L * 2048 * 2);              // hid bf16 / qkv bf16 / y1 fp32
  short* Rb     = (short*)take(8192L * 512 * 2);       // ln out / att_o / conv z
  short* Rg     = (short*)take((8L * 1056 + 2) * 512 * 2); // glu_pad (+slack rows)
  char*  Rshare = take(2L * 8192 * 512 * 4);           // conv partials x2 (32MB)
  short* vt     = (short*)take(64L * 64 * 1024 * 2);   // V^T per (b,h)
  float* pe     = (float*)take(1024L * 512 * 4);
  float* stats  = (float*)take(2048L * 4);

  short* hid = (short*)Ra;
  short* qkv = (short*)Ra;
  float* y1  = (float*)Ra;
  float* part0 = (float*)Rshare;

  // ---- weight packs (fp32 -> bf16; per call) ----
  transpose64<1><<<dim3(256, 1, 1), 256, 0, stream>>>(ff1_w1, 2048, ff1w1T, 512, 32, 0, 0, 0, 0);
  transpose64<1><<<dim3(256, 1, 1), 256, 0, stream>>>(ff1_w2, 512, ff1w2T, 2048, 8, 0, 0, 0, 0);
  transpose64<1><<<dim3(8, 1, 8), 256, 0, stream>>>(wq, 64, qkvT, 512, 1, 0, 32768, 0, 32768);
  transpose64<1><<<dim3(8, 1, 8), 256, 0, stream>>>(wk, 64, qkvT + 512 * 512, 512, 1, 0, 32768, 0, 32768);
  transpose64<1><<<dim3(8, 1, 8), 256, 0, stream>>>(wv, 64, qkvT + 1024 * 512, 512, 1, 0, 32768, 0, 32768);
  transpose64<1><<<dim3(64, 1, 1), 256, 0, stream>>>(wo, 512, woT, 512, 8, 0, 0, 0, 0);
  transpose64<1><<<dim3(256, 1, 1), 256, 0, stream>>>(ff2_w1, 2048, ff2w1T, 512, 32, 0, 0, 0, 0);
  transpose64<1><<<dim3(256, 1, 1), 256, 0, stream>>>(ff2_w2, 512, ff2w2T, 2048, 8, 0, 0, 0, 0);
  (void)hipMemsetAsync(wdP, 0, 32L * 512 * 512 * 2, stream);   // zero tap 31
  wd_pack<<<1024, 256, 0, stream>>>(cv_wd, wdP);
  pe_init<<<1024, 256, 0, stream>>>(pe);
  cast_bf16<<<2048, 256, 0, stream>>>(cv_w1, cw1b, 524288L);
  cast_bf16<<<1024, 256, 0, stream>>>(cv_w2, cw2b, 262144L);

  // ---- FF1: x1 = 1.5 x + 0.5 (silu(ln(x) W1 + b1) W2 + b2) ----
  ln_rows<0, 0><<<2048, 256, 0, stream>>>(x_in, ff1_g, ff1_bb, nullptr, Rb);
  gemm_bt<128, 128, 2, 2, EPI_SILU><<<dim3(64, 16, 1), 256, 0, stream>>>(
      Rb, 512, 0, 0, ff1w1T, 512, 0, 0, 512, 0,
      hid, 2048, 0, 0, 0, ff1_b1, nullptr, nullptr, nullptr, 0.f, 0.f);
  gemm_bt<64, 64, 2, 2, EPI_RES><<<dim3(128, 8, 1), 256, 0, stream>>>(
      hid, 2048, 0, 0, ff1w2T, 2048, 0, 0, 2048, 0,
      xcur, 512, 0, 0, 0, ff1_b2, nullptr, nullptr, x_in, 1.5f, 0.5f);

  // ---- MHSA: x2 = 2 x1 + (scramble(attn) Wo + bo) ----
  ln_rows<1, 0><<<2048, 256, 0, stream>>>(xcur, mha_g, mha_b, pe, Rb);
  gemm_bt<128, 128, 2, 2, EPI_QKV><<<dim3(64, 12, 1), 256, 0, stream>>>(
      Rb, 512, 0, 0, qkvT, 512, 0, 0, 512, 0,
      qkv, 1536, 0, 0, 0, bq, bk, bv, nullptr, 0.f, 0.f);
  transpose64<0><<<dim3(16, 1, 64), 256, 0, stream>>>(qkv + 1024, 1536, vt, 1024, 1, 3,
                                                      1024L * 1536, 64, 65536);
  flash_attn<<<dim3(16, 1, 64), 256, 0, stream>>>(qkv, vt, Rb);
  gemm_bt<64, 64, 2, 2, EPI_RES><<<dim3(128, 8, 1), 256, 0, stream>>>(
      Rb, 512, 0, 0, woT, 512, 0, 0, 512, 0,
      xcur, 512, 0, 0, 0, bo, nullptr, nullptr, xcur, 2.f, 1.f);

  // ---- Conv module: x3 = 2 x2 + (W2 silu(BN(conv(glu(W1 ln(x2) + b1)))) + b2) ----
  ln_rows<0, 0><<<2048, 256, 0, stream>>>(xcur, cv_g, cv_b, nullptr, Rb);
  gemm_bt<128, 128, 2, 2, EPI_F32BIAS><<<dim3(64, 8, 1), 256, 0, stream>>>(
      Rb, 512, 0, 0, cw1b, 512, 0, 0, 512, 0,
      y1, 1024, 0, 0, 0, cv_b1, nullptr, nullptr, nullptr, 0.f, 0.f);
  (void)hipMemsetAsync(Rg, 0, (8L * 1056 + 2) * 512 * 2, stream);
  glu_kernel<<<4096, 256, 0, stream>>>(y1, Rg);
  (void)hipMemsetAsync(stats, 0, 1024 * sizeof(float), stream);
  conv_tap<<<512, 256, 0, stream>>>(Rg, wdP, part0);
  reduce_bn<<<512, 256, 0, stream>>>(part0, 8192L * 512, Rb, stats);
  bn_stats<<<2, 256, 0, stream>>>(stats, bn_g, bn_b);
  bn_silu<<<2048, 256, 0, stream>>>(Rb, stats, (short*)Rg);
  gemm_bt<64, 64, 2, 2, EPI_RES><<<dim3(128, 8, 1), 256, 0, stream>>>(
      (short*)Rg, 512, 0, 0, cw2b, 512, 0, 0, 512, 0,
      xcur, 512, 0, 0, 0, cv_b2, nullptr, nullptr, xcur, 2.f, 1.f);

  // ---- FF2: x4 = 1.5 x3 + 0.5 (...) ----
  ln_rows<0, 0><<<2048, 256, 0, stream>>>(xcur, ff2_g, ff2_b, nullptr, Rb);
  gemm_bt<128, 128, 2, 2, EPI_SILU><<<dim3(64, 16, 1), 256, 0, stream>>>(
      Rb, 512, 0, 0, ff2w1T, 512, 0, 0, 512, 0,
      hid, 2048, 0, 0, 0, ff2_b1, nullptr, nullptr, nullptr, 0.f, 0.f);
  gemm_bt<64, 64, 2, 2, EPI_RES><<<dim3(128, 8, 1), 256, 0, stream>>>(
      hid, 2048, 0, 0, ff2w2T, 2048, 0, 0, 2048, 0,
      xcur, 512, 0, 0, 0, ff2_b2, nullptr, nullptr, xcur, 1.5f, 0.5f);

  // ---- final LN -> d_out (fp32) ----
  ln_rows<0, 1><<<2048, 256, 0, stream>>>(xcur, fin_g, fin_b, nullptr, (float*)d_out);
}

// Round 17
// 508.026 us; speedup vs baseline: 1.0855x; 1.0800x over previous
//
#include <hip/hip_runtime.h>

// ---------------------------------------------------------------------------
// Conformer block, MI355X gfx950. Inputs/outputs fp32; internal activations
// bf16 with fp32 accumulation via bf16 MFMA 16x16x32.
// Round 17: low-risk bundle. (1) s_setprio(1) around MFMA clusters in
// conv_tap + flash_attn (T5: both have wave role diversity between barriers;
// skip gemm_bt where it's proven null). (2) bf16 conv partials (-48MB
// traffic; ~0.4% relative on z, washed out by BN). (3) wd_pack self-zeroes
// tap 31 -> drop 16MB memset. Everything else frozen at round-16 state.
// ---------------------------------------------------------------------------

typedef __attribute__((ext_vector_type(4))) float f32x4;
typedef __attribute__((ext_vector_type(8))) short short8;
typedef __attribute__((ext_vector_type(4))) short s16x4;

__device__ __forceinline__ float bfs2f(short s) {
  unsigned u = ((unsigned)(unsigned short)s) << 16;
  float f; __builtin_memcpy(&f, &u, 4); return f;
}
__device__ __forceinline__ short f2bfs(float f) {
  unsigned u; __builtin_memcpy(&u, &f, 4);
  u = (u + 0x7FFFu + ((u >> 16) & 1u)) >> 16;   // RNE
  return (short)u;
}
__device__ __forceinline__ float sigmoidf_(float x) { return 1.f / (1.f + __expf(-x)); }

#define GLOADLDS(gsrc, ldst) \
  __builtin_amdgcn_global_load_lds((__attribute__((address_space(1))) void*)(gsrc), \
                                   (__attribute__((address_space(3))) void*)(ldst), 16, 0, 0)

#define VMCNT_ASM(n) asm volatile("s_waitcnt vmcnt(" #n ")" ::: "memory")
template<int N> __device__ __forceinline__ void vmcnt_wait() {
  if      constexpr (N == 0)  VMCNT_ASM(0);
  else if constexpr (N == 2)  VMCNT_ASM(2);
  else if constexpr (N == 3)  VMCNT_ASM(3);
  else if constexpr (N == 4)  VMCNT_ASM(4);
  else if constexpr (N == 6)  VMCNT_ASM(6);
  else if constexpr (N == 8)  VMCNT_ASM(8);
  else                        VMCNT_ASM(0);
}
#define MEMFENCE asm volatile("" ::: "memory")

enum { EPI_SILU = 0, EPI_F32BIAS = 1, EPI_RES = 2, EPI_QKV = 3, EPI_F32 = 6 };

// ---------------------------------------------------------------------------
// Generic GEMM: C[M,N] = A[M,K] * BT[N,K]^T, bf16 in, fp32 accum. BK=32.
// Triple-buffered; counted vmcnt(L) + RAW s_barrier. Last-z K decrement.
// ---------------------------------------------------------------------------
template<int BM, int BN, int WM, int WN, int EPI>
__global__ __launch_bounds__(256) void gemm_bt(
    const short* __restrict__ A, int lda, long zAh, long zAl,
    const short* __restrict__ BT, int ldbt, long zBh, long zBl,
    int K, int Kdec,
    void* C, int ldc, long zCh, long zCl, int zdiv,
    const float* bias, const float* bias2, const float* bias3,
    const float* resid, float alpha, float beta)
{
  constexpr int FM = BM / (WM * 16), FN = BN / (WN * 16);
  constexpr int AIT = (BM * 4) / 256, BIT = (BN * 4) / 256;
  constexpr int L = AIT + BIT;
  __shared__ short sA[3][BM * 32];
  __shared__ short sB[3][BN * 32];
  const int tid = threadIdx.x;
  const int zmask = (1 << zdiv) - 1;
  const int zhi = (int)(blockIdx.z >> zdiv);
  const int zlo = (int)(blockIdx.z & zmask);
  A  += (long)zhi * zAh + (long)zlo * zAl;
  BT += (long)zhi * zBh + (long)zlo * zBl;
  char* cbase = (char*)C + (long)zhi * zCh + (long)zlo * zCl;
  const int m0 = blockIdx.x * BM, n0 = blockIdx.y * BN;
  const int Keff = K - (zlo == zmask ? Kdec : 0);

  auto stage = [&](int buf, int k0) {
#pragma unroll
    for (int it = 0; it < AIT; ++it) {
      int idx = it * 256 + tid;
      GLOADLDS(A + (long)(m0 + (idx >> 2)) * lda + k0 + (idx & 3) * 8, &sA[buf][idx * 8]);
    }
#pragma unroll
    for (int it = 0; it < BIT; ++it) {
      int idx = it * 256 + tid;
      GLOADLDS(BT + (long)(n0 + (idx >> 2)) * ldbt + k0 + (idx & 3) * 8, &sB[buf][idx * 8]);
    }
  };

  f32x4 acc[FM][FN];
#pragma unroll
  for (int i = 0; i < FM; ++i) {
#pragma unroll
    for (int j = 0; j < FN; ++j) acc[i][j] = (f32x4){0.f, 0.f, 0.f, 0.f};
  }
  const int lane = tid & 63, wid = tid >> 6;
  const int wm = wid / WN, wn = wid % WN;
  const int lr = lane & 15, kg = lane >> 4;
  const int aRow = wm * (BM / WM), bRow = wn * (BN / WN);

  const int nt = Keff >> 5;
  stage(0, 0);
  stage(1, 32);
  vmcnt_wait<L>();
  __builtin_amdgcn_s_barrier();

  int cur = 0, sbuf = 2;
  for (int t = 0; t < nt; ++t) {
    const bool st = (t + 2 < nt);
    if (st) stage(sbuf, (t + 2) * 32);
    short8 af[FM], bfr[FN];
#pragma unroll
    for (int mi = 0; mi < FM; ++mi)
      af[mi] = *(const short8*)&sA[cur][(aRow + mi * 16 + lr) * 32 + kg * 8];
#pragma unroll
    for (int ni = 0; ni < FN; ++ni)
      bfr[ni] = *(const short8*)&sB[cur][(bRow + ni * 16 + lr) * 32 + kg * 8];
#pragma unroll
    for (int mi = 0; mi < FM; ++mi) {
#pragma unroll
      for (int ni = 0; ni < FN; ++ni)
        acc[mi][ni] = __builtin_amdgcn_mfma_f32_16x16x32_bf16(af[mi], bfr[ni], acc[mi][ni], 0, 0, 0);
    }
    if (st) vmcnt_wait<L>(); else vmcnt_wait<0>();
    __builtin_amdgcn_s_barrier();
    cur = (cur == 2) ? 0 : cur + 1;
    sbuf = (sbuf == 2) ? 0 : sbuf + 1;
  }

  const int baseRow = m0 + aRow, baseCol = n0 + bRow;
#pragma unroll
  for (int mi = 0; mi < FM; ++mi) {
#pragma unroll
    for (int ni = 0; ni < FN; ++ni) {
      const int col = baseCol + ni * 16 + lr;
#pragma unroll
      for (int r = 0; r < 4; ++r) {
        const int row = baseRow + mi * 16 + kg * 4 + r;
        float v = acc[mi][ni][r];
        if (EPI == EPI_SILU) {
          v += bias[col];
          v = v * sigmoidf_(v);
          ((short*)cbase)[(long)row * ldc + col] = f2bfs(v);
        } else if (EPI == EPI_F32BIAS) {
          v += bias[col];
          ((float*)cbase)[(long)row * ldc + col] = v;
        } else if (EPI == EPI_RES) {
          v += bias[col];
          float rv = resid[(long)row * ldc + col];
          ((float*)cbase)[(long)row * ldc + col] = alpha * rv + beta * v;
        } else if (EPI == EPI_QKV) {
          if (col < 512)       v = (v + bias[col]) * 0.125f;   // fold 1/sqrt(64) into q
          else if (col < 1024) v += bias2[col - 512];
          else                 v += bias3[col - 1024];
          ((short*)cbase)[(long)row * ldc + col] = f2bfs(v);
        } else if (EPI == EPI_F32) {
          ((float*)cbase)[(long)row * ldc + col] = v;
        }
      }
    }
  }
}

// ---------------------------------------------------------------------------
// Conv, tap-tiled: per i-chunk (32 ch), stage 144-row glu slab in LDS once,
// run 16 taps against it (frag row = tap + t-row). B weight-direct
// (fragment-packed wdP, 32 taps with tap 31 zeroed), ping-pong reg prefetch.
// 2-way split-K, XCD-pinned flat grid 512. bf16 partials. setprio on MFMA.
// ---------------------------------------------------------------------------
__global__ __launch_bounds__(256) void conv_tap(
    const short* __restrict__ glu,    // glu_pad base (b stride 1056*512)
    const short* __restrict__ wdP,    // [(e>>4)*512 + chunk][512]
    short* __restrict__ parts)        // bf16 partials, 2 copies
{
  __shared__ short sA[2][144 * 32];
  const int tid = threadIdx.x;
  const int bid = blockIdx.x;
  const int cc = bid & 7, j = bid >> 3;
  const int y = cc >> 1, kg = cc & 1;
  const int x = j & 7, b = j >> 3;
  const int m0 = x * 128, n0 = y * 128;
  const short* Arow0 = glu + ((long)b * 1056 + m0 + 1 + kg * 16) * 512;
  short* cbase = parts + (long)kg * (8192L * 512) + (long)b * (1024L * 512);

  const int lane = tid & 63, wid = tid >> 6;
  const int wm = wid >> 1, wn = wid & 1;
  const int lr = lane & 15, kgr = lane >> 4;
  const int aRow = wm * 64, bRow = wn * 64;

  const short* Bp = wdP + (long)((n0 + bRow) >> 4) * (512L * 512)
                  + (long)(kg * 256) * 512 + lane * 8;
  const long NSTR = 512L * 512;   // per-16e-rowtile stride

  auto stageA = [&](int buf, int ib) {
#pragma unroll
    for (int it = 0; it < 3; ++it) {
      int idx = it * 256 + tid;
      if (idx < 576) {
        GLOADLDS(Arow0 + (long)(idx >> 2) * 512 + ib * 32 + (idx & 3) * 8,
                 &sA[buf][idx * 8]);
      }
    }
  };

  f32x4 acc[4][4];
#pragma unroll
  for (int i = 0; i < 4; ++i) {
#pragma unroll
    for (int jj = 0; jj < 4; ++jj) acc[i][jj] = (f32x4){0.f, 0.f, 0.f, 0.f};
  }
  short8 b0[4], b1[4];

  stageA(0, 0);
  MEMFENCE;
#pragma unroll
  for (int ni = 0; ni < 4; ++ni)
    b0[ni] = *(const short8*)(Bp + ni * NSTR);
  MEMFENCE;
  vmcnt_wait<4>();              // stage(0) done; b0 may be in flight
  __builtin_amdgcn_s_barrier();

  int cur = 0;
  for (int ib = 0; ib < 16; ++ib) {
    if (ib + 1 < 16) stageA(cur ^ 1, ib + 1);
    MEMFENCE;
#pragma unroll
    for (int kk = 0; kk < 16; ++kk) {
      // prefetch next frag: (kk+1, ib) or (0, ib+1)
      const long noff = (kk + 1 < 16) ? (long)((kk + 1) * 16 + ib) * 512
                                      : (long)(ib + 1) * 512;
      if ((kk & 1) == 0) {
#pragma unroll
        for (int ni = 0; ni < 4; ++ni)
          b1[ni] = *(const short8*)(Bp + noff + ni * NSTR);
      } else {
#pragma unroll
        for (int ni = 0; ni < 4; ++ni)
          b0[ni] = *(const short8*)(Bp + noff + ni * NSTR);
      }
      short8 af[4];
#pragma unroll
      for (int mi = 0; mi < 4; ++mi)
        af[mi] = *(const short8*)&sA[cur][(kk + aRow + mi * 16 + lr) * 32 + kgr * 8];
      __builtin_amdgcn_s_setprio(1);
      if ((kk & 1) == 0) {
#pragma unroll
        for (int mi = 0; mi < 4; ++mi) {
#pragma unroll
          for (int ni = 0; ni < 4; ++ni)
            acc[mi][ni] = __builtin_amdgcn_mfma_f32_16x16x32_bf16(af[mi], b0[ni], acc[mi][ni], 0, 0, 0);
        }
      } else {
#pragma unroll
        for (int mi = 0; mi < 4; ++mi) {
#pragma unroll
          for (int ni = 0; ni < 4; ++ni)
            acc[mi][ni] = __builtin_amdgcn_mfma_f32_16x16x32_bf16(af[mi], b1[ni], acc[mi][ni], 0, 0, 0);
        }
      }
      __builtin_amdgcn_s_setprio(0);
    }
    vmcnt_wait<4>();            // only newest 4 (unconsumed B prefetch) in flight
    __builtin_amdgcn_s_barrier();
    cur ^= 1;
  }
  vmcnt_wait<0>();

  const int baseRow = m0 + aRow, baseCol = n0 + bRow;
#pragma unroll
  for (int mi = 0; mi < 4; ++mi) {
#pragma unroll
    for (int ni = 0; ni < 4; ++ni) {
      const int col = baseCol + ni * 16 + lr;
#pragma unroll
      for (int r = 0; r < 4; ++r) {
        const int row = baseRow + mi * 16 + kgr * 4 + r;
        cbase[(long)row * 512 + col] = f2bfs(acc[mi][ni][r]);
      }
    }
  }
}

// ---------------------------------------------------------------------------
// Flash attention. Block = 64 q-rows of one (b,h); 4 waves. setprio on MFMA.
// ---------------------------------------------------------------------------
__global__ __launch_bounds__(256) void flash_attn(
    const short* __restrict__ qkv,   // [b][t][1536], q pre-scaled by 1/8
    const short* __restrict__ vt,    // [(b*8+h)][e=64][t=1024]
    short* __restrict__ out)         // scrambled: [b][n>>3][(n&7)*64+e]
{
  __shared__ short sQ[64 * 64];
  __shared__ short sK[64 * 64];
  __shared__ short sV[64 * 64];
  __shared__ short sP[4][16 * 64];
  const int tid = threadIdx.x;
  const int lane = tid & 63, w = tid >> 6;
  const int lr = lane & 15, kg = lane >> 4;
  const int bh = (int)blockIdx.z;
  const int b = bh >> 3, h = bh & 7;
  const int q0 = blockIdx.x * 64;
  const short* qbase = qkv + (long)b * 1024 * 1536 + h * 64;
  const short* kbase = qbase + 512;
  const short* vtb = vt + (long)bh * 65536;

#pragma unroll
  for (int it = 0; it < 2; ++it) {
    int idx = it * 256 + tid;
    int row = idx >> 3, c = (idx & 7) ^ (row & 7);
    GLOADLDS(qbase + (long)(q0 + row) * 1536 + c * 8, &sQ[idx * 8]);
  }
  __syncthreads();
  short8 bq[2];
#pragma unroll
  for (int ks = 0; ks < 2; ++ks)
    bq[ks] = *(const short8*)&sQ[(w * 16 + lr) * 64 + ((ks * 4 + kg) ^ (lr & 7)) * 8];

  f32x4 po[4];
#pragma unroll
  for (int mi = 0; mi < 4; ++mi) po[mi] = (f32x4){0.f, 0.f, 0.f, 0.f};
  float m = -3.0e38f, l = 0.f;

  for (int s0 = 0; s0 < 1024; s0 += 64) {
#pragma unroll
    for (int it = 0; it < 2; ++it) {
      int idx = it * 256 + tid;
      int row = idx >> 3, c = (idx & 7) ^ (row & 7);
      GLOADLDS(kbase + (long)(s0 + row) * 1536 + c * 8, &sK[idx * 8]);
    }
#pragma unroll
    for (int it = 0; it < 2; ++it) {
      int idx = it * 256 + tid;
      int row = idx >> 3, c = (idx & 7) ^ (row & 7);
      GLOADLDS(vtb + (long)row * 1024 + s0 + c * 8, &sV[idx * 8]);
    }
    __syncthreads();

    f32x4 as[4];
#pragma unroll
    for (int mi = 0; mi < 4; ++mi) as[mi] = (f32x4){0.f, 0.f, 0.f, 0.f};
    __builtin_amdgcn_s_setprio(1);
#pragma unroll
    for (int ks = 0; ks < 2; ++ks) {
#pragma unroll
      for (int mi = 0; mi < 4; ++mi) {
        short8 ak = *(const short8*)&sK[(mi * 16 + lr) * 64 + ((ks * 4 + kg) ^ (lr & 7)) * 8];
        as[mi] = __builtin_amdgcn_mfma_f32_16x16x32_bf16(ak, bq[ks], as[mi], 0, 0, 0);
      }
    }
    __builtin_amdgcn_s_setprio(0);

    float rmax = as[0][0];
#pragma unroll
    for (int mi = 0; mi < 4; ++mi) {
#pragma unroll
      for (int r = 0; r < 4; ++r) rmax = fmaxf(rmax, as[mi][r]);
    }
    rmax = fmaxf(rmax, __shfl_xor(rmax, 16));
    rmax = fmaxf(rmax, __shfl_xor(rmax, 32));
    const float mn = fmaxf(m, rmax);
    const float sc = __expf(m - mn);
    float p[4][4];
    float rsum = 0.f;
#pragma unroll
    for (int mi = 0; mi < 4; ++mi) {
#pragma unroll
      for (int r = 0; r < 4; ++r) { p[mi][r] = __expf(as[mi][r] - mn); rsum += p[mi][r]; }
    }
    rsum += __shfl_xor(rsum, 16);
    rsum += __shfl_xor(rsum, 32);
    l = l * sc + rsum;
    m = mn;
#pragma unroll
    for (int mi = 0; mi < 4; ++mi) {
#pragma unroll
      for (int r = 0; r < 4; ++r) po[mi][r] *= sc;
    }
#pragma unroll
    for (int mi = 0; mi < 4; ++mi) {
      s16x4 pk;
#pragma unroll
      for (int r = 0; r < 4; ++r) pk[r] = f2bfs(p[mi][r]);
      *(s16x4*)&sP[w][lr * 64 + ((mi ^ (lr & 3)) * 16 + kg * 4)] = pk;
    }
    __builtin_amdgcn_s_setprio(1);
#pragma unroll
    for (int ks = 0; ks < 2; ++ks) {
      short8 bp = *(const short8*)&sP[w][lr * 64 + (((ks * 2 + (kg >> 1)) ^ (lr & 3)) * 16 + (kg & 1) * 8)];
#pragma unroll
      for (int mi = 0; mi < 4; ++mi) {
        short8 av = *(const short8*)&sV[(mi * 16 + lr) * 64 + ((ks * 4 + kg) ^ (lr & 7)) * 8];
        po[mi] = __builtin_amdgcn_mfma_f32_16x16x32_bf16(av, bp, po[mi], 0, 0, 0);
      }
    }
    __builtin_amdgcn_s_setprio(0);
    __syncthreads();
  }

  const float inv = 1.f / l;
  const int t2 = q0 + w * 16 + lr;
  const int n = h * 1024 + t2;
  short* ob = out + ((long)b * 1024 + (n >> 3)) * 512 + (n & 7) * 64;
#pragma unroll
  for (int mi = 0; mi < 4; ++mi) {
    s16x4 o;
#pragma unroll
    for (int r = 0; r < 4; ++r) o[r] = f2bfs(po[mi][r] * inv);
    *(s16x4*)&ob[mi * 16 + kg * 4] = o;
  }
}

// ---------------------------------------------------------------------------
// Sum TWO bf16 conv partials -> z bf16, accumulate BN sum/sumsq stats.
// ---------------------------------------------------------------------------
__global__ __launch_bounds__(256) void reduce_bn(
    const short* __restrict__ parts, long pstride,
    short* __restrict__ z, float* stats)
{
  const int r0 = blockIdx.x * 16;
  const int c = threadIdx.x * 2;
  float s0 = 0.f, s1 = 0.f, q0 = 0.f, q1 = 0.f;
#pragma unroll 4
  for (int r = 0; r < 16; ++r) {
    const long idx = (long)(r0 + r) * 512 + c;
    int p0 = *(const int*)&parts[idx];
    int p1 = *(const int*)&parts[idx + pstride];
    float a0 = bfs2f((short)(p0 & 0xffff)) + bfs2f((short)(p1 & 0xffff));
    float a1 = bfs2f((short)(p0 >> 16)) + bfs2f((short)(p1 >> 16));
    int zo = ((int)(unsigned short)f2bfs(a0)) | (((int)(unsigned short)f2bfs(a1)) << 16);
    *(int*)&z[idx] = zo;
    s0 += a0; s1 += a1; q0 += a0 * a0; q1 += a1 * a1;
  }
  atomicAdd(&stats[c], s0);
  atomicAdd(&stats[c + 1], s1);
  atomicAdd(&stats[512 + c], q0);
  atomicAdd(&stats[512 + c + 1], q1);
}

// ---------------------------------------------------------------------------
// LayerNorm rows of 512 (fp32 in), one wave per row (4 rows/block).
// ---------------------------------------------------------------------------
template<int ADDPE, int OUTF32>
__global__ __launch_bounds__(256) void ln_rows(
    const float* __restrict__ X, const float* __restrict__ g, const float* __restrict__ b,
    const float* __restrict__ pe, void* __restrict__ Y)
{
  const int row = blockIdx.x * 4 + (threadIdx.x >> 6);
  const int lane = threadIdx.x & 63;
  const int c0 = lane * 8;
  const float* src = X + (long)row * 512 + c0;
  f32x4 a = *(const f32x4*)src, c = *(const f32x4*)(src + 4);
  float x[8] = {a[0], a[1], a[2], a[3], c[0], c[1], c[2], c[3]};
  float s = 0.f, q = 0.f;
#pragma unroll
  for (int j = 0; j < 8; ++j) { s += x[j]; q += x[j] * x[j]; }
#pragma unroll
  for (int off = 32; off > 0; off >>= 1) { s += __shfl_xor(s, off); q += __shfl_xor(q, off); }
  const float mean = s * (1.f / 512.f);
  const float var = q * (1.f / 512.f) - mean * mean;
  const float rstd = rsqrtf(var + 1e-5f);
  f32x4 g0 = *(const f32x4*)(g + c0), g1 = *(const f32x4*)(g + c0 + 4);
  f32x4 b0 = *(const f32x4*)(b + c0), b1 = *(const f32x4*)(b + c0 + 4);
  float gg[8] = {g0[0], g0[1], g0[2], g0[3], g1[0], g1[1], g1[2], g1[3]};
  float bb[8] = {b0[0], b0[1], b0[2], b0[3], b1[0], b1[1], b1[2], b1[3]};
  float y[8];
#pragma unroll
  for (int j = 0; j < 8; ++j) {
    y[j] = (x[j] - mean) * rstd * gg[j] + bb[j];
    if (ADDPE) y[j] += pe[(long)(row & 1023) * 512 + c0 + j];
  }
  if (OUTF32) {
    float* dst = (float*)Y + (long)row * 512 + c0;
    *(f32x4*)dst = (f32x4){y[0], y[1], y[2], y[3]};
    *(f32x4*)(dst + 4) = (f32x4){y[4], y[5], y[6], y[7]};
  } else {
    short8 o;
#pragma unroll
    for (int j = 0; j < 8; ++j) o[j] = f2bfs(y[j]);
    *(short8*)((short*)Y + (long)row * 512 + c0) = o;
  }
}

// ---------------------------------------------------------------------------
// 64x64-tile transpose -> bf16 out. INF32: fp32 input (weights) or bf16 input.
// ---------------------------------------------------------------------------
template<int INF32>
__global__ __launch_bounds__(256) void transpose64(
    const void* __restrict__ in_, int ldin, short* __restrict__ out, int ldout,
    int ctiles, int zshift, long zh_in, long zl_in, long z_out)
{
  __shared__ short t[64][72];
  const int z = blockIdx.z;
  const long inoff = (long)(z >> zshift) * zh_in + (long)(z & ((1 << zshift) - 1)) * zl_in;
  const int tr = blockIdx.x / ctiles, tc = blockIdx.x % ctiles;
  short* dst = out + (long)z * z_out + (long)(tc * 64) * ldout + tr * 64;
  const int tid = threadIdx.x;
#pragma unroll
  for (int p = 0; p < 2; ++p) {
    int idx = p * 256 + tid;
    int r = idx >> 3, c8 = (idx & 7) * 8;
    if (INF32) {
      const float* src = (const float*)in_ + inoff + (long)(tr * 64 + r) * ldin + tc * 64 + c8;
      f32x4 v0 = *(const f32x4*)src, v1 = *(const f32x4*)(src + 4);
#pragma unroll
      for (int j = 0; j < 4; ++j) { t[r][c8 + j] = f2bfs(v0[j]); t[r][c8 + 4 + j] = f2bfs(v1[j]); }
    } else {
      const short* src = (const short*)in_ + inoff + (long)(tr * 64 + r) * ldin + tc * 64 + c8;
      short8 v = *(const short8*)src;
#pragma unroll
      for (int j = 0; j < 8; ++j) t[r][c8 + j] = v[j];
    }
  }
  __syncthreads();
#pragma unroll
  for (int p = 0; p < 2; ++p) {
    int idx = p * 256 + tid;
    int c = idx >> 3, r8 = (idx & 7) * 8;
    short8 v;
#pragma unroll
    for (int j = 0; j < 8; ++j) v[j] = t[r8 + j][c];
    *(short8*)(dst + (long)c * ldout + r8) = v;
  }
}

// wdP fragment-packed, 32 taps; this kernel also zeroes tap 31 (no memset):
// value wd[e][i][KK] ->
// wdP[((e>>4)*512 + KK*16 + (i>>5))*512 + ((i>>3)&3)*128 + (e&15)*8 + (i&7)]
__global__ __launch_bounds__(256) void wd_pack(const float* __restrict__ wd, short* __restrict__ wdP)
{
  const int gid = blockIdx.x * 256 + threadIdx.x;  // 262144 = 512*512
  const int e = gid >> 9, i = gid & 511;
  const float* src = wd + ((long)e * 512 + i) * 31;
  const long rowtile = (long)(e >> 4) * (512L * 512);
  const int inner = ((i >> 3) & 3) * 128 + (e & 15) * 8 + (i & 7);
#pragma unroll
  for (int KK = 0; KK < 31; ++KK)
    wdP[rowtile + (long)(KK * 16 + (i >> 5)) * 512 + inner] = f2bfs(src[KK]);
  wdP[rowtile + (long)(31 * 16 + (i >> 5)) * 512 + inner] = 0;   // tap 31 zero
}

// pe[t][2p] = sin(t * 10000^(-p/256)), pe[t][2p+1] = cos(...)
__global__ __launch_bounds__(256) void pe_init(float* __restrict__ pe)
{
  const int gid = blockIdx.x * 256 + threadIdx.x;  // 262144 = 1024*256
  const int t = gid >> 8, p = gid & 255;
  const float freq = __expf(-(float)p * (9.210340371976184f / 256.f));
  const float ang = (float)t * freq;
  pe[(long)t * 512 + 2 * p]     = sinf(ang);
  pe[(long)t * 512 + 2 * p + 1] = cosf(ang);
}

// glu = a * sigmoid(g) from y1[N][1024] fp32 -> glu_pad[b][16+t][512] bf16
__global__ __launch_bounds__(256) void glu_kernel(const float* __restrict__ y1, short* __restrict__ gp)
{
  const int gid = blockIdx.x * 256 + threadIdx.x;  // 1048576
  const int row = gid >> 7;
  const int ci = (gid & 127) * 4;
  const float* base = y1 + (long)row * 1024;
  f32x4 a = *(const f32x4*)(base + ci);
  f32x4 g = *(const f32x4*)(base + 512 + ci);
  const int b = row >> 10, t = row & 1023;
  s16x4 o;
#pragma unroll
  for (int j = 0; j < 4; ++j) o[j] = f2bfs(a[j] * sigmoidf_(g[j]));
  *(s16x4*)(gp + ((long)b * 1056 + 16 + t) * 512 + ci) = o;
}

__global__ void bn_stats(float* stats, const float* __restrict__ bn_g, const float* __restrict__ bn_b)
{
  const int c = blockIdx.x * 256 + threadIdx.x;
  if (c < 512) {
    float mean = stats[c] * (1.f / 8192.f);
    float var = stats[512 + c] * (1.f / 8192.f) - mean * mean;
    float sc = bn_g[c] * rsqrtf(var + 1e-5f);
    stats[1024 + c] = sc;
    stats[1536 + c] = bn_b[c] - mean * sc;
  }
}

__global__ __launch_bounds__(256) void bn_silu(const short* __restrict__ z, const float* __restrict__ stats,
                                               short* __restrict__ out)
{
  const long base = ((long)blockIdx.x * 256 + threadIdx.x) * 8;
  const int c0 = (int)(base & 511);
  short8 v = *(const short8*)(z + base);
  short8 o;
#pragma unroll
  for (int j = 0; j < 8; ++j) {
    const int c = c0 + j;
    float y = bfs2f(v[j]) * stats[1024 + c] + stats[1536 + c];
    o[j] = f2bfs(y * sigmoidf_(y));
  }
  *(short8*)(out + base) = o;
}

// plain elementwise fp32 -> bf16 cast (grid-stride)
__global__ __launch_bounds__(256) void cast_bf16(const float* __restrict__ in, short* __restrict__ out, long n)
{
  for (long i = (long)blockIdx.x * 256 + threadIdx.x; i < n; i += (long)gridDim.x * 256)
    out[i] = f2bfs(in[i]);
}

// ---------------------------------------------------------------------------
extern "C" void kernel_launch(void* const* d_in, const int* in_sizes, int n_in,
                              void* d_out, int out_size, void* d_ws, size_t ws_size,
                              hipStream_t stream)
{
  (void)in_sizes; (void)n_in; (void)out_size; (void)ws_size;
  const float* x_in   = (const float*)d_in[0];
  const float* ff1_g  = (const float*)d_in[1];
  const float* ff1_bb = (const float*)d_in[2];
  const float* ff1_w1 = (const float*)d_in[3];
  const float* ff1_b1 = (const float*)d_in[4];
  const float* ff1_w2 = (const float*)d_in[5];
  const float* ff1_b2 = (const float*)d_in[6];
  const float* mha_g  = (const float*)d_in[7];
  const float* mha_b  = (const float*)d_in[8];
  const float* wq     = (const float*)d_in[9];
  const float* bq     = (const float*)d_in[10];
  const float* wk     = (const float*)d_in[11];
  const float* bk     = (const float*)d_in[12];
  const float* wv     = (const float*)d_in[13];
  const float* bv     = (const float*)d_in[14];
  const float* wo     = (const float*)d_in[15];
  const float* bo     = (const float*)d_in[16];
  const float* cv_g   = (const float*)d_in[17];
  const float* cv_b   = (const float*)d_in[18];
  const float* cv_w1  = (const float*)d_in[19];
  const float* cv_b1  = (const float*)d_in[20];
  const float* cv_wd  = (const float*)d_in[21];
  const float* bn_g   = (const float*)d_in[22];
  const float* bn_b   = (const float*)d_in[23];
  const float* cv_w2  = (const float*)d_in[24];
  const float* cv_b2  = (const float*)d_in[25];
  const float* ff2_g  = (const float*)d_in[26];
  const float* ff2_b  = (const float*)d_in[27];
  const float* ff2_w1 = (const float*)d_in[28];
  const float* ff2_b1 = (const float*)d_in[29];
  const float* ff2_w2 = (const float*)d_in[30];
  const float* ff2_b2 = (const float*)d_in[31];
  const float* fin_g  = (const float*)d_in[32];
  const float* fin_b  = (const float*)d_in[33];

  size_t off = 0;
  char* wsb = (char*)d_ws;
  auto take = [&](size_t n) { char* p = wsb + off; off += (n + 255) & ~(size_t)255; return p; };
  short* ff1w1T = (short*)take(2048L * 512 * 2);
  short* ff1w2T = (short*)take(512L * 2048 * 2);
  short* qkvT   = (short*)take(1536L * 512 * 2);
  short* woT    = (short*)take(512L * 512 * 2);
  short* cw1b   = (short*)take(1024L * 512 * 2);
  short* cw2b   = (short*)take(512L * 512 * 2);
  short* wdP    = (short*)take(32L * 512 * 512 * 2);   // 32 taps (tap 31 zero)
  short* ff2w1T = (short*)take(2048L * 512 * 2);
  short* ff2w2T = (short*)take(512L * 2048 * 2);
  float* xcur   = (float*)take(8192L * 512 * 4);
  char*  Ra     = take(8192L * 2048 * 2);              // hid bf16 / qkv bf16 / y1 fp32
  short* Rb     = (short*)take(8192L * 512 * 2);       // ln out / att_o / conv z
  short* Rg     = (short*)take((8L * 1056 + 2) * 512 * 2); // glu_pad (+slack rows)
  short* parts  = (short*)take(2L * 8192 * 512 * 2);   // conv partials x2 (bf16, 16MB)
  short* vt     = (short*)take(64L * 64 * 1024 * 2);   // V^T per (b,h)
  float* pe     = (float*)take(1024L * 512 * 4);
  float* stats  = (float*)take(2048L * 4);

  short* hid = (short*)Ra;
  short* qkv = (short*)Ra;
  float* y1  = (float*)Ra;

  // ---- weight packs (fp32 -> bf16; per call) ----
  transpose64<1><<<dim3(256, 1, 1), 256, 0, stream>>>(ff1_w1, 2048, ff1w1T, 512, 32, 0, 0, 0, 0);
  transpose64<1><<<dim3(256, 1, 1), 256, 0, stream>>>(ff1_w2, 512, ff1w2T, 2048, 8, 0, 0, 0, 0);
  transpose64<1><<<dim3(8, 1, 8), 256, 0, stream>>>(wq, 64, qkvT, 512, 1, 0, 32768, 0, 32768);
  transpose64<1><<<dim3(8, 1, 8), 256, 0, stream>>>(wk, 64, qkvT + 512 * 512, 512, 1, 0, 32768, 0, 32768);
  transpose64<1><<<dim3(8, 1, 8), 256, 0, stream>>>(wv, 64, qkvT + 1024 * 512, 512, 1, 0, 32768, 0, 32768);
  transpose64<1><<<dim3(64, 1, 1), 256, 0, stream>>>(wo, 512, woT, 512, 8, 0, 0, 0, 0);
  transpose64<1><<<dim3(256, 1, 1), 256, 0, stream>>>(ff2_w1, 2048, ff2w1T, 512, 32, 0, 0, 0, 0);
  transpose64<1><<<dim3(256, 1, 1), 256, 0, stream>>>(ff2_w2, 512, ff2w2T, 2048, 8, 0, 0, 0, 0);
  wd_pack<<<1024, 256, 0, stream>>>(cv_wd, wdP);
  pe_init<<<1024, 256, 0, stream>>>(pe);
  cast_bf16<<<2048, 256, 0, stream>>>(cv_w1, cw1b, 524288L);
  cast_bf16<<<1024, 256, 0, stream>>>(cv_w2, cw2b, 262144L);

  // ---- FF1: x1 = 1.5 x + 0.5 (silu(ln(x) W1 + b1) W2 + b2) ----
  ln_rows<0, 0><<<2048, 256, 0, stream>>>(x_in, ff1_g, ff1_bb, nullptr, Rb);
  gemm_bt<128, 128, 2, 2, EPI_SILU><<<dim3(64, 16, 1), 256, 0, stream>>>(
      Rb, 512, 0, 0, ff1w1T, 512, 0, 0, 512, 0,
      hid, 2048, 0, 0, 0, ff1_b1, nullptr, nullptr, nullptr, 0.f, 0.f);
  gemm_bt<64, 64, 2, 2, EPI_RES><<<dim3(128, 8, 1), 256, 0, stream>>>(
      hid, 2048, 0, 0, ff1w2T, 2048, 0, 0, 2048, 0,
      xcur, 512, 0, 0, 0, ff1_b2, nullptr, nullptr, x_in, 1.5f, 0.5f);

  // ---- MHSA: x2 = 2 x1 + (scramble(attn) Wo + bo) ----
  ln_rows<1, 0><<<2048, 256, 0, stream>>>(xcur, mha_g, mha_b, pe, Rb);
  gemm_bt<128, 128, 2, 2, EPI_QKV><<<dim3(64, 12, 1), 256, 0, stream>>>(
      Rb, 512, 0, 0, qkvT, 512, 0, 0, 512, 0,
      qkv, 1536, 0, 0, 0, bq, bk, bv, nullptr, 0.f, 0.f);
  transpose64<0><<<dim3(16, 1, 64), 256, 0, stream>>>(qkv + 1024, 1536, vt, 1024, 1, 3,
                                                      1024L * 1536, 64, 65536);
  flash_attn<<<dim3(16, 1, 64), 256, 0, stream>>>(qkv, vt, Rb);
  gemm_bt<64, 64, 2, 2, EPI_RES><<<dim3(128, 8, 1), 256, 0, stream>>>(
      Rb, 512, 0, 0, woT, 512, 0, 0, 512, 0,
      xcur, 512, 0, 0, 0, bo, nullptr, nullptr, xcur, 2.f, 1.f);

  // ---- Conv module: x3 = 2 x2 + (W2 silu(BN(conv(glu(W1 ln(x2) + b1)))) + b2) ----
  ln_rows<0, 0><<<2048, 256, 0, stream>>>(xcur, cv_g, cv_b, nullptr, Rb);
  gemm_bt<128, 128, 2, 2, EPI_F32BIAS><<<dim3(64, 8, 1), 256, 0, stream>>>(
      Rb, 512, 0, 0, cw1b, 512, 0, 0, 512, 0,
      y1, 1024, 0, 0, 0, cv_b1, nullptr, nullptr, nullptr, 0.f, 0.f);
  (void)hipMemsetAsync(Rg, 0, (8L * 1056 + 2) * 512 * 2, stream);
  glu_kernel<<<4096, 256, 0, stream>>>(y1, Rg);
  (void)hipMemsetAsync(stats, 0, 1024 * sizeof(float), stream);
  conv_tap<<<512, 256, 0, stream>>>(Rg, wdP, parts);
  reduce_bn<<<512, 256, 0, stream>>>(parts, 8192L * 512, Rb, stats);
  bn_stats<<<2, 256, 0, stream>>>(stats, bn_g, bn_b);
  bn_silu<<<2048, 256, 0, stream>>>(Rb, stats, (short*)Rg);
  gemm_bt<64, 64, 2, 2, EPI_RES><<<dim3(128, 8, 1), 256, 0, stream>>>(
      (short*)Rg, 512, 0, 0, cw2b, 512, 0, 0, 512, 0,
      xcur, 512, 0, 0, 0, cv_b2, nullptr, nullptr, xcur, 2.f, 1.f);

  // ---- FF2: x4 = 1.5 x3 + 0.5 (...) ----
  ln_rows<0, 0><<<2048, 256, 0, stream>>>(xcur, ff2_g, ff2_b, nullptr, Rb);
  gemm_bt<128, 128, 2, 2, EPI_SILU><<<dim3(64, 16, 1), 256, 0, stream>>>(
      Rb, 512, 0, 0, ff2w1T, 512, 0, 0, 512, 0,
      hid, 2048, 0, 0, 0, ff2_b1, nullptr, nullptr, nullptr, 0.f, 0.f);
  gemm_bt<64, 64, 2, 2, EPI_RES><<<dim3(128, 8, 1), 256, 0, stream>>>(
      hid, 2048, 0, 0, ff2w2T, 2048, 0, 0, 2048, 0,
      xcur, 512, 0, 0, 0, ff2_b2, nullptr, nullptr, xcur, 1.5f, 0.5f);

  // ---- final LN -> d_out (fp32) ----
  ln_rows<0, 1><<<2048, 256, 0, stream>>>(xcur, fin_g, fin_b, nullptr, (float*)d_out);
}

// Round 18
// 498.223 us; speedup vs baseline: 1.1068x; 1.0197x over previous
//
#include <hip/hip_runtime.h>

// ---------------------------------------------------------------------------
// Conformer block, MI355X gfx950. Inputs/outputs fp32; internal activations
// bf16 with fp32 accumulation via bf16 MFMA 16x16x32.
// Round 18: (1) bf16 y1 (EPI_BBIAS) - 32MB fp32 round-trip removed;
// (2) halo-only zero kernel replaces 8.6MB glu_pad memset; (3) T5 setprio
// in gemm_bt MFMA cluster (counted-vmcnt structure has role diversity).
// Conv/flash frozen at round-17 state (conv 113us, MfmaUtil 54%).
// ---------------------------------------------------------------------------

typedef __attribute__((ext_vector_type(4))) float f32x4;
typedef __attribute__((ext_vector_type(8))) short short8;
typedef __attribute__((ext_vector_type(4))) short s16x4;

__device__ __forceinline__ float bfs2f(short s) {
  unsigned u = ((unsigned)(unsigned short)s) << 16;
  float f; __builtin_memcpy(&f, &u, 4); return f;
}
__device__ __forceinline__ short f2bfs(float f) {
  unsigned u; __builtin_memcpy(&u, &f, 4);
  u = (u + 0x7FFFu + ((u >> 16) & 1u)) >> 16;   // RNE
  return (short)u;
}
__device__ __forceinline__ float sigmoidf_(float x) { return 1.f / (1.f + __expf(-x)); }

#define GLOADLDS(gsrc, ldst) \
  __builtin_amdgcn_global_load_lds((__attribute__((address_space(1))) void*)(gsrc), \
                                   (__attribute__((address_space(3))) void*)(ldst), 16, 0, 0)

#define VMCNT_ASM(n) asm volatile("s_waitcnt vmcnt(" #n ")" ::: "memory")
template<int N> __device__ __forceinline__ void vmcnt_wait() {
  if      constexpr (N == 0)  VMCNT_ASM(0);
  else if constexpr (N == 2)  VMCNT_ASM(2);
  else if constexpr (N == 3)  VMCNT_ASM(3);
  else if constexpr (N == 4)  VMCNT_ASM(4);
  else if constexpr (N == 6)  VMCNT_ASM(6);
  else if constexpr (N == 8)  VMCNT_ASM(8);
  else                        VMCNT_ASM(0);
}
#define MEMFENCE asm volatile("" ::: "memory")

enum { EPI_SILU = 0, EPI_BBIAS = 1, EPI_RES = 2, EPI_QKV = 3, EPI_F32 = 6 };

// ---------------------------------------------------------------------------
// Generic GEMM: C[M,N] = A[M,K] * BT[N,K]^T, bf16 in, fp32 accum. BK=32.
// Triple-buffered; counted vmcnt(L) + RAW s_barrier. Last-z K decrement.
// ---------------------------------------------------------------------------
template<int BM, int BN, int WM, int WN, int EPI>
__global__ __launch_bounds__(256) void gemm_bt(
    const short* __restrict__ A, int lda, long zAh, long zAl,
    const short* __restrict__ BT, int ldbt, long zBh, long zBl,
    int K, int Kdec,
    void* C, int ldc, long zCh, long zCl, int zdiv,
    const float* bias, const float* bias2, const float* bias3,
    const float* resid, float alpha, float beta)
{
  constexpr int FM = BM / (WM * 16), FN = BN / (WN * 16);
  constexpr int AIT = (BM * 4) / 256, BIT = (BN * 4) / 256;
  constexpr int L = AIT + BIT;
  __shared__ short sA[3][BM * 32];
  __shared__ short sB[3][BN * 32];
  const int tid = threadIdx.x;
  const int zmask = (1 << zdiv) - 1;
  const int zhi = (int)(blockIdx.z >> zdiv);
  const int zlo = (int)(blockIdx.z & zmask);
  A  += (long)zhi * zAh + (long)zlo * zAl;
  BT += (long)zhi * zBh + (long)zlo * zBl;
  char* cbase = (char*)C + (long)zhi * zCh + (long)zlo * zCl;
  const int m0 = blockIdx.x * BM, n0 = blockIdx.y * BN;
  const int Keff = K - (zlo == zmask ? Kdec : 0);

  auto stage = [&](int buf, int k0) {
#pragma unroll
    for (int it = 0; it < AIT; ++it) {
      int idx = it * 256 + tid;
      GLOADLDS(A + (long)(m0 + (idx >> 2)) * lda + k0 + (idx & 3) * 8, &sA[buf][idx * 8]);
    }
#pragma unroll
    for (int it = 0; it < BIT; ++it) {
      int idx = it * 256 + tid;
      GLOADLDS(BT + (long)(n0 + (idx >> 2)) * ldbt + k0 + (idx & 3) * 8, &sB[buf][idx * 8]);
    }
  };

  f32x4 acc[FM][FN];
#pragma unroll
  for (int i = 0; i < FM; ++i) {
#pragma unroll
    for (int j = 0; j < FN; ++j) acc[i][j] = (f32x4){0.f, 0.f, 0.f, 0.f};
  }
  const int lane = tid & 63, wid = tid >> 6;
  const int wm = wid / WN, wn = wid % WN;
  const int lr = lane & 15, kg = lane >> 4;
  const int aRow = wm * (BM / WM), bRow = wn * (BN / WN);

  const int nt = Keff >> 5;
  stage(0, 0);
  stage(1, 32);
  vmcnt_wait<L>();
  __builtin_amdgcn_s_barrier();

  int cur = 0, sbuf = 2;
  for (int t = 0; t < nt; ++t) {
    const bool st = (t + 2 < nt);
    if (st) stage(sbuf, (t + 2) * 32);
    short8 af[FM], bfr[FN];
#pragma unroll
    for (int mi = 0; mi < FM; ++mi)
      af[mi] = *(const short8*)&sA[cur][(aRow + mi * 16 + lr) * 32 + kg * 8];
#pragma unroll
    for (int ni = 0; ni < FN; ++ni)
      bfr[ni] = *(const short8*)&sB[cur][(bRow + ni * 16 + lr) * 32 + kg * 8];
    __builtin_amdgcn_s_setprio(1);
#pragma unroll
    for (int mi = 0; mi < FM; ++mi) {
#pragma unroll
      for (int ni = 0; ni < FN; ++ni)
        acc[mi][ni] = __builtin_amdgcn_mfma_f32_16x16x32_bf16(af[mi], bfr[ni], acc[mi][ni], 0, 0, 0);
    }
    __builtin_amdgcn_s_setprio(0);
    if (st) vmcnt_wait<L>(); else vmcnt_wait<0>();
    __builtin_amdgcn_s_barrier();
    cur = (cur == 2) ? 0 : cur + 1;
    sbuf = (sbuf == 2) ? 0 : sbuf + 1;
  }

  const int baseRow = m0 + aRow, baseCol = n0 + bRow;
#pragma unroll
  for (int mi = 0; mi < FM; ++mi) {
#pragma unroll
    for (int ni = 0; ni < FN; ++ni) {
      const int col = baseCol + ni * 16 + lr;
#pragma unroll
      for (int r = 0; r < 4; ++r) {
        const int row = baseRow + mi * 16 + kg * 4 + r;
        float v = acc[mi][ni][r];
        if (EPI == EPI_SILU) {
          v += bias[col];
          v = v * sigmoidf_(v);
          ((short*)cbase)[(long)row * ldc + col] = f2bfs(v);
        } else if (EPI == EPI_BBIAS) {
          v += bias[col];
          ((short*)cbase)[(long)row * ldc + col] = f2bfs(v);
        } else if (EPI == EPI_RES) {
          v += bias[col];
          float rv = resid[(long)row * ldc + col];
          ((float*)cbase)[(long)row * ldc + col] = alpha * rv + beta * v;
        } else if (EPI == EPI_QKV) {
          if (col < 512)       v = (v + bias[col]) * 0.125f;   // fold 1/sqrt(64) into q
          else if (col < 1024) v += bias2[col - 512];
          else                 v += bias3[col - 1024];
          ((short*)cbase)[(long)row * ldc + col] = f2bfs(v);
        } else if (EPI == EPI_F32) {
          ((float*)cbase)[(long)row * ldc + col] = v;
        }
      }
    }
  }
}

// ---------------------------------------------------------------------------
// Conv, tap-tiled: per i-chunk (32 ch), stage 144-row glu slab in LDS once,
// run 16 taps against it. B weight-direct, ping-pong reg prefetch. 2-way
// split-K, XCD-pinned flat grid 512. bf16 partials. setprio on MFMA.
// ---------------------------------------------------------------------------
__global__ __launch_bounds__(256) void conv_tap(
    const short* __restrict__ glu,    // glu_pad base (b stride 1056*512)
    const short* __restrict__ wdP,    // [(e>>4)*512 + chunk][512]
    short* __restrict__ parts)        // bf16 partials, 2 copies
{
  __shared__ short sA[2][144 * 32];
  const int tid = threadIdx.x;
  const int bid = blockIdx.x;
  const int cc = bid & 7, j = bid >> 3;
  const int y = cc >> 1, kg = cc & 1;
  const int x = j & 7, b = j >> 3;
  const int m0 = x * 128, n0 = y * 128;
  const short* Arow0 = glu + ((long)b * 1056 + m0 + 1 + kg * 16) * 512;
  short* cbase = parts + (long)kg * (8192L * 512) + (long)b * (1024L * 512);

  const int lane = tid & 63, wid = tid >> 6;
  const int wm = wid >> 1, wn = wid & 1;
  const int lr = lane & 15, kgr = lane >> 4;
  const int aRow = wm * 64, bRow = wn * 64;

  const short* Bp = wdP + (long)((n0 + bRow) >> 4) * (512L * 512)
                  + (long)(kg * 256) * 512 + lane * 8;
  const long NSTR = 512L * 512;   // per-16e-rowtile stride

  auto stageA = [&](int buf, int ib) {
#pragma unroll
    for (int it = 0; it < 3; ++it) {
      int idx = it * 256 + tid;
      if (idx < 576) {
        GLOADLDS(Arow0 + (long)(idx >> 2) * 512 + ib * 32 + (idx & 3) * 8,
                 &sA[buf][idx * 8]);
      }
    }
  };

  f32x4 acc[4][4];
#pragma unroll
  for (int i = 0; i < 4; ++i) {
#pragma unroll
    for (int jj = 0; jj < 4; ++jj) acc[i][jj] = (f32x4){0.f, 0.f, 0.f, 0.f};
  }
  short8 b0[4], b1[4];

  stageA(0, 0);
  MEMFENCE;
#pragma unroll
  for (int ni = 0; ni < 4; ++ni)
    b0[ni] = *(const short8*)(Bp + ni * NSTR);
  MEMFENCE;
  vmcnt_wait<4>();              // stage(0) done; b0 may be in flight
  __builtin_amdgcn_s_barrier();

  int cur = 0;
  for (int ib = 0; ib < 16; ++ib) {
    if (ib + 1 < 16) stageA(cur ^ 1, ib + 1);
    MEMFENCE;
#pragma unroll
    for (int kk = 0; kk < 16; ++kk) {
      const long noff = (kk + 1 < 16) ? (long)((kk + 1) * 16 + ib) * 512
                                      : (long)(ib + 1) * 512;
      if ((kk & 1) == 0) {
#pragma unroll
        for (int ni = 0; ni < 4; ++ni)
          b1[ni] = *(const short8*)(Bp + noff + ni * NSTR);
      } else {
#pragma unroll
        for (int ni = 0; ni < 4; ++ni)
          b0[ni] = *(const short8*)(Bp + noff + ni * NSTR);
      }
      short8 af[4];
#pragma unroll
      for (int mi = 0; mi < 4; ++mi)
        af[mi] = *(const short8*)&sA[cur][(kk + aRow + mi * 16 + lr) * 32 + kgr * 8];
      __builtin_amdgcn_s_setprio(1);
      if ((kk & 1) == 0) {
#pragma unroll
        for (int mi = 0; mi < 4; ++mi) {
#pragma unroll
          for (int ni = 0; ni < 4; ++ni)
            acc[mi][ni] = __builtin_amdgcn_mfma_f32_16x16x32_bf16(af[mi], b0[ni], acc[mi][ni], 0, 0, 0);
        }
      } else {
#pragma unroll
        for (int mi = 0; mi < 4; ++mi) {
#pragma unroll
          for (int ni = 0; ni < 4; ++ni)
            acc[mi][ni] = __builtin_amdgcn_mfma_f32_16x16x32_bf16(af[mi], b1[ni], acc[mi][ni], 0, 0, 0);
        }
      }
      __builtin_amdgcn_s_setprio(0);
    }
    vmcnt_wait<4>();            // only newest 4 (unconsumed B prefetch) in flight
    __builtin_amdgcn_s_barrier();
    cur ^= 1;
  }
  vmcnt_wait<0>();

  const int baseRow = m0 + aRow, baseCol = n0 + bRow;
#pragma unroll
  for (int mi = 0; mi < 4; ++mi) {
#pragma unroll
    for (int ni = 0; ni < 4; ++ni) {
      const int col = baseCol + ni * 16 + lr;
#pragma unroll
      for (int r = 0; r < 4; ++r) {
        const int row = baseRow + mi * 16 + kgr * 4 + r;
        cbase[(long)row * 512 + col] = f2bfs(acc[mi][ni][r]);
      }
    }
  }
}

// ---------------------------------------------------------------------------
// Flash attention. Block = 64 q-rows of one (b,h); 4 waves. setprio on MFMA.
// ---------------------------------------------------------------------------
__global__ __launch_bounds__(256) void flash_attn(
    const short* __restrict__ qkv,   // [b][t][1536], q pre-scaled by 1/8
    const short* __restrict__ vt,    // [(b*8+h)][e=64][t=1024]
    short* __restrict__ out)         // scrambled: [b][n>>3][(n&7)*64+e]
{
  __shared__ short sQ[64 * 64];
  __shared__ short sK[64 * 64];
  __shared__ short sV[64 * 64];
  __shared__ short sP[4][16 * 64];
  const int tid = threadIdx.x;
  const int lane = tid & 63, w = tid >> 6;
  const int lr = lane & 15, kg = lane >> 4;
  const int bh = (int)blockIdx.z;
  const int b = bh >> 3, h = bh & 7;
  const int q0 = blockIdx.x * 64;
  const short* qbase = qkv + (long)b * 1024 * 1536 + h * 64;
  const short* kbase = qbase + 512;
  const short* vtb = vt + (long)bh * 65536;

#pragma unroll
  for (int it = 0; it < 2; ++it) {
    int idx = it * 256 + tid;
    int row = idx >> 3, c = (idx & 7) ^ (row & 7);
    GLOADLDS(qbase + (long)(q0 + row) * 1536 + c * 8, &sQ[idx * 8]);
  }
  __syncthreads();
  short8 bq[2];
#pragma unroll
  for (int ks = 0; ks < 2; ++ks)
    bq[ks] = *(const short8*)&sQ[(w * 16 + lr) * 64 + ((ks * 4 + kg) ^ (lr & 7)) * 8];

  f32x4 po[4];
#pragma unroll
  for (int mi = 0; mi < 4; ++mi) po[mi] = (f32x4){0.f, 0.f, 0.f, 0.f};
  float m = -3.0e38f, l = 0.f;

  for (int s0 = 0; s0 < 1024; s0 += 64) {
#pragma unroll
    for (int it = 0; it < 2; ++it) {
      int idx = it * 256 + tid;
      int row = idx >> 3, c = (idx & 7) ^ (row & 7);
      GLOADLDS(kbase + (long)(s0 + row) * 1536 + c * 8, &sK[idx * 8]);
    }
#pragma unroll
    for (int it = 0; it < 2; ++it) {
      int idx = it * 256 + tid;
      int row = idx >> 3, c = (idx & 7) ^ (row & 7);
      GLOADLDS(vtb + (long)row * 1024 + s0 + c * 8, &sV[idx * 8]);
    }
    __syncthreads();

    f32x4 as[4];
#pragma unroll
    for (int mi = 0; mi < 4; ++mi) as[mi] = (f32x4){0.f, 0.f, 0.f, 0.f};
    __builtin_amdgcn_s_setprio(1);
#pragma unroll
    for (int ks = 0; ks < 2; ++ks) {
#pragma unroll
      for (int mi = 0; mi < 4; ++mi) {
        short8 ak = *(const short8*)&sK[(mi * 16 + lr) * 64 + ((ks * 4 + kg) ^ (lr & 7)) * 8];
        as[mi] = __builtin_amdgcn_mfma_f32_16x16x32_bf16(ak, bq[ks], as[mi], 0, 0, 0);
      }
    }
    __builtin_amdgcn_s_setprio(0);

    float rmax = as[0][0];
#pragma unroll
    for (int mi = 0; mi < 4; ++mi) {
#pragma unroll
      for (int r = 0; r < 4; ++r) rmax = fmaxf(rmax, as[mi][r]);
    }
    rmax = fmaxf(rmax, __shfl_xor(rmax, 16));
    rmax = fmaxf(rmax, __shfl_xor(rmax, 32));
    const float mn = fmaxf(m, rmax);
    const float sc = __expf(m - mn);
    float p[4][4];
    float rsum = 0.f;
#pragma unroll
    for (int mi = 0; mi < 4; ++mi) {
#pragma unroll
      for (int r = 0; r < 4; ++r) { p[mi][r] = __expf(as[mi][r] - mn); rsum += p[mi][r]; }
    }
    rsum += __shfl_xor(rsum, 16);
    rsum += __shfl_xor(rsum, 32);
    l = l * sc + rsum;
    m = mn;
#pragma unroll
    for (int mi = 0; mi < 4; ++mi) {
#pragma unroll
      for (int r = 0; r < 4; ++r) po[mi][r] *= sc;
    }
#pragma unroll
    for (int mi = 0; mi < 4; ++mi) {
      s16x4 pk;
#pragma unroll
      for (int r = 0; r < 4; ++r) pk[r] = f2bfs(p[mi][r]);
      *(s16x4*)&sP[w][lr * 64 + ((mi ^ (lr & 3)) * 16 + kg * 4)] = pk;
    }
    __builtin_amdgcn_s_setprio(1);
#pragma unroll
    for (int ks = 0; ks < 2; ++ks) {
      short8 bp = *(const short8*)&sP[w][lr * 64 + (((ks * 2 + (kg >> 1)) ^ (lr & 3)) * 16 + (kg & 1) * 8)];
#pragma unroll
      for (int mi = 0; mi < 4; ++mi) {
        short8 av = *(const short8*)&sV[(mi * 16 + lr) * 64 + ((ks * 4 + kg) ^ (lr & 7)) * 8];
        po[mi] = __builtin_amdgcn_mfma_f32_16x16x32_bf16(av, bp, po[mi], 0, 0, 0);
      }
    }
    __builtin_amdgcn_s_setprio(0);
    __syncthreads();
  }

  const float inv = 1.f / l;
  const int t2 = q0 + w * 16 + lr;
  const int n = h * 1024 + t2;
  short* ob = out + ((long)b * 1024 + (n >> 3)) * 512 + (n & 7) * 64;
#pragma unroll
  for (int mi = 0; mi < 4; ++mi) {
    s16x4 o;
#pragma unroll
    for (int r = 0; r < 4; ++r) o[r] = f2bfs(po[mi][r] * inv);
    *(s16x4*)&ob[mi * 16 + kg * 4] = o;
  }
}

// ---------------------------------------------------------------------------
// Sum TWO bf16 conv partials -> z bf16, accumulate BN sum/sumsq stats.
// ---------------------------------------------------------------------------
__global__ __launch_bounds__(256) void reduce_bn(
    const short* __restrict__ parts, long pstride,
    short* __restrict__ z, float* stats)
{
  const int r0 = blockIdx.x * 16;
  const int c = threadIdx.x * 2;
  float s0 = 0.f, s1 = 0.f, q0 = 0.f, q1 = 0.f;
#pragma unroll 4
  for (int r = 0; r < 16; ++r) {
    const long idx = (long)(r0 + r) * 512 + c;
    int p0 = *(const int*)&parts[idx];
    int p1 = *(const int*)&parts[idx + pstride];
    float a0 = bfs2f((short)(p0 & 0xffff)) + bfs2f((short)(p1 & 0xffff));
    float a1 = bfs2f((short)(p0 >> 16)) + bfs2f((short)(p1 >> 16));
    int zo = ((int)(unsigned short)f2bfs(a0)) | (((int)(unsigned short)f2bfs(a1)) << 16);
    *(int*)&z[idx] = zo;
    s0 += a0; s1 += a1; q0 += a0 * a0; q1 += a1 * a1;
  }
  atomicAdd(&stats[c], s0);
  atomicAdd(&stats[c + 1], s1);
  atomicAdd(&stats[512 + c], q0);
  atomicAdd(&stats[512 + c + 1], q1);
}

// ---------------------------------------------------------------------------
// LayerNorm rows of 512 (fp32 in), one wave per row (4 rows/block).
// ---------------------------------------------------------------------------
template<int ADDPE, int OUTF32>
__global__ __launch_bounds__(256) void ln_rows(
    const float* __restrict__ X, const float* __restrict__ g, const float* __restrict__ b,
    const float* __restrict__ pe, void* __restrict__ Y)
{
  const int row = blockIdx.x * 4 + (threadIdx.x >> 6);
  const int lane = threadIdx.x & 63;
  const int c0 = lane * 8;
  const float* src = X + (long)row * 512 + c0;
  f32x4 a = *(const f32x4*)src, c = *(const f32x4*)(src + 4);
  float x[8] = {a[0], a[1], a[2], a[3], c[0], c[1], c[2], c[3]};
  float s = 0.f, q = 0.f;
#pragma unroll
  for (int j = 0; j < 8; ++j) { s += x[j]; q += x[j] * x[j]; }
#pragma unroll
  for (int off = 32; off > 0; off >>= 1) { s += __shfl_xor(s, off); q += __shfl_xor(q, off); }
  const float mean = s * (1.f / 512.f);
  const float var = q * (1.f / 512.f) - mean * mean;
  const float rstd = rsqrtf(var + 1e-5f);
  f32x4 g0 = *(const f32x4*)(g + c0), g1 = *(const f32x4*)(g + c0 + 4);
  f32x4 b0 = *(const f32x4*)(b + c0), b1 = *(const f32x4*)(b + c0 + 4);
  float gg[8] = {g0[0], g0[1], g0[2], g0[3], g1[0], g1[1], g1[2], g1[3]};
  float bb[8] = {b0[0], b0[1], b0[2], b0[3], b1[0], b1[1], b1[2], b1[3]};
  float y[8];
#pragma unroll
  for (int j = 0; j < 8; ++j) {
    y[j] = (x[j] - mean) * rstd * gg[j] + bb[j];
    if (ADDPE) y[j] += pe[(long)(row & 1023) * 512 + c0 + j];
  }
  if (OUTF32) {
    float* dst = (float*)Y + (long)row * 512 + c0;
    *(f32x4*)dst = (f32x4){y[0], y[1], y[2], y[3]};
    *(f32x4*)(dst + 4) = (f32x4){y[4], y[5], y[6], y[7]};
  } else {
    short8 o;
#pragma unroll
    for (int j = 0; j < 8; ++j) o[j] = f2bfs(y[j]);
    *(short8*)((short*)Y + (long)row * 512 + c0) = o;
  }
}

// ---------------------------------------------------------------------------
// 64x64-tile transpose -> bf16 out. INF32: fp32 input (weights) or bf16 input.
// ---------------------------------------------------------------------------
template<int INF32>
__global__ __launch_bounds__(256) void transpose64(
    const void* __restrict__ in_, int ldin, short* __restrict__ out, int ldout,
    int ctiles, int zshift, long zh_in, long zl_in, long z_out)
{
  __shared__ short t[64][72];
  const int z = blockIdx.z;
  const long inoff = (long)(z >> zshift) * zh_in + (long)(z & ((1 << zshift) - 1)) * zl_in;
  const int tr = blockIdx.x / ctiles, tc = blockIdx.x % ctiles;
  short* dst = out + (long)z * z_out + (long)(tc * 64) * ldout + tr * 64;
  const int tid = threadIdx.x;
#pragma unroll
  for (int p = 0; p < 2; ++p) {
    int idx = p * 256 + tid;
    int r = idx >> 3, c8 = (idx & 7) * 8;
    if (INF32) {
      const float* src = (const float*)in_ + inoff + (long)(tr * 64 + r) * ldin + tc * 64 + c8;
      f32x4 v0 = *(const f32x4*)src, v1 = *(const f32x4*)(src + 4);
#pragma unroll
      for (int j = 0; j < 4; ++j) { t[r][c8 + j] = f2bfs(v0[j]); t[r][c8 + 4 + j] = f2bfs(v1[j]); }
    } else {
      const short* src = (const short*)in_ + inoff + (long)(tr * 64 + r) * ldin + tc * 64 + c8;
      short8 v = *(const short8*)src;
#pragma unroll
      for (int j = 0; j < 8; ++j) t[r][c8 + j] = v[j];
    }
  }
  __syncthreads();
#pragma unroll
  for (int p = 0; p < 2; ++p) {
    int idx = p * 256 + tid;
    int c = idx >> 3, r8 = (idx & 7) * 8;
    short8 v;
#pragma unroll
    for (int j = 0; j < 8; ++j) v[j] = t[r8 + j][c];
    *(short8*)(dst + (long)c * ldout + r8) = v;
  }
}

// wdP fragment-packed, 32 taps; this kernel also zeroes tap 31 (no memset):
// value wd[e][i][KK] ->
// wdP[((e>>4)*512 + KK*16 + (i>>5))*512 + ((i>>3)&3)*128 + (e&15)*8 + (i&7)]
__global__ __launch_bounds__(256) void wd_pack(const float* __restrict__ wd, short* __restrict__ wdP)
{
  const int gid = blockIdx.x * 256 + threadIdx.x;  // 262144 = 512*512
  const int e = gid >> 9, i = gid & 511;
  const float* src = wd + ((long)e * 512 + i) * 31;
  const long rowtile = (long)(e >> 4) * (512L * 512);
  const int inner = ((i >> 3) & 3) * 128 + (e & 15) * 8 + (i & 7);
#pragma unroll
  for (int KK = 0; KK < 31; ++KK)
    wdP[rowtile + (long)(KK * 16 + (i >> 5)) * 512 + inner] = f2bfs(src[KK]);
  wdP[rowtile + (long)(31 * 16 + (i >> 5)) * 512 + inner] = 0;   // tap 31 zero
}

// pe[t][2p] = sin(t * 10000^(-p/256)), pe[t][2p+1] = cos(...)
__global__ __launch_bounds__(256) void pe_init(float* __restrict__ pe)
{
  const int gid = blockIdx.x * 256 + threadIdx.x;  // 262144 = 1024*256
  const int t = gid >> 8, p = gid & 255;
  const float freq = __expf(-(float)p * (9.210340371976184f / 256.f));
  const float ang = (float)t * freq;
  pe[(long)t * 512 + 2 * p]     = sinf(ang);
  pe[(long)t * 512 + 2 * p + 1] = cosf(ang);
}

// zero only the halo rows of glu_pad: rows 0-15 and 1040-1055 per batch,
// plus 2 slack rows at the very end. 16512 chunks of 8 shorts.
__global__ __launch_bounds__(256) void halo_zero(short* __restrict__ gp)
{
  const int gid = blockIdx.x * 256 + threadIdx.x;
  if (gid >= 16512) return;
  long row;
  int c8;
  if (gid < 16384) {
    const int b = gid >> 11;
    const int r = (gid >> 6) & 31;
    c8 = (gid & 63) * 8;
    row = (long)b * 1056 + ((r < 16) ? r : (1024 + r));   // 0-15, 1040-1055
  } else {
    const int k = gid - 16384;
    c8 = (k & 63) * 8;
    row = 8448 + (k >> 6);                                 // 2 slack rows
  }
  *(short8*)(gp + row * 512 + c8) = (short8){0, 0, 0, 0, 0, 0, 0, 0};
}

// glu = a * sigmoid(g) from y1[N][1024] bf16 -> glu_pad[b][16+t][512] bf16
__global__ __launch_bounds__(256) void glu_kernel(const short* __restrict__ y1, short* __restrict__ gp)
{
  const int gid = blockIdx.x * 256 + threadIdx.x;  // 1048576
  const int row = gid >> 7;
  const int ci = (gid & 127) * 4;
  const short* base = y1 + (long)row * 1024;
  s16x4 a = *(const s16x4*)(base + ci);
  s16x4 g = *(const s16x4*)(base + 512 + ci);
  const int b = row >> 10, t = row & 1023;
  s16x4 o;
#pragma unroll
  for (int j = 0; j < 4; ++j) o[j] = f2bfs(bfs2f(a[j]) * sigmoidf_(bfs2f(g[j])));
  *(s16x4*)(gp + ((long)b * 1056 + 16 + t) * 512 + ci) = o;
}

__global__ void bn_stats(float* stats, const float* __restrict__ bn_g, const float* __restrict__ bn_b)
{
  const int c = blockIdx.x * 256 + threadIdx.x;
  if (c < 512) {
    float mean = stats[c] * (1.f / 8192.f);
    float var = stats[512 + c] * (1.f / 8192.f) - mean * mean;
    float sc = bn_g[c] * rsqrtf(var + 1e-5f);
    stats[1024 + c] = sc;
    stats[1536 + c] = bn_b[c] - mean * sc;
  }
}

__global__ __launch_bounds__(256) void bn_silu(const short* __restrict__ z, const float* __restrict__ stats,
                                               short* __restrict__ out)
{
  const long base = ((long)blockIdx.x * 256 + threadIdx.x) * 8;
  const int c0 = (int)(base & 511);
  short8 v = *(const short8*)(z + base);
  short8 o;
#pragma unroll
  for (int j = 0; j < 8; ++j) {
    const int c = c0 + j;
    float y = bfs2f(v[j]) * stats[1024 + c] + stats[1536 + c];
    o[j] = f2bfs(y * sigmoidf_(y));
  }
  *(short8*)(out + base) = o;
}

// plain elementwise fp32 -> bf16 cast (grid-stride)
__global__ __launch_bounds__(256) void cast_bf16(const float* __restrict__ in, short* __restrict__ out, long n)
{
  for (long i = (long)blockIdx.x * 256 + threadIdx.x; i < n; i += (long)gridDim.x * 256)
    out[i] = f2bfs(in[i]);
}

// ---------------------------------------------------------------------------
extern "C" void kernel_launch(void* const* d_in, const int* in_sizes, int n_in,
                              void* d_out, int out_size, void* d_ws, size_t ws_size,
                              hipStream_t stream)
{
  (void)in_sizes; (void)n_in; (void)out_size; (void)ws_size;
  const float* x_in   = (const float*)d_in[0];
  const float* ff1_g  = (const float*)d_in[1];
  const float* ff1_bb = (const float*)d_in[2];
  const float* ff1_w1 = (const float*)d_in[3];
  const float* ff1_b1 = (const float*)d_in[4];
  const float* ff1_w2 = (const float*)d_in[5];
  const float* ff1_b2 = (const float*)d_in[6];
  const float* mha_g  = (const float*)d_in[7];
  const float* mha_b  = (const float*)d_in[8];
  const float* wq     = (const float*)d_in[9];
  const float* bq     = (const float*)d_in[10];
  const float* wk     = (const float*)d_in[11];
  const float* bk     = (const float*)d_in[12];
  const float* wv     = (const float*)d_in[13];
  const float* bv     = (const float*)d_in[14];
  const float* wo     = (const float*)d_in[15];
  const float* bo     = (const float*)d_in[16];
  const float* cv_g   = (const float*)d_in[17];
  const float* cv_b   = (const float*)d_in[18];
  const float* cv_w1  = (const float*)d_in[19];
  const float* cv_b1  = (const float*)d_in[20];
  const float* cv_wd  = (const float*)d_in[21];
  const float* bn_g   = (const float*)d_in[22];
  const float* bn_b   = (const float*)d_in[23];
  const float* cv_w2  = (const float*)d_in[24];
  const float* cv_b2  = (const float*)d_in[25];
  const float* ff2_g  = (const float*)d_in[26];
  const float* ff2_b  = (const float*)d_in[27];
  const float* ff2_w1 = (const float*)d_in[28];
  const float* ff2_b1 = (const float*)d_in[29];
  const float* ff2_w2 = (const float*)d_in[30];
  const float* ff2_b2 = (const float*)d_in[31];
  const float* fin_g  = (const float*)d_in[32];
  const float* fin_b  = (const float*)d_in[33];

  size_t off = 0;
  char* wsb = (char*)d_ws;
  auto take = [&](size_t n) { char* p = wsb + off; off += (n + 255) & ~(size_t)255; return p; };
  short* ff1w1T = (short*)take(2048L * 512 * 2);
  short* ff1w2T = (short*)take(512L * 2048 * 2);
  short* qkvT   = (short*)take(1536L * 512 * 2);
  short* woT    = (short*)take(512L * 512 * 2);
  short* cw1b   = (short*)take(1024L * 512 * 2);
  short* cw2b   = (short*)take(512L * 512 * 2);
  short* wdP    = (short*)take(32L * 512 * 512 * 2);   // 32 taps (tap 31 zero)
  short* ff2w1T = (short*)take(2048L * 512 * 2);
  short* ff2w2T = (short*)take(512L * 2048 * 2);
  float* xcur   = (float*)take(8192L * 512 * 4);
  char*  Ra     = take(8192L * 2048 * 2);              // hid bf16 / qkv bf16 / y1 bf16
  short* Rb     = (short*)take(8192L * 512 * 2);       // ln out / att_o / conv z
  short* Rg     = (short*)take((8L * 1056 + 2) * 512 * 2); // glu_pad (+slack rows)
  short* parts  = (short*)take(2L * 8192 * 512 * 2);   // conv partials x2 (bf16, 16MB)
  short* vt     = (short*)take(64L * 64 * 1024 * 2);   // V^T per (b,h)
  float* pe     = (float*)take(1024L * 512 * 4);
  float* stats  = (float*)take(2048L * 4);

  short* hid = (short*)Ra;
  short* qkv = (short*)Ra;
  short* y1  = (short*)Ra;

  // ---- weight packs (fp32 -> bf16; per call) ----
  transpose64<1><<<dim3(256, 1, 1), 256, 0, stream>>>(ff1_w1, 2048, ff1w1T, 512, 32, 0, 0, 0, 0);
  transpose64<1><<<dim3(256, 1, 1), 256, 0, stream>>>(ff1_w2, 512, ff1w2T, 2048, 8, 0, 0, 0, 0);
  transpose64<1><<<dim3(8, 1, 8), 256, 0, stream>>>(wq, 64, qkvT, 512, 1, 0, 32768, 0, 32768);
  transpose64<1><<<dim3(8, 1, 8), 256, 0, stream>>>(wk, 64, qkvT + 512 * 512, 512, 1, 0, 32768, 0, 32768);
  transpose64<1><<<dim3(8, 1, 8), 256, 0, stream>>>(wv, 64, qkvT + 1024 * 512, 512, 1, 0, 32768, 0, 32768);
  transpose64<1><<<dim3(64, 1, 1), 256, 0, stream>>>(wo, 512, woT, 512, 8, 0, 0, 0, 0);
  transpose64<1><<<dim3(256, 1, 1), 256, 0, stream>>>(ff2_w1, 2048, ff2w1T, 512, 32, 0, 0, 0, 0);
  transpose64<1><<<dim3(256, 1, 1), 256, 0, stream>>>(ff2_w2, 512, ff2w2T, 2048, 8, 0, 0, 0, 0);
  wd_pack<<<1024, 256, 0, stream>>>(cv_wd, wdP);
  pe_init<<<1024, 256, 0, stream>>>(pe);
  cast_bf16<<<2048, 256, 0, stream>>>(cv_w1, cw1b, 524288L);
  cast_bf16<<<1024, 256, 0, stream>>>(cv_w2, cw2b, 262144L);

  // ---- FF1: x1 = 1.5 x + 0.5 (silu(ln(x) W1 + b1) W2 + b2) ----
  ln_rows<0, 0><<<2048, 256, 0, stream>>>(x_in, ff1_g, ff1_bb, nullptr, Rb);
  gemm_bt<128, 128, 2, 2, EPI_SILU><<<dim3(64, 16, 1), 256, 0, stream>>>(
      Rb, 512, 0, 0, ff1w1T, 512, 0, 0, 512, 0,
      hid, 2048, 0, 0, 0, ff1_b1, nullptr, nullptr, nullptr, 0.f, 0.f);
  gemm_bt<64, 64, 2, 2, EPI_RES><<<dim3(128, 8, 1), 256, 0, stream>>>(
      hid, 2048, 0, 0, ff1w2T, 2048, 0, 0, 2048, 0,
      xcur, 512, 0, 0, 0, ff1_b2, nullptr, nullptr, x_in, 1.5f, 0.5f);

  // ---- MHSA: x2 = 2 x1 + (scramble(attn) Wo + bo) ----
  ln_rows<1, 0><<<2048, 256, 0, stream>>>(xcur, mha_g, mha_b, pe, Rb);
  gemm_bt<128, 128, 2, 2, EPI_QKV><<<dim3(64, 12, 1), 256, 0, stream>>>(
      Rb, 512, 0, 0, qkvT, 512, 0, 0, 512, 0,
      qkv, 1536, 0, 0, 0, bq, bk, bv, nullptr, 0.f, 0.f);
  transpose64<0><<<dim3(16, 1, 64), 256, 0, stream>>>(qkv + 1024, 1536, vt, 1024, 1, 3,
                                                      1024L * 1536, 64, 65536);
  flash_attn<<<dim3(16, 1, 64), 256, 0, stream>>>(qkv, vt, Rb);
  gemm_bt<64, 64, 2, 2, EPI_RES><<<dim3(128, 8, 1), 256, 0, stream>>>(
      Rb, 512, 0, 0, woT, 512, 0, 0, 512, 0,
      xcur, 512, 0, 0, 0, bo, nullptr, nullptr, xcur, 2.f, 1.f);

  // ---- Conv module: x3 = 2 x2 + (W2 silu(BN(conv(glu(W1 ln(x2) + b1)))) + b2) ----
  ln_rows<0, 0><<<2048, 256, 0, stream>>>(xcur, cv_g, cv_b, nullptr, Rb);
  gemm_bt<128, 128, 2, 2, EPI_BBIAS><<<dim3(64, 8, 1), 256, 0, stream>>>(
      Rb, 512, 0, 0, cw1b, 512, 0, 0, 512, 0,
      y1, 1024, 0, 0, 0, cv_b1, nullptr, nullptr, nullptr, 0.f, 0.f);
  halo_zero<<<65, 256, 0, stream>>>(Rg);
  glu_kernel<<<4096, 256, 0, stream>>>(y1, Rg);
  (void)hipMemsetAsync(stats, 0, 1024 * sizeof(float), stream);
  conv_tap<<<512, 256, 0, stream>>>(Rg, wdP, parts);
  reduce_bn<<<512, 256, 0, stream>>>(parts, 8192L * 512, Rb, stats);
  bn_stats<<<2, 256, 0, stream>>>(stats, bn_g, bn_b);
  bn_silu<<<2048, 256, 0, stream>>>(Rb, stats, (short*)Rg);
  gemm_bt<64, 64, 2, 2, EPI_RES><<<dim3(128, 8, 1), 256, 0, stream>>>(
      (short*)Rg, 512, 0, 0, cw2b, 512, 0, 0, 512, 0,
      xcur, 512, 0, 0, 0, cv_b2, nullptr, nullptr, xcur, 2.f, 1.f);

  // ---- FF2: x4 = 1.5 x3 + 0.5 (...) ----
  ln_rows<0, 0><<<2048, 256, 0, stream>>>(xcur, ff2_g, ff2_b, nullptr, Rb);
  gemm_bt<128, 128, 2, 2, EPI_SILU><<<dim3(64, 16, 1), 256, 0, stream>>>(
      Rb, 512, 0, 0, ff2w1T, 512, 0, 0, 512, 0,
      hid, 2048, 0, 0, 0, ff2_b1, nullptr, nullptr, nullptr, 0.f, 0.f);
  gemm_bt<64, 64, 2, 2, EPI_RES><<<dim3(128, 8, 1), 256, 0, stream>>>(
      hid, 2048, 0, 0, ff2w2T, 2048, 0, 0, 2048, 0,
      xcur, 512, 0, 0, 0, ff2_b2, nullptr, nullptr, xcur, 1.5f, 0.5f);

  // ---- final LN -> d_out (fp32) ----
  ln_rows<0, 1><<<2048, 256, 0, stream>>>(xcur, fin_g, fin_b, nullptr, (float*)d_out);
}

// Round 19
// 491.922 us; speedup vs baseline: 1.1210x; 1.0128x over previous
//
#include <hip/hip_runtime.h>

// ---------------------------------------------------------------------------
// Conformer block, MI355X gfx950. Inputs/outputs fp32; internal activations
// bf16 with fp32 accumulation via bf16 MFMA 16x16x32.
// Round 19: B-direct GEMM (gemm_bd) for the four N=512 residual GEMMs
// (ff1w2/ff2w2 K=2048, wo/cv_w2 K=512): B fragment-packed in global, loaded
// straight to regs (conv_tap's proven pattern); A-only LDS (ratio 1.0->0.25
// reads/MFMA). y=bid&3 pins each XCD to one 512KB B-slice. Accumulation
// order identical -> bitwise-same results. Rest frozen at round-18 state.
// ---------------------------------------------------------------------------

typedef __attribute__((ext_vector_type(4))) float f32x4;
typedef __attribute__((ext_vector_type(8))) short short8;
typedef __attribute__((ext_vector_type(4))) short s16x4;

__device__ __forceinline__ float bfs2f(short s) {
  unsigned u = ((unsigned)(unsigned short)s) << 16;
  float f; __builtin_memcpy(&f, &u, 4); return f;
}
__device__ __forceinline__ short f2bfs(float f) {
  unsigned u; __builtin_memcpy(&u, &f, 4);
  u = (u + 0x7FFFu + ((u >> 16) & 1u)) >> 16;   // RNE
  return (short)u;
}
__device__ __forceinline__ float sigmoidf_(float x) { return 1.f / (1.f + __expf(-x)); }

#define GLOADLDS(gsrc, ldst) \
  __builtin_amdgcn_global_load_lds((__attribute__((address_space(1))) void*)(gsrc), \
                                   (__attribute__((address_space(3))) void*)(ldst), 16, 0, 0)

#define VMCNT_ASM(n) asm volatile("s_waitcnt vmcnt(" #n ")" ::: "memory")
template<int N> __device__ __forceinline__ void vmcnt_wait() {
  if      constexpr (N == 0)  VMCNT_ASM(0);
  else if constexpr (N == 2)  VMCNT_ASM(2);
  else if constexpr (N == 3)  VMCNT_ASM(3);
  else if constexpr (N == 4)  VMCNT_ASM(4);
  else if constexpr (N == 5)  VMCNT_ASM(5);
  else if constexpr (N == 6)  VMCNT_ASM(6);
  else if constexpr (N == 8)  VMCNT_ASM(8);
  else                        VMCNT_ASM(0);
}
#define MEMFENCE asm volatile("" ::: "memory")

enum { EPI_SILU = 0, EPI_BBIAS = 1, EPI_RES = 2, EPI_QKV = 3, EPI_F32 = 6 };

// ---------------------------------------------------------------------------
// Generic GEMM: C[M,N] = A[M,K] * BT[N,K]^T, bf16 in, fp32 accum. BK=32.
// Triple-buffered; counted vmcnt(L) + RAW s_barrier. Last-z K decrement.
// ---------------------------------------------------------------------------
template<int BM, int BN, int WM, int WN, int EPI>
__global__ __launch_bounds__(256) void gemm_bt(
    const short* __restrict__ A, int lda, long zAh, long zAl,
    const short* __restrict__ BT, int ldbt, long zBh, long zBl,
    int K, int Kdec,
    void* C, int ldc, long zCh, long zCl, int zdiv,
    const float* bias, const float* bias2, const float* bias3,
    const float* resid, float alpha, float beta)
{
  constexpr int FM = BM / (WM * 16), FN = BN / (WN * 16);
  constexpr int AIT = (BM * 4) / 256, BIT = (BN * 4) / 256;
  constexpr int L = AIT + BIT;
  __shared__ short sA[3][BM * 32];
  __shared__ short sB[3][BN * 32];
  const int tid = threadIdx.x;
  const int zmask = (1 << zdiv) - 1;
  const int zhi = (int)(blockIdx.z >> zdiv);
  const int zlo = (int)(blockIdx.z & zmask);
  A  += (long)zhi * zAh + (long)zlo * zAl;
  BT += (long)zhi * zBh + (long)zlo * zBl;
  char* cbase = (char*)C + (long)zhi * zCh + (long)zlo * zCl;
  const int m0 = blockIdx.x * BM, n0 = blockIdx.y * BN;
  const int Keff = K - (zlo == zmask ? Kdec : 0);

  auto stage = [&](int buf, int k0) {
#pragma unroll
    for (int it = 0; it < AIT; ++it) {
      int idx = it * 256 + tid;
      GLOADLDS(A + (long)(m0 + (idx >> 2)) * lda + k0 + (idx & 3) * 8, &sA[buf][idx * 8]);
    }
#pragma unroll
    for (int it = 0; it < BIT; ++it) {
      int idx = it * 256 + tid;
      GLOADLDS(BT + (long)(n0 + (idx >> 2)) * ldbt + k0 + (idx & 3) * 8, &sB[buf][idx * 8]);
    }
  };

  f32x4 acc[FM][FN];
#pragma unroll
  for (int i = 0; i < FM; ++i) {
#pragma unroll
    for (int j = 0; j < FN; ++j) acc[i][j] = (f32x4){0.f, 0.f, 0.f, 0.f};
  }
  const int lane = tid & 63, wid = tid >> 6;
  const int wm = wid / WN, wn = wid % WN;
  const int lr = lane & 15, kg = lane >> 4;
  const int aRow = wm * (BM / WM), bRow = wn * (BN / WN);

  const int nt = Keff >> 5;
  stage(0, 0);
  stage(1, 32);
  vmcnt_wait<L>();
  __builtin_amdgcn_s_barrier();

  int cur = 0, sbuf = 2;
  for (int t = 0; t < nt; ++t) {
    const bool st = (t + 2 < nt);
    if (st) stage(sbuf, (t + 2) * 32);
    short8 af[FM], bfr[FN];
#pragma unroll
    for (int mi = 0; mi < FM; ++mi)
      af[mi] = *(const short8*)&sA[cur][(aRow + mi * 16 + lr) * 32 + kg * 8];
#pragma unroll
    for (int ni = 0; ni < FN; ++ni)
      bfr[ni] = *(const short8*)&sB[cur][(bRow + ni * 16 + lr) * 32 + kg * 8];
    __builtin_amdgcn_s_setprio(1);
#pragma unroll
    for (int mi = 0; mi < FM; ++mi) {
#pragma unroll
      for (int ni = 0; ni < FN; ++ni)
        acc[mi][ni] = __builtin_amdgcn_mfma_f32_16x16x32_bf16(af[mi], bfr[ni], acc[mi][ni], 0, 0, 0);
    }
    __builtin_amdgcn_s_setprio(0);
    if (st) vmcnt_wait<L>(); else vmcnt_wait<0>();
    __builtin_amdgcn_s_barrier();
    cur = (cur == 2) ? 0 : cur + 1;
    sbuf = (sbuf == 2) ? 0 : sbuf + 1;
  }

  const int baseRow = m0 + aRow, baseCol = n0 + bRow;
#pragma unroll
  for (int mi = 0; mi < FM; ++mi) {
#pragma unroll
    for (int ni = 0; ni < FN; ++ni) {
      const int col = baseCol + ni * 16 + lr;
#pragma unroll
      for (int r = 0; r < 4; ++r) {
        const int row = baseRow + mi * 16 + kg * 4 + r;
        float v = acc[mi][ni][r];
        if (EPI == EPI_SILU) {
          v += bias[col];
          v = v * sigmoidf_(v);
          ((short*)cbase)[(long)row * ldc + col] = f2bfs(v);
        } else if (EPI == EPI_BBIAS) {
          v += bias[col];
          ((short*)cbase)[(long)row * ldc + col] = f2bfs(v);
        } else if (EPI == EPI_RES) {
          v += bias[col];
          float rv = resid[(long)row * ldc + col];
          ((float*)cbase)[(long)row * ldc + col] = alpha * rv + beta * v;
        } else if (EPI == EPI_QKV) {
          if (col < 512)       v = (v + bias[col]) * 0.125f;   // fold 1/sqrt(64) into q
          else if (col < 1024) v += bias2[col - 512];
          else                 v += bias3[col - 1024];
          ((short*)cbase)[(long)row * ldc + col] = f2bfs(v);
        } else if (EPI == EPI_F32) {
          ((float*)cbase)[(long)row * ldc + col] = v;
        }
      }
    }
  }
}

// ---------------------------------------------------------------------------
// B-direct GEMM for N=512 residual outputs: C = alpha*resid + beta*(A.B^T+b).
// A [8192][K] bf16 staged in LDS (64-row tiles, triple buffer); B fragment-
// packed in global (wBP), loaded straight to regs with 1-step ping-pong.
// BM=64, BN=128, 4 waves of 32x64 (FM=2, FN=4): 2 LDS reads / 8 MFMA.
// Grid 512 flat: x=bid>>2, y=bid&3 -> each XCD pinned to one 512KB B-slice.
// NT = K/32 (even). Counted vmcnt(5) steady state.
// ---------------------------------------------------------------------------
template<int NT>
__global__ __launch_bounds__(256) void gemm_bd(
    const short* __restrict__ A,      // [8192][NT*32]
    const short* __restrict__ wBP,    // [(n>>4)*NT + (k>>5)][512] frag-packed
    const float* __restrict__ bias,
    const float* __restrict__ resid,
    float* __restrict__ C,
    float alpha, float beta)
{
  constexpr int K = NT * 32;
  __shared__ short sA[3][64 * 32];
  const int tid = threadIdx.x;
  const int x = (int)blockIdx.x >> 2, y = (int)blockIdx.x & 3;
  const int m0 = x * 64, n0 = y * 128;
  const int lane = tid & 63, wid = tid >> 6;
  const int wm = wid >> 1, wn = wid & 1;
  const int lr = lane & 15, kgr = lane >> 4;
  const int aRow = wm * 32, bRow = wn * 64;
  const long NSTR = (long)NT * 512;
  const short* Bp = wBP + (long)((n0 + bRow) >> 4) * NSTR + lane * 8;

  auto stageA = [&](int buf, int t) {
    GLOADLDS(A + (long)(m0 + (tid >> 2)) * K + t * 32 + (tid & 3) * 8, &sA[buf][tid * 8]);
  };

  f32x4 acc[2][4];
#pragma unroll
  for (int i = 0; i < 2; ++i) {
#pragma unroll
    for (int j = 0; j < 4; ++j) acc[i][j] = (f32x4){0.f, 0.f, 0.f, 0.f};
  }
  short8 b0[4], b1[4];

  stageA(0, 0);
  stageA(1, 1);
  MEMFENCE;
#pragma unroll
  for (int ni = 0; ni < 4; ++ni)
    b0[ni] = *(const short8*)(Bp + ni * NSTR);
  MEMFENCE;
  vmcnt_wait<5>();              // Ast(0) done; Ast(1)+b0 may be in flight
  __builtin_amdgcn_s_barrier();

  int rd = 0;
  for (int t = 0; t < NT; t += 2) {
    { // even phase: consume b0, prefetch B(t+1) -> b1, stage A(t+2)
      int wr = rd - 1; if (wr < 0) wr += 3;
      if (t + 2 < NT) stageA(wr, t + 2);
      MEMFENCE;
#pragma unroll
      for (int ni = 0; ni < 4; ++ni)
        b1[ni] = *(const short8*)(Bp + (long)(t + 1) * 512 + ni * NSTR);
      MEMFENCE;
      short8 af[2];
#pragma unroll
      for (int mi = 0; mi < 2; ++mi)
        af[mi] = *(const short8*)&sA[rd][(aRow + mi * 16 + lr) * 32 + kgr * 8];
      __builtin_amdgcn_s_setprio(1);
#pragma unroll
      for (int mi = 0; mi < 2; ++mi) {
#pragma unroll
        for (int ni = 0; ni < 4; ++ni)
          acc[mi][ni] = __builtin_amdgcn_mfma_f32_16x16x32_bf16(af[mi], b0[ni], acc[mi][ni], 0, 0, 0);
      }
      __builtin_amdgcn_s_setprio(0);
      if (t + 2 < NT) vmcnt_wait<5>(); else vmcnt_wait<4>();  // A(t+1) resident
      __builtin_amdgcn_s_barrier();
      rd = (rd == 2) ? 0 : rd + 1;
    }
    { // odd phase: consume b1, prefetch B(t+2) -> b0, stage A(t+3)
      int wr = rd - 1; if (wr < 0) wr += 3;
      if (t + 3 < NT) stageA(wr, t + 3);
      MEMFENCE;
      if (t + 2 < NT) {
#pragma unroll
        for (int ni = 0; ni < 4; ++ni)
          b0[ni] = *(const short8*)(Bp + (long)(t + 2) * 512 + ni * NSTR);
      }
      MEMFENCE;
      short8 af[2];
#pragma unroll
      for (int mi = 0; mi < 2; ++mi)
        af[mi] = *(const short8*)&sA[rd][(aRow + mi * 16 + lr) * 32 + kgr * 8];
      __builtin_amdgcn_s_setprio(1);
#pragma unroll
      for (int mi = 0; mi < 2; ++mi) {
#pragma unroll
        for (int ni = 0; ni < 4; ++ni)
          acc[mi][ni] = __builtin_amdgcn_mfma_f32_16x16x32_bf16(af[mi], b1[ni], acc[mi][ni], 0, 0, 0);
      }
      __builtin_amdgcn_s_setprio(0);
      if (t + 3 < NT) vmcnt_wait<5>(); else vmcnt_wait<0>();
      __builtin_amdgcn_s_barrier();
      rd = (rd == 2) ? 0 : rd + 1;
    }
  }

  const int baseRow = m0 + aRow, baseCol = n0 + bRow;
#pragma unroll
  for (int mi = 0; mi < 2; ++mi) {
#pragma unroll
    for (int ni = 0; ni < 4; ++ni) {
      const int col = baseCol + ni * 16 + lr;
#pragma unroll
      for (int r = 0; r < 4; ++r) {
        const int row = baseRow + mi * 16 + kgr * 4 + r;
        float v = acc[mi][ni][r] + bias[col];
        float rv = resid[(long)row * 512 + col];
        C[(long)row * 512 + col] = alpha * rv + beta * v;
      }
    }
  }
}

// ---------------------------------------------------------------------------
// Fragment-pack B^T[n][k] (N=512) from fp32 weights. TRANS: in is [K][512]
// (take in[k*512+n]); else in is [512][K] (take in[n*K+k]). KSHIFT=log2(K).
// dst[((n>>4)*(K/32) + (k>>5))*512 + ((k>>3)&3)*128 + (n&15)*8 + (k&7)]
// ---------------------------------------------------------------------------
template<int TRANS, int KSHIFT>
__global__ __launch_bounds__(256) void packB(const float* __restrict__ in, short* __restrict__ out)
{
  const int gid = blockIdx.x * 256 + threadIdx.x;
  const int n = gid >> KSHIFT;
  const int k = gid & ((1 << KSHIFT) - 1);
  const float v = TRANS ? in[(long)k * 512 + n] : in[((long)n << KSHIFT) | k];
  out[((long)((n >> 4) << (KSHIFT - 5)) + (k >> 5)) * 512 + ((k >> 3) & 3) * 128 + (n & 15) * 8 + (k & 7)] = f2bfs(v);
}

// ---------------------------------------------------------------------------
// Conv, tap-tiled: per i-chunk (32 ch), stage 144-row glu slab in LDS once,
// run 16 taps against it. B weight-direct, ping-pong reg prefetch. 2-way
// split-K, XCD-pinned flat grid 512. bf16 partials. setprio on MFMA.
// ---------------------------------------------------------------------------
__global__ __launch_bounds__(256) void conv_tap(
    const short* __restrict__ glu,    // glu_pad base (b stride 1056*512)
    const short* __restrict__ wdP,    // [(e>>4)*512 + chunk][512]
    short* __restrict__ parts)        // bf16 partials, 2 copies
{
  __shared__ short sA[2][144 * 32];
  const int tid = threadIdx.x;
  const int bid = blockIdx.x;
  const int cc = bid & 7, j = bid >> 3;
  const int y = cc >> 1, kg = cc & 1;
  const int x = j & 7, b = j >> 3;
  const int m0 = x * 128, n0 = y * 128;
  const short* Arow0 = glu + ((long)b * 1056 + m0 + 1 + kg * 16) * 512;
  short* cbase = parts + (long)kg * (8192L * 512) + (long)b * (1024L * 512);

  const int lane = tid & 63, wid = tid >> 6;
  const int wm = wid >> 1, wn = wid & 1;
  const int lr = lane & 15, kgr = lane >> 4;
  const int aRow = wm * 64, bRow = wn * 64;

  const short* Bp = wdP + (long)((n0 + bRow) >> 4) * (512L * 512)
                  + (long)(kg * 256) * 512 + lane * 8;
  const long NSTR = 512L * 512;   // per-16e-rowtile stride

  auto stageA = [&](int buf, int ib) {
#pragma unroll
    for (int it = 0; it < 3; ++it) {
      int idx = it * 256 + tid;
      if (idx < 576) {
        GLOADLDS(Arow0 + (long)(idx >> 2) * 512 + ib * 32 + (idx & 3) * 8,
                 &sA[buf][idx * 8]);
      }
    }
  };

  f32x4 acc[4][4];
#pragma unroll
  for (int i = 0; i < 4; ++i) {
#pragma unroll
    for (int jj = 0; jj < 4; ++jj) acc[i][jj] = (f32x4){0.f, 0.f, 0.f, 0.f};
  }
  short8 b0[4], b1[4];

  stageA(0, 0);
  MEMFENCE;
#pragma unroll
  for (int ni = 0; ni < 4; ++ni)
    b0[ni] = *(const short8*)(Bp + ni * NSTR);
  MEMFENCE;
  vmcnt_wait<4>();              // stage(0) done; b0 may be in flight
  __builtin_amdgcn_s_barrier();

  int cur = 0;
  for (int ib = 0; ib < 16; ++ib) {
    if (ib + 1 < 16) stageA(cur ^ 1, ib + 1);
    MEMFENCE;
#pragma unroll
    for (int kk = 0; kk < 16; ++kk) {
      const long noff = (kk + 1 < 16) ? (long)((kk + 1) * 16 + ib) * 512
                                      : (long)(ib + 1) * 512;
      if ((kk & 1) == 0) {
#pragma unroll
        for (int ni = 0; ni < 4; ++ni)
          b1[ni] = *(const short8*)(Bp + noff + ni * NSTR);
      } else {
#pragma unroll
        for (int ni = 0; ni < 4; ++ni)
          b0[ni] = *(const short8*)(Bp + noff + ni * NSTR);
      }
      short8 af[4];
#pragma unroll
      for (int mi = 0; mi < 4; ++mi)
        af[mi] = *(const short8*)&sA[cur][(kk + aRow + mi * 16 + lr) * 32 + kgr * 8];
      __builtin_amdgcn_s_setprio(1);
      if ((kk & 1) == 0) {
#pragma unroll
        for (int mi = 0; mi < 4; ++mi) {
#pragma unroll
          for (int ni = 0; ni < 4; ++ni)
            acc[mi][ni] = __builtin_amdgcn_mfma_f32_16x16x32_bf16(af[mi], b0[ni], acc[mi][ni], 0, 0, 0);
        }
      } else {
#pragma unroll
        for (int mi = 0; mi < 4; ++mi) {
#pragma unroll
          for (int ni = 0; ni < 4; ++ni)
            acc[mi][ni] = __builtin_amdgcn_mfma_f32_16x16x32_bf16(af[mi], b1[ni], acc[mi][ni], 0, 0, 0);
        }
      }
      __builtin_amdgcn_s_setprio(0);
    }
    vmcnt_wait<4>();            // only newest 4 (unconsumed B prefetch) in flight
    __builtin_amdgcn_s_barrier();
    cur ^= 1;
  }
  vmcnt_wait<0>();

  const int baseRow = m0 + aRow, baseCol = n0 + bRow;
#pragma unroll
  for (int mi = 0; mi < 4; ++mi) {
#pragma unroll
    for (int ni = 0; ni < 4; ++ni) {
      const int col = baseCol + ni * 16 + lr;
#pragma unroll
      for (int r = 0; r < 4; ++r) {
        const int row = baseRow + mi * 16 + kgr * 4 + r;
        cbase[(long)row * 512 + col] = f2bfs(acc[mi][ni][r]);
      }
    }
  }
}

// ---------------------------------------------------------------------------
// Flash attention. Block = 64 q-rows of one (b,h); 4 waves. setprio on MFMA.
// ---------------------------------------------------------------------------
__global__ __launch_bounds__(256) void flash_attn(
    const short* __restrict__ qkv,   // [b][t][1536], q pre-scaled by 1/8
    const short* __restrict__ vt,    // [(b*8+h)][e=64][t=1024]
    short* __restrict__ out)         // scrambled: [b][n>>3][(n&7)*64+e]
{
  __shared__ short sQ[64 * 64];
  __shared__ short sK[64 * 64];
  __shared__ short sV[64 * 64];
  __shared__ short sP[4][16 * 64];
  const int tid = threadIdx.x;
  const int lane = tid & 63, w = tid >> 6;
  const int lr = lane & 15, kg = lane >> 4;
  const int bh = (int)blockIdx.z;
  const int b = bh >> 3, h = bh & 7;
  const int q0 = blockIdx.x * 64;
  const short* qbase = qkv + (long)b * 1024 * 1536 + h * 64;
  const short* kbase = qbase + 512;
  const short* vtb = vt + (long)bh * 65536;

#pragma unroll
  for (int it = 0; it < 2; ++it) {
    int idx = it * 256 + tid;
    int row = idx >> 3, c = (idx & 7) ^ (row & 7);
    GLOADLDS(qbase + (long)(q0 + row) * 1536 + c * 8, &sQ[idx * 8]);
  }
  __syncthreads();
  short8 bq[2];
#pragma unroll
  for (int ks = 0; ks < 2; ++ks)
    bq[ks] = *(const short8*)&sQ[(w * 16 + lr) * 64 + ((ks * 4 + kg) ^ (lr & 7)) * 8];

  f32x4 po[4];
#pragma unroll
  for (int mi = 0; mi < 4; ++mi) po[mi] = (f32x4){0.f, 0.f, 0.f, 0.f};
  float m = -3.0e38f, l = 0.f;

  for (int s0 = 0; s0 < 1024; s0 += 64) {
#pragma unroll
    for (int it = 0; it < 2; ++it) {
      int idx = it * 256 + tid;
      int row = idx >> 3, c = (idx & 7) ^ (row & 7);
      GLOADLDS(kbase + (long)(s0 + row) * 1536 + c * 8, &sK[idx * 8]);
    }
#pragma unroll
    for (int it = 0; it < 2; ++it) {
      int idx = it * 256 + tid;
      int row = idx >> 3, c = (idx & 7) ^ (row & 7);
      GLOADLDS(vtb + (long)row * 1024 + s0 + c * 8, &sV[idx * 8]);
    }
    __syncthreads();

    f32x4 as[4];
#pragma unroll
    for (int mi = 0; mi < 4; ++mi) as[mi] = (f32x4){0.f, 0.f, 0.f, 0.f};
    __builtin_amdgcn_s_setprio(1);
#pragma unroll
    for (int ks = 0; ks < 2; ++ks) {
#pragma unroll
      for (int mi = 0; mi < 4; ++mi) {
        short8 ak = *(const short8*)&sK[(mi * 16 + lr) * 64 + ((ks * 4 + kg) ^ (lr & 7)) * 8];
        as[mi] = __builtin_amdgcn_mfma_f32_16x16x32_bf16(ak, bq[ks], as[mi], 0, 0, 0);
      }
    }
    __builtin_amdgcn_s_setprio(0);

    float rmax = as[0][0];
#pragma unroll
    for (int mi = 0; mi < 4; ++mi) {
#pragma unroll
      for (int r = 0; r < 4; ++r) rmax = fmaxf(rmax, as[mi][r]);
    }
    rmax = fmaxf(rmax, __shfl_xor(rmax, 16));
    rmax = fmaxf(rmax, __shfl_xor(rmax, 32));
    const float mn = fmaxf(m, rmax);
    const float sc = __expf(m - mn);
    float p[4][4];
    float rsum = 0.f;
#pragma unroll
    for (int mi = 0; mi < 4; ++mi) {
#pragma unroll
      for (int r = 0; r < 4; ++r) { p[mi][r] = __expf(as[mi][r] - mn); rsum += p[mi][r]; }
    }
    rsum += __shfl_xor(rsum, 16);
    rsum += __shfl_xor(rsum, 32);
    l = l * sc + rsum;
    m = mn;
#pragma unroll
    for (int mi = 0; mi < 4; ++mi) {
#pragma unroll
      for (int r = 0; r < 4; ++r) po[mi][r] *= sc;
    }
#pragma unroll
    for (int mi = 0; mi < 4; ++mi) {
      s16x4 pk;
#pragma unroll
      for (int r = 0; r < 4; ++r) pk[r] = f2bfs(p[mi][r]);
      *(s16x4*)&sP[w][lr * 64 + ((mi ^ (lr & 3)) * 16 + kg * 4)] = pk;
    }
    __builtin_amdgcn_s_setprio(1);
#pragma unroll
    for (int ks = 0; ks < 2; ++ks) {
      short8 bp = *(const short8*)&sP[w][lr * 64 + (((ks * 2 + (kg >> 1)) ^ (lr & 3)) * 16 + (kg & 1) * 8)];
#pragma unroll
      for (int mi = 0; mi < 4; ++mi) {
        short8 av = *(const short8*)&sV[(mi * 16 + lr) * 64 + ((ks * 4 + kg) ^ (lr & 7)) * 8];
        po[mi] = __builtin_amdgcn_mfma_f32_16x16x32_bf16(av, bp, po[mi], 0, 0, 0);
      }
    }
    __builtin_amdgcn_s_setprio(0);
    __syncthreads();
  }

  const float inv = 1.f / l;
  const int t2 = q0 + w * 16 + lr;
  const int n = h * 1024 + t2;
  short* ob = out + ((long)b * 1024 + (n >> 3)) * 512 + (n & 7) * 64;
#pragma unroll
  for (int mi = 0; mi < 4; ++mi) {
    s16x4 o;
#pragma unroll
    for (int r = 0; r < 4; ++r) o[r] = f2bfs(po[mi][r] * inv);
    *(s16x4*)&ob[mi * 16 + kg * 4] = o;
  }
}

// ---------------------------------------------------------------------------
// Sum TWO bf16 conv partials -> z bf16, accumulate BN sum/sumsq stats.
// ---------------------------------------------------------------------------
__global__ __launch_bounds__(256) void reduce_bn(
    const short* __restrict__ parts, long pstride,
    short* __restrict__ z, float* stats)
{
  const int r0 = blockIdx.x * 16;
  const int c = threadIdx.x * 2;
  float s0 = 0.f, s1 = 0.f, q0 = 0.f, q1 = 0.f;
#pragma unroll 4
  for (int r = 0; r < 16; ++r) {
    const long idx = (long)(r0 + r) * 512 + c;
    int p0 = *(const int*)&parts[idx];
    int p1 = *(const int*)&parts[idx + pstride];
    float a0 = bfs2f((short)(p0 & 0xffff)) + bfs2f((short)(p1 & 0xffff));
    float a1 = bfs2f((short)(p0 >> 16)) + bfs2f((short)(p1 >> 16));
    int zo = ((int)(unsigned short)f2bfs(a0)) | (((int)(unsigned short)f2bfs(a1)) << 16);
    *(int*)&z[idx] = zo;
    s0 += a0; s1 += a1; q0 += a0 * a0; q1 += a1 * a1;
  }
  atomicAdd(&stats[c], s0);
  atomicAdd(&stats[c + 1], s1);
  atomicAdd(&stats[512 + c], q0);
  atomicAdd(&stats[512 + c + 1], q1);
}

// ---------------------------------------------------------------------------
// LayerNorm rows of 512 (fp32 in), one wave per row (4 rows/block).
// ---------------------------------------------------------------------------
template<int ADDPE, int OUTF32>
__global__ __launch_bounds__(256) void ln_rows(
    const float* __restrict__ X, const float* __restrict__ g, const float* __restrict__ b,
    const float* __restrict__ pe, void* __restrict__ Y)
{
  const int row = blockIdx.x * 4 + (threadIdx.x >> 6);
  const int lane = threadIdx.x & 63;
  const int c0 = lane * 8;
  const float* src = X + (long)row * 512 + c0;
  f32x4 a = *(const f32x4*)src, c = *(const f32x4*)(src + 4);
  float x[8] = {a[0], a[1], a[2], a[3], c[0], c[1], c[2], c[3]};
  float s = 0.f, q = 0.f;
#pragma unroll
  for (int j = 0; j < 8; ++j) { s += x[j]; q += x[j] * x[j]; }
#pragma unroll
  for (int off = 32; off > 0; off >>= 1) { s += __shfl_xor(s, off); q += __shfl_xor(q, off); }
  const float mean = s * (1.f / 512.f);
  const float var = q * (1.f / 512.f) - mean * mean;
  const float rstd = rsqrtf(var + 1e-5f);
  f32x4 g0 = *(const f32x4*)(g + c0), g1 = *(const f32x4*)(g + c0 + 4);
  f32x4 b0 = *(const f32x4*)(b + c0), b1 = *(const f32x4*)(b + c0 + 4);
  float gg[8] = {g0[0], g0[1], g0[2], g0[3], g1[0], g1[1], g1[2], g1[3]};
  float bb[8] = {b0[0], b0[1], b0[2], b0[3], b1[0], b1[1], b1[2], b1[3]};
  float y[8];
#pragma unroll
  for (int j = 0; j < 8; ++j) {
    y[j] = (x[j] - mean) * rstd * gg[j] + bb[j];
    if (ADDPE) y[j] += pe[(long)(row & 1023) * 512 + c0 + j];
  }
  if (OUTF32) {
    float* dst = (float*)Y + (long)row * 512 + c0;
    *(f32x4*)dst = (f32x4){y[0], y[1], y[2], y[3]};
    *(f32x4*)(dst + 4) = (f32x4){y[4], y[5], y[6], y[7]};
  } else {
    short8 o;
#pragma unroll
    for (int j = 0; j < 8; ++j) o[j] = f2bfs(y[j]);
    *(short8*)((short*)Y + (long)row * 512 + c0) = o;
  }
}

// ---------------------------------------------------------------------------
// 64x64-tile transpose -> bf16 out. INF32: fp32 input (weights) or bf16 input.
// ---------------------------------------------------------------------------
template<int INF32>
__global__ __launch_bounds__(256) void transpose64(
    const void* __restrict__ in_, int ldin, short* __restrict__ out, int ldout,
    int ctiles, int zshift, long zh_in, long zl_in, long z_out)
{
  __shared__ short t[64][72];
  const int z = blockIdx.z;
  const long inoff = (long)(z >> zshift) * zh_in + (long)(z & ((1 << zshift) - 1)) * zl_in;
  const int tr = blockIdx.x / ctiles, tc = blockIdx.x % ctiles;
  short* dst = out + (long)z * z_out + (long)(tc * 64) * ldout + tr * 64;
  const int tid = threadIdx.x;
#pragma unroll
  for (int p = 0; p < 2; ++p) {
    int idx = p * 256 + tid;
    int r = idx >> 3, c8 = (idx & 7) * 8;
    if (INF32) {
      const float* src = (const float*)in_ + inoff + (long)(tr * 64 + r) * ldin + tc * 64 + c8;
      f32x4 v0 = *(const f32x4*)src, v1 = *(const f32x4*)(src + 4);
#pragma unroll
      for (int j = 0; j < 4; ++j) { t[r][c8 + j] = f2bfs(v0[j]); t[r][c8 + 4 + j] = f2bfs(v1[j]); }
    } else {
      const short* src = (const short*)in_ + inoff + (long)(tr * 64 + r) * ldin + tc * 64 + c8;
      short8 v = *(const short8*)src;
#pragma unroll
      for (int j = 0; j < 8; ++j) t[r][c8 + j] = v[j];
    }
  }
  __syncthreads();
#pragma unroll
  for (int p = 0; p < 2; ++p) {
    int idx = p * 256 + tid;
    int c = idx >> 3, r8 = (idx & 7) * 8;
    short8 v;
#pragma unroll
    for (int j = 0; j < 8; ++j) v[j] = t[r8 + j][c];
    *(short8*)(dst + (long)c * ldout + r8) = v;
  }
}

// wdP fragment-packed, 32 taps; this kernel also zeroes tap 31 (no memset):
// value wd[e][i][KK] ->
// wdP[((e>>4)*512 + KK*16 + (i>>5))*512 + ((i>>3)&3)*128 + (e&15)*8 + (i&7)]
__global__ __launch_bounds__(256) void wd_pack(const float* __restrict__ wd, short* __restrict__ wdP)
{
  const int gid = blockIdx.x * 256 + threadIdx.x;  // 262144 = 512*512
  const int e = gid >> 9, i = gid & 511;
  const float* src = wd + ((long)e * 512 + i) * 31;
  const long rowtile = (long)(e >> 4) * (512L * 512);
  const int inner = ((i >> 3) & 3) * 128 + (e & 15) * 8 + (i & 7);
#pragma unroll
  for (int KK = 0; KK < 31; ++KK)
    wdP[rowtile + (long)(KK * 16 + (i >> 5)) * 512 + inner] = f2bfs(src[KK]);
  wdP[rowtile + (long)(31 * 16 + (i >> 5)) * 512 + inner] = 0;   // tap 31 zero
}

// pe[t][2p] = sin(t * 10000^(-p/256)), pe[t][2p+1] = cos(...)
__global__ __launch_bounds__(256) void pe_init(float* __restrict__ pe)
{
  const int gid = blockIdx.x * 256 + threadIdx.x;  // 262144 = 1024*256
  const int t = gid >> 8, p = gid & 255;
  const float freq = __expf(-(float)p * (9.210340371976184f / 256.f));
  const float ang = (float)t * freq;
  pe[(long)t * 512 + 2 * p]     = sinf(ang);
  pe[(long)t * 512 + 2 * p + 1] = cosf(ang);
}

// zero only the halo rows of glu_pad: rows 0-15 and 1040-1055 per batch,
// plus 2 slack rows at the very end. 16512 chunks of 8 shorts.
__global__ __launch_bounds__(256) void halo_zero(short* __restrict__ gp)
{
  const int gid = blockIdx.x * 256 + threadIdx.x;
  if (gid >= 16512) return;
  long row;
  int c8;
  if (gid < 16384) {
    const int b = gid >> 11;
    const int r = (gid >> 6) & 31;
    c8 = (gid & 63) * 8;
    row = (long)b * 1056 + ((r < 16) ? r : (1024 + r));   // 0-15, 1040-1055
  } else {
    const int k = gid - 16384;
    c8 = (k & 63) * 8;
    row = 8448 + (k >> 6);                                 // 2 slack rows
  }
  *(short8*)(gp + row * 512 + c8) = (short8){0, 0, 0, 0, 0, 0, 0, 0};
}

// glu = a * sigmoid(g) from y1[N][1024] bf16 -> glu_pad[b][16+t][512] bf16
__global__ __launch_bounds__(256) void glu_kernel(const short* __restrict__ y1, short* __restrict__ gp)
{
  const int gid = blockIdx.x * 256 + threadIdx.x;  // 1048576
  const int row = gid >> 7;
  const int ci = (gid & 127) * 4;
  const short* base = y1 + (long)row * 1024;
  s16x4 a = *(const s16x4*)(base + ci);
  s16x4 g = *(const s16x4*)(base + 512 + ci);
  const int b = row >> 10, t = row & 1023;
  s16x4 o;
#pragma unroll
  for (int j = 0; j < 4; ++j) o[j] = f2bfs(bfs2f(a[j]) * sigmoidf_(bfs2f(g[j])));
  *(s16x4*)(gp + ((long)b * 1056 + 16 + t) * 512 + ci) = o;
}

__global__ void bn_stats(float* stats, const float* __restrict__ bn_g, const float* __restrict__ bn_b)
{
  const int c = blockIdx.x * 256 + threadIdx.x;
  if (c < 512) {
    float mean = stats[c] * (1.f / 8192.f);
    float var = stats[512 + c] * (1.f / 8192.f) - mean * mean;
    float sc = bn_g[c] * rsqrtf(var + 1e-5f);
    stats[1024 + c] = sc;
    stats[1536 + c] = bn_b[c] - mean * sc;
  }
}

__global__ __launch_bounds__(256) void bn_silu(const short* __restrict__ z, const float* __restrict__ stats,
                                               short* __restrict__ out)
{
  const long base = ((long)blockIdx.x * 256 + threadIdx.x) * 8;
  const int c0 = (int)(base & 511);
  short8 v = *(const short8*)(z + base);
  short8 o;
#pragma unroll
  for (int j = 0; j < 8; ++j) {
    const int c = c0 + j;
    float y = bfs2f(v[j]) * stats[1024 + c] + stats[1536 + c];
    o[j] = f2bfs(y * sigmoidf_(y));
  }
  *(short8*)(out + base) = o;
}

// plain elementwise fp32 -> bf16 cast (grid-stride)
__global__ __launch_bounds__(256) void cast_bf16(const float* __restrict__ in, short* __restrict__ out, long n)
{
  for (long i = (long)blockIdx.x * 256 + threadIdx.x; i < n; i += (long)gridDim.x * 256)
    out[i] = f2bfs(in[i]);
}

// ---------------------------------------------------------------------------
extern "C" void kernel_launch(void* const* d_in, const int* in_sizes, int n_in,
                              void* d_out, int out_size, void* d_ws, size_t ws_size,
                              hipStream_t stream)
{
  (void)in_sizes; (void)n_in; (void)out_size; (void)ws_size;
  const float* x_in   = (const float*)d_in[0];
  const float* ff1_g  = (const float*)d_in[1];
  const float* ff1_bb = (const float*)d_in[2];
  const float* ff1_w1 = (const float*)d_in[3];
  const float* ff1_b1 = (const float*)d_in[4];
  const float* ff1_w2 = (const float*)d_in[5];
  const float* ff1_b2 = (const float*)d_in[6];
  const float* mha_g  = (const float*)d_in[7];
  const float* mha_b  = (const float*)d_in[8];
  const float* wq     = (const float*)d_in[9];
  const float* bq     = (const float*)d_in[10];
  const float* wk     = (const float*)d_in[11];
  const float* bk     = (const float*)d_in[12];
  const float* wv     = (const float*)d_in[13];
  const float* bv     = (const float*)d_in[14];
  const float* wo     = (const float*)d_in[15];
  const float* bo     = (const float*)d_in[16];
  const float* cv_g   = (const float*)d_in[17];
  const float* cv_b   = (const float*)d_in[18];
  const float* cv_w1  = (const float*)d_in[19];
  const float* cv_b1  = (const float*)d_in[20];
  const float* cv_wd  = (const float*)d_in[21];
  const float* bn_g   = (const float*)d_in[22];
  const float* bn_b   = (const float*)d_in[23];
  const float* cv_w2  = (const float*)d_in[24];
  const float* cv_b2  = (const float*)d_in[25];
  const float* ff2_g  = (const float*)d_in[26];
  const float* ff2_b  = (const float*)d_in[27];
  const float* ff2_w1 = (const float*)d_in[28];
  const float* ff2_b1 = (const float*)d_in[29];
  const float* ff2_w2 = (const float*)d_in[30];
  const float* ff2_b2 = (const float*)d_in[31];
  const float* fin_g  = (const float*)d_in[32];
  const float* fin_b  = (const float*)d_in[33];

  size_t off = 0;
  char* wsb = (char*)d_ws;
  auto take = [&](size_t n) { char* p = wsb + off; off += (n + 255) & ~(size_t)255; return p; };
  short* ff1w1T = (short*)take(2048L * 512 * 2);
  short* ff1w2P = (short*)take(2048L * 512 * 2);   // fragment-packed
  short* qkvT   = (short*)take(1536L * 512 * 2);
  short* woP    = (short*)take(512L * 512 * 2);    // fragment-packed
  short* cw1b   = (short*)take(1024L * 512 * 2);
  short* cw2P   = (short*)take(512L * 512 * 2);    // fragment-packed
  short* wdP    = (short*)take(32L * 512 * 512 * 2);   // 32 taps (tap 31 zero)
  short* ff2w1T = (short*)take(2048L * 512 * 2);
  short* ff2w2P = (short*)take(2048L * 512 * 2);   // fragment-packed
  float* xcur   = (float*)take(8192L * 512 * 4);
  char*  Ra     = take(8192L * 2048 * 2);              // hid bf16 / qkv bf16 / y1 bf16
  short* Rb     = (short*)take(8192L * 512 * 2);       // ln out / att_o / conv z
  short* Rg     = (short*)take((8L * 1056 + 2) * 512 * 2); // glu_pad (+slack rows)
  short* parts  = (short*)take(2L * 8192 * 512 * 2);   // conv partials x2 (bf16, 16MB)
  short* vt     = (short*)take(64L * 64 * 1024 * 2);   // V^T per (b,h)
  float* pe     = (float*)take(1024L * 512 * 4);
  float* stats  = (float*)take(2048L * 4);

  short* hid = (short*)Ra;
  short* qkv = (short*)Ra;
  short* y1  = (short*)Ra;

  // ---- weight packs (fp32 -> bf16; per call) ----
  transpose64<1><<<dim3(256, 1, 1), 256, 0, stream>>>(ff1_w1, 2048, ff1w1T, 512, 32, 0, 0, 0, 0);
  packB<1, 11><<<4096, 256, 0, stream>>>(ff1_w2, ff1w2P);
  transpose64<1><<<dim3(8, 1, 8), 256, 0, stream>>>(wq, 64, qkvT, 512, 1, 0, 32768, 0, 32768);
  transpose64<1><<<dim3(8, 1, 8), 256, 0, stream>>>(wk, 64, qkvT + 512 * 512, 512, 1, 0, 32768, 0, 32768);
  transpose64<1><<<dim3(8, 1, 8), 256, 0, stream>>>(wv, 64, qkvT + 1024 * 512, 512, 1, 0, 32768, 0, 32768);
  packB<1, 9><<<1024, 256, 0, stream>>>(wo, woP);
  transpose64<1><<<dim3(256, 1, 1), 256, 0, stream>>>(ff2_w1, 2048, ff2w1T, 512, 32, 0, 0, 0, 0);
  packB<1, 11><<<4096, 256, 0, stream>>>(ff2_w2, ff2w2P);
  packB<0, 9><<<1024, 256, 0, stream>>>(cv_w2, cw2P);
  wd_pack<<<1024, 256, 0, stream>>>(cv_wd, wdP);
  pe_init<<<1024, 256, 0, stream>>>(pe);
  cast_bf16<<<2048, 256, 0, stream>>>(cv_w1, cw1b, 524288L);

  // ---- FF1: x1 = 1.5 x + 0.5 (silu(ln(x) W1 + b1) W2 + b2) ----
  ln_rows<0, 0><<<2048, 256, 0, stream>>>(x_in, ff1_g, ff1_bb, nullptr, Rb);
  gemm_bt<128, 128, 2, 2, EPI_SILU><<<dim3(64, 16, 1), 256, 0, stream>>>(
      Rb, 512, 0, 0, ff1w1T, 512, 0, 0, 512, 0,
      hid, 2048, 0, 0, 0, ff1_b1, nullptr, nullptr, nullptr, 0.f, 0.f);
  gemm_bd<64><<<512, 256, 0, stream>>>(hid, ff1w2P, ff1_b2, x_in, xcur, 1.5f, 0.5f);

  // ---- MHSA: x2 = 2 x1 + (scramble(attn) Wo + bo) ----
  ln_rows<1, 0><<<2048, 256, 0, stream>>>(xcur, mha_g, mha_b, pe, Rb);
  gemm_bt<128, 128, 2, 2, EPI_QKV><<<dim3(64, 12, 1), 256, 0, stream>>>(
      Rb, 512, 0, 0, qkvT, 512, 0, 0, 512, 0,
      qkv, 1536, 0, 0, 0, bq, bk, bv, nullptr, 0.f, 0.f);
  transpose64<0><<<dim3(16, 1, 64), 256, 0, stream>>>(qkv + 1024, 1536, vt, 1024, 1, 3,
                                                      1024L * 1536, 64, 65536);
  flash_attn<<<dim3(16, 1, 64), 256, 0, stream>>>(qkv, vt, Rb);
  gemm_bd<16><<<512, 256, 0, stream>>>(Rb, woP, bo, xcur, xcur, 2.f, 1.f);

  // ---- Conv module: x3 = 2 x2 + (W2 silu(BN(conv(glu(W1 ln(x2) + b1)))) + b2) ----
  ln_rows<0, 0><<<2048, 256, 0, stream>>>(xcur, cv_g, cv_b, nullptr, Rb);
  gemm_bt<128, 128, 2, 2, EPI_BBIAS><<<dim3(64, 8, 1), 256, 0, stream>>>(
      Rb, 512, 0, 0, cw1b, 512, 0, 0, 512, 0,
      y1, 1024, 0, 0, 0, cv_b1, nullptr, nullptr, nullptr, 0.f, 0.f);
  halo_zero<<<65, 256, 0, stream>>>(Rg);
  glu_kernel<<<4096, 256, 0, stream>>>(y1, Rg);
  (void)hipMemsetAsync(stats, 0, 1024 * sizeof(float), stream);
  conv_tap<<<512, 256, 0, stream>>>(Rg, wdP, parts);
  reduce_bn<<<512, 256, 0, stream>>>(parts, 8192L * 512, Rb, stats);
  bn_stats<<<2, 256, 0, stream>>>(stats, bn_g, bn_b);
  bn_silu<<<2048, 256, 0, stream>>>(Rb, stats, (short*)Rg);
  gemm_bd<16><<<512, 256, 0, stream>>>((short*)Rg, cw2P, cv_b2, xcur, xcur, 2.f, 1.f);

  // ---- FF2: x4 = 1.5 x3 + 0.5 (...) ----
  ln_rows<0, 0><<<2048, 256, 0, stream>>>(xcur, ff2_g, ff2_b, nullptr, Rb);
  gemm_bt<128, 128, 2, 2, EPI_SILU><<<dim3(64, 16, 1), 256, 0, stream>>>(
      Rb, 512, 0, 0, ff2w1T, 512, 0, 0, 512, 0,
      hid, 2048, 0, 0, 0, ff2_b1, nullptr, nullptr, nullptr, 0.f, 0.f);
  gemm_bd<64><<<512, 256, 0, stream>>>(hid, ff2w2P, ff2_b2, xcur, xcur, 1.5f, 0.5f);

  // ---- final LN -> d_out (fp32) ----
  ln_rows<0, 1><<<2048, 256, 0, stream>>>(xcur, fin_g, fin_b, nullptr, (float*)d_out);
}

// Round 20
// 479.932 us; speedup vs baseline: 1.1490x; 1.0250x over previous
//
#include <hip/hip_runtime.h>

// ---------------------------------------------------------------------------
// Conformer block, MI355X gfx950. Inputs/outputs fp32; internal activations
// bf16 with fp32 accumulation via bf16 MFMA 16x16x32.
// Round 20: B-direct wide GEMM (gemm_bdw = conv_tap structure minus taps)
// replaces gemm_bt for ALL remaining K=512 GEMMs (FF W1 x2, QKV, cv_w1):
// A-only LDS (ratio 0.25 reads/MFMA), B frag-packed direct to regs, counted
// vmcnt(6), setprio. gemm_bt retired. Bitwise-identical accumulation order.
// ---------------------------------------------------------------------------

typedef __attribute__((ext_vector_type(4))) float f32x4;
typedef __attribute__((ext_vector_type(8))) short short8;
typedef __attribute__((ext_vector_type(4))) short s16x4;

__device__ __forceinline__ float bfs2f(short s) {
  unsigned u = ((unsigned)(unsigned short)s) << 16;
  float f; __builtin_memcpy(&f, &u, 4); return f;
}
__device__ __forceinline__ short f2bfs(float f) {
  unsigned u; __builtin_memcpy(&u, &f, 4);
  u = (u + 0x7FFFu + ((u >> 16) & 1u)) >> 16;   // RNE
  return (short)u;
}
__device__ __forceinline__ float sigmoidf_(float x) { return 1.f / (1.f + __expf(-x)); }

#define GLOADLDS(gsrc, ldst) \
  __builtin_amdgcn_global_load_lds((__attribute__((address_space(1))) void*)(gsrc), \
                                   (__attribute__((address_space(3))) void*)(ldst), 16, 0, 0)

#define VMCNT_ASM(n) asm volatile("s_waitcnt vmcnt(" #n ")" ::: "memory")
template<int N> __device__ __forceinline__ void vmcnt_wait() {
  if      constexpr (N == 0)  VMCNT_ASM(0);
  else if constexpr (N == 2)  VMCNT_ASM(2);
  else if constexpr (N == 3)  VMCNT_ASM(3);
  else if constexpr (N == 4)  VMCNT_ASM(4);
  else if constexpr (N == 5)  VMCNT_ASM(5);
  else if constexpr (N == 6)  VMCNT_ASM(6);
  else if constexpr (N == 8)  VMCNT_ASM(8);
  else                        VMCNT_ASM(0);
}
#define MEMFENCE asm volatile("" ::: "memory")

enum { EPI_SILU = 0, EPI_BBIAS = 1, EPI_QKV = 3 };

// ---------------------------------------------------------------------------
// B-direct wide GEMM: C[8192][NB*128] = f(A[8192][512] . B^T + bias).
// conv_tap structure: A staged in LDS (128 rows x 32 k, triple buffer),
// B fragment-packed in global, ping-pong reg prefetch. 4 waves of 64x64
// (FM=4, FN=4): 4 LDS reads / 16 MFMA. NT=16. Counted vmcnt(6).
// ---------------------------------------------------------------------------
template<int NB, int EPI>
__global__ __launch_bounds__(256) void gemm_bdw(
    const short* __restrict__ A,      // [8192][512] bf16
    const short* __restrict__ wBP,    // frag-packed [(n>>4)*16 + (k>>5)][512]
    const float* __restrict__ bias,
    const float* __restrict__ bias2,
    const float* __restrict__ bias3,
    short* __restrict__ C)            // [8192][NB*128] bf16
{
  constexpr int NT = 16;
  constexpr int LDC = NB * 128;
  __shared__ short sA[3][128 * 32];
  const int tid = threadIdx.x;
  const int m0 = (int)blockIdx.x * 128, n0 = (int)blockIdx.y * 128;
  const int lane = tid & 63, wid = tid >> 6;
  const int wm = wid >> 1, wn = wid & 1;
  const int lr = lane & 15, kgr = lane >> 4;
  const int aRow = wm * 64, bRow = wn * 64;
  const long NSTR = (long)NT * 512;
  const short* Bp = wBP + (long)((n0 + bRow) >> 4) * NSTR + lane * 8;

  auto stageA = [&](int buf, int t) {
#pragma unroll
    for (int it = 0; it < 2; ++it) {
      int idx = it * 256 + tid;
      GLOADLDS(A + (long)(m0 + (idx >> 2)) * 512 + t * 32 + (idx & 3) * 8, &sA[buf][idx * 8]);
    }
  };

  f32x4 acc[4][4];
#pragma unroll
  for (int i = 0; i < 4; ++i) {
#pragma unroll
    for (int j = 0; j < 4; ++j) acc[i][j] = (f32x4){0.f, 0.f, 0.f, 0.f};
  }
  short8 b0[4], b1[4];

  stageA(0, 0);
  stageA(1, 1);
  MEMFENCE;
#pragma unroll
  for (int ni = 0; ni < 4; ++ni)
    b0[ni] = *(const short8*)(Bp + ni * NSTR);
  MEMFENCE;
  vmcnt_wait<6>();              // Ast(0) done; Ast(1)+b0 may be in flight
  __builtin_amdgcn_s_barrier();

  int rd = 0;
  for (int t = 0; t < NT; t += 2) {
    { // even: consume b0, prefetch B(t+1)->b1, stage A(t+2)
      int wr = rd - 1; if (wr < 0) wr += 3;
      if (t + 2 < NT) stageA(wr, t + 2);
      MEMFENCE;
#pragma unroll
      for (int ni = 0; ni < 4; ++ni)
        b1[ni] = *(const short8*)(Bp + (long)(t + 1) * 512 + ni * NSTR);
      MEMFENCE;
      short8 af[4];
#pragma unroll
      for (int mi = 0; mi < 4; ++mi)
        af[mi] = *(const short8*)&sA[rd][(aRow + mi * 16 + lr) * 32 + kgr * 8];
      __builtin_amdgcn_s_setprio(1);
#pragma unroll
      for (int mi = 0; mi < 4; ++mi) {
#pragma unroll
        for (int ni = 0; ni < 4; ++ni)
          acc[mi][ni] = __builtin_amdgcn_mfma_f32_16x16x32_bf16(af[mi], b0[ni], acc[mi][ni], 0, 0, 0);
      }
      __builtin_amdgcn_s_setprio(0);
      if (t + 2 < NT) vmcnt_wait<6>(); else vmcnt_wait<4>();  // A(t+1) resident
      __builtin_amdgcn_s_barrier();
      rd = (rd == 2) ? 0 : rd + 1;
    }
    { // odd: consume b1, prefetch B(t+2)->b0, stage A(t+3)
      int wr = rd - 1; if (wr < 0) wr += 3;
      if (t + 3 < NT) stageA(wr, t + 3);
      MEMFENCE;
      if (t + 2 < NT) {
#pragma unroll
        for (int ni = 0; ni < 4; ++ni)
          b0[ni] = *(const short8*)(Bp + (long)(t + 2) * 512 + ni * NSTR);
      }
      MEMFENCE;
      short8 af[4];
#pragma unroll
      for (int mi = 0; mi < 4; ++mi)
        af[mi] = *(const short8*)&sA[rd][(aRow + mi * 16 + lr) * 32 + kgr * 8];
      __builtin_amdgcn_s_setprio(1);
#pragma unroll
      for (int mi = 0; mi < 4; ++mi) {
#pragma unroll
        for (int ni = 0; ni < 4; ++ni)
          acc[mi][ni] = __builtin_amdgcn_mfma_f32_16x16x32_bf16(af[mi], b1[ni], acc[mi][ni], 0, 0, 0);
      }
      __builtin_amdgcn_s_setprio(0);
      if (t + 3 < NT) vmcnt_wait<6>(); else vmcnt_wait<0>();
      __builtin_amdgcn_s_barrier();
      rd = (rd == 2) ? 0 : rd + 1;
    }
  }

  const int baseRow = m0 + aRow, baseCol = n0 + bRow;
#pragma unroll
  for (int mi = 0; mi < 4; ++mi) {
#pragma unroll
    for (int ni = 0; ni < 4; ++ni) {
      const int col = baseCol + ni * 16 + lr;
#pragma unroll
      for (int r = 0; r < 4; ++r) {
        const int row = baseRow + mi * 16 + kgr * 4 + r;
        float v = acc[mi][ni][r];
        if (EPI == EPI_SILU) {
          v += bias[col];
          v = v * sigmoidf_(v);
          C[(long)row * LDC + col] = f2bfs(v);
        } else if (EPI == EPI_BBIAS) {
          v += bias[col];
          C[(long)row * LDC + col] = f2bfs(v);
        } else if (EPI == EPI_QKV) {
          if (col < 512)       v = (v + bias[col]) * 0.125f;
          else if (col < 1024) v += bias2[col - 512];
          else                 v += bias3[col - 1024];
          C[(long)row * LDC + col] = f2bfs(v);
        }
      }
    }
  }
}

// ---------------------------------------------------------------------------
// B-direct GEMM for N=512 residual outputs (round 19, proven).
// ---------------------------------------------------------------------------
template<int NT>
__global__ __launch_bounds__(256) void gemm_bd(
    const short* __restrict__ A,      // [8192][NT*32]
    const short* __restrict__ wBP,
    const float* __restrict__ bias,
    const float* __restrict__ resid,
    float* __restrict__ C,
    float alpha, float beta)
{
  constexpr int K = NT * 32;
  __shared__ short sA[3][64 * 32];
  const int tid = threadIdx.x;
  const int x = (int)blockIdx.x >> 2, y = (int)blockIdx.x & 3;
  const int m0 = x * 64, n0 = y * 128;
  const int lane = tid & 63, wid = tid >> 6;
  const int wm = wid >> 1, wn = wid & 1;
  const int lr = lane & 15, kgr = lane >> 4;
  const int aRow = wm * 32, bRow = wn * 64;
  const long NSTR = (long)NT * 512;
  const short* Bp = wBP + (long)((n0 + bRow) >> 4) * NSTR + lane * 8;

  auto stageA = [&](int buf, int t) {
    GLOADLDS(A + (long)(m0 + (tid >> 2)) * K + t * 32 + (tid & 3) * 8, &sA[buf][tid * 8]);
  };

  f32x4 acc[2][4];
#pragma unroll
  for (int i = 0; i < 2; ++i) {
#pragma unroll
    for (int j = 0; j < 4; ++j) acc[i][j] = (f32x4){0.f, 0.f, 0.f, 0.f};
  }
  short8 b0[4], b1[4];

  stageA(0, 0);
  stageA(1, 1);
  MEMFENCE;
#pragma unroll
  for (int ni = 0; ni < 4; ++ni)
    b0[ni] = *(const short8*)(Bp + ni * NSTR);
  MEMFENCE;
  vmcnt_wait<5>();
  __builtin_amdgcn_s_barrier();

  int rd = 0;
  for (int t = 0; t < NT; t += 2) {
    {
      int wr = rd - 1; if (wr < 0) wr += 3;
      if (t + 2 < NT) stageA(wr, t + 2);
      MEMFENCE;
#pragma unroll
      for (int ni = 0; ni < 4; ++ni)
        b1[ni] = *(const short8*)(Bp + (long)(t + 1) * 512 + ni * NSTR);
      MEMFENCE;
      short8 af[2];
#pragma unroll
      for (int mi = 0; mi < 2; ++mi)
        af[mi] = *(const short8*)&sA[rd][(aRow + mi * 16 + lr) * 32 + kgr * 8];
      __builtin_amdgcn_s_setprio(1);
#pragma unroll
      for (int mi = 0; mi < 2; ++mi) {
#pragma unroll
        for (int ni = 0; ni < 4; ++ni)
          acc[mi][ni] = __builtin_amdgcn_mfma_f32_16x16x32_bf16(af[mi], b0[ni], acc[mi][ni], 0, 0, 0);
      }
      __builtin_amdgcn_s_setprio(0);
      if (t + 2 < NT) vmcnt_wait<5>(); else vmcnt_wait<4>();
      __builtin_amdgcn_s_barrier();
      rd = (rd == 2) ? 0 : rd + 1;
    }
    {
      int wr = rd - 1; if (wr < 0) wr += 3;
      if (t + 3 < NT) stageA(wr, t + 3);
      MEMFENCE;
      if (t + 2 < NT) {
#pragma unroll
        for (int ni = 0; ni < 4; ++ni)
          b0[ni] = *(const short8*)(Bp + (long)(t + 2) * 512 + ni * NSTR);
      }
      MEMFENCE;
      short8 af[2];
#pragma unroll
      for (int mi = 0; mi < 2; ++mi)
        af[mi] = *(const short8*)&sA[rd][(aRow + mi * 16 + lr) * 32 + kgr * 8];
      __builtin_amdgcn_s_setprio(1);
#pragma unroll
      for (int mi = 0; mi < 2; ++mi) {
#pragma unroll
        for (int ni = 0; ni < 4; ++ni)
          acc[mi][ni] = __builtin_amdgcn_mfma_f32_16x16x32_bf16(af[mi], b1[ni], acc[mi][ni], 0, 0, 0);
      }
      __builtin_amdgcn_s_setprio(0);
      if (t + 3 < NT) vmcnt_wait<5>(); else vmcnt_wait<0>();
      __builtin_amdgcn_s_barrier();
      rd = (rd == 2) ? 0 : rd + 1;
    }
  }

  const int baseRow = m0 + aRow, baseCol = n0 + bRow;
#pragma unroll
  for (int mi = 0; mi < 2; ++mi) {
#pragma unroll
    for (int ni = 0; ni < 4; ++ni) {
      const int col = baseCol + ni * 16 + lr;
#pragma unroll
      for (int r = 0; r < 4; ++r) {
        const int row = baseRow + mi * 16 + kgr * 4 + r;
        float v = acc[mi][ni][r] + bias[col];
        float rv = resid[(long)row * 512 + col];
        C[(long)row * 512 + col] = alpha * rv + beta * v;
      }
    }
  }
}

// ---------------------------------------------------------------------------
// Fragment-pack helpers. Layout:
// dst[((n>>4)*(K/32) + (k>>5))*512 + ((k>>3)&3)*128 + (n&15)*8 + (k&7)]
// ---------------------------------------------------------------------------
// N=512 weights (W2s/wo/cw2). TRANS: in [K][512]; else [512][K].
template<int TRANS, int KSHIFT>
__global__ __launch_bounds__(256) void packB(const float* __restrict__ in, short* __restrict__ out)
{
  const int gid = blockIdx.x * 256 + threadIdx.x;
  const int n = gid >> KSHIFT;
  const int k = gid & ((1 << KSHIFT) - 1);
  const float v = TRANS ? in[(long)k * 512 + n] : in[((long)n << KSHIFT) | k];
  out[((long)((n >> 4) << (KSHIFT - 5)) + (k >> 5)) * 512 + ((k >> 3) & 3) * 128 + (n & 15) * 8 + (k & 7)] = f2bfs(v);
}

// generic N (K=512): TRANS: in [512][N] (take in[k*N+n]); else in [N][512].
template<int TRANS, int NSHIFT>
__global__ __launch_bounds__(256) void packB2(const float* __restrict__ in, short* __restrict__ out)
{
  const int gid = blockIdx.x * 256 + threadIdx.x;   // N*512 total
  const int n = gid >> 9;
  const int k = gid & 511;
  const float v = TRANS ? in[((long)k << NSHIFT) | n] : in[((long)n << 9) | k];
  out[((long)(n >> 4) * 16 + (k >> 5)) * 512 + ((k >> 3) & 3) * 128 + (n & 15) * 8 + (k & 7)] = f2bfs(v);
}

// QKV pack: n in [0,1536), k in [0,512). wq/wk/wv are [8][512][64] fp32.
__global__ __launch_bounds__(256) void packQKV(
    const float* __restrict__ wq, const float* __restrict__ wk,
    const float* __restrict__ wv, short* __restrict__ out)
{
  const int gid = blockIdx.x * 256 + threadIdx.x;   // 1536*512
  const int n = gid >> 9;
  const int k = gid & 511;
  const int sel = n >> 9;                           // 0:q 1:k 2:v
  const int nn = n & 511;
  const float* w = (sel == 0) ? wq : (sel == 1) ? wk : wv;
  const float v = w[(long)(nn >> 6) * 32768 + (long)k * 64 + (nn & 63)];
  out[((long)(n >> 4) * 16 + (k >> 5)) * 512 + ((k >> 3) & 3) * 128 + (n & 15) * 8 + (k & 7)] = f2bfs(v);
}

// ---------------------------------------------------------------------------
// Conv, tap-tiled (round 17, frozen).
// ---------------------------------------------------------------------------
__global__ __launch_bounds__(256) void conv_tap(
    const short* __restrict__ glu,
    const short* __restrict__ wdP,
    short* __restrict__ parts)
{
  __shared__ short sA[2][144 * 32];
  const int tid = threadIdx.x;
  const int bid = blockIdx.x;
  const int cc = bid & 7, j = bid >> 3;
  const int y = cc >> 1, kg = cc & 1;
  const int x = j & 7, b = j >> 3;
  const int m0 = x * 128, n0 = y * 128;
  const short* Arow0 = glu + ((long)b * 1056 + m0 + 1 + kg * 16) * 512;
  short* cbase = parts + (long)kg * (8192L * 512) + (long)b * (1024L * 512);

  const int lane = tid & 63, wid = tid >> 6;
  const int wm = wid >> 1, wn = wid & 1;
  const int lr = lane & 15, kgr = lane >> 4;
  const int aRow = wm * 64, bRow = wn * 64;

  const short* Bp = wdP + (long)((n0 + bRow) >> 4) * (512L * 512)
                  + (long)(kg * 256) * 512 + lane * 8;
  const long NSTR = 512L * 512;

  auto stageA = [&](int buf, int ib) {
#pragma unroll
    for (int it = 0; it < 3; ++it) {
      int idx = it * 256 + tid;
      if (idx < 576) {
        GLOADLDS(Arow0 + (long)(idx >> 2) * 512 + ib * 32 + (idx & 3) * 8,
                 &sA[buf][idx * 8]);
      }
    }
  };

  f32x4 acc[4][4];
#pragma unroll
  for (int i = 0; i < 4; ++i) {
#pragma unroll
    for (int jj = 0; jj < 4; ++jj) acc[i][jj] = (f32x4){0.f, 0.f, 0.f, 0.f};
  }
  short8 b0[4], b1[4];

  stageA(0, 0);
  MEMFENCE;
#pragma unroll
  for (int ni = 0; ni < 4; ++ni)
    b0[ni] = *(const short8*)(Bp + ni * NSTR);
  MEMFENCE;
  vmcnt_wait<4>();
  __builtin_amdgcn_s_barrier();

  int cur = 0;
  for (int ib = 0; ib < 16; ++ib) {
    if (ib + 1 < 16) stageA(cur ^ 1, ib + 1);
    MEMFENCE;
#pragma unroll
    for (int kk = 0; kk < 16; ++kk) {
      const long noff = (kk + 1 < 16) ? (long)((kk + 1) * 16 + ib) * 512
                                      : (long)(ib + 1) * 512;
      if ((kk & 1) == 0) {
#pragma unroll
        for (int ni = 0; ni < 4; ++ni)
          b1[ni] = *(const short8*)(Bp + noff + ni * NSTR);
      } else {
#pragma unroll
        for (int ni = 0; ni < 4; ++ni)
          b0[ni] = *(const short8*)(Bp + noff + ni * NSTR);
      }
      short8 af[4];
#pragma unroll
      for (int mi = 0; mi < 4; ++mi)
        af[mi] = *(const short8*)&sA[cur][(kk + aRow + mi * 16 + lr) * 32 + kgr * 8];
      __builtin_amdgcn_s_setprio(1);
      if ((kk & 1) == 0) {
#pragma unroll
        for (int mi = 0; mi < 4; ++mi) {
#pragma unroll
          for (int ni = 0; ni < 4; ++ni)
            acc[mi][ni] = __builtin_amdgcn_mfma_f32_16x16x32_bf16(af[mi], b0[ni], acc[mi][ni], 0, 0, 0);
        }
      } else {
#pragma unroll
        for (int mi = 0; mi < 4; ++mi) {
#pragma unroll
          for (int ni = 0; ni < 4; ++ni)
            acc[mi][ni] = __builtin_amdgcn_mfma_f32_16x16x32_bf16(af[mi], b1[ni], acc[mi][ni], 0, 0, 0);
        }
      }
      __builtin_amdgcn_s_setprio(0);
    }
    vmcnt_wait<4>();
    __builtin_amdgcn_s_barrier();
    cur ^= 1;
  }
  vmcnt_wait<0>();

  const int baseRow = m0 + aRow, baseCol = n0 + bRow;
#pragma unroll
  for (int mi = 0; mi < 4; ++mi) {
#pragma unroll
    for (int ni = 0; ni < 4; ++ni) {
      const int col = baseCol + ni * 16 + lr;
#pragma unroll
      for (int r = 0; r < 4; ++r) {
        const int row = baseRow + mi * 16 + kgr * 4 + r;
        cbase[(long)row * 512 + col] = f2bfs(acc[mi][ni][r]);
      }
    }
  }
}

// ---------------------------------------------------------------------------
// Flash attention (round 17, frozen).
// ---------------------------------------------------------------------------
__global__ __launch_bounds__(256) void flash_attn(
    const short* __restrict__ qkv,
    const short* __restrict__ vt,
    short* __restrict__ out)
{
  __shared__ short sQ[64 * 64];
  __shared__ short sK[64 * 64];
  __shared__ short sV[64 * 64];
  __shared__ short sP[4][16 * 64];
  const int tid = threadIdx.x;
  const int lane = tid & 63, w = tid >> 6;
  const int lr = lane & 15, kg = lane >> 4;
  const int bh = (int)blockIdx.z;
  const int b = bh >> 3, h = bh & 7;
  const int q0 = blockIdx.x * 64;
  const short* qbase = qkv + (long)b * 1024 * 1536 + h * 64;
  const short* kbase = qbase + 512;
  const short* vtb = vt + (long)bh * 65536;

#pragma unroll
  for (int it = 0; it < 2; ++it) {
    int idx = it * 256 + tid;
    int row = idx >> 3, c = (idx & 7) ^ (row & 7);
    GLOADLDS(qbase + (long)(q0 + row) * 1536 + c * 8, &sQ[idx * 8]);
  }
  __syncthreads();
  short8 bq[2];
#pragma unroll
  for (int ks = 0; ks < 2; ++ks)
    bq[ks] = *(const short8*)&sQ[(w * 16 + lr) * 64 + ((ks * 4 + kg) ^ (lr & 7)) * 8];

  f32x4 po[4];
#pragma unroll
  for (int mi = 0; mi < 4; ++mi) po[mi] = (f32x4){0.f, 0.f, 0.f, 0.f};
  float m = -3.0e38f, l = 0.f;

  for (int s0 = 0; s0 < 1024; s0 += 64) {
#pragma unroll
    for (int it = 0; it < 2; ++it) {
      int idx = it * 256 + tid;
      int row = idx >> 3, c = (idx & 7) ^ (row & 7);
      GLOADLDS(kbase + (long)(s0 + row) * 1536 + c * 8, &sK[idx * 8]);
    }
#pragma unroll
    for (int it = 0; it < 2; ++it) {
      int idx = it * 256 + tid;
      int row = idx >> 3, c = (idx & 7) ^ (row & 7);
      GLOADLDS(vtb + (long)row * 1024 + s0 + c * 8, &sV[idx * 8]);
    }
    __syncthreads();

    f32x4 as[4];
#pragma unroll
    for (int mi = 0; mi < 4; ++mi) as[mi] = (f32x4){0.f, 0.f, 0.f, 0.f};
    __builtin_amdgcn_s_setprio(1);
#pragma unroll
    for (int ks = 0; ks < 2; ++ks) {
#pragma unroll
      for (int mi = 0; mi < 4; ++mi) {
        short8 ak = *(const short8*)&sK[(mi * 16 + lr) * 64 + ((ks * 4 + kg) ^ (lr & 7)) * 8];
        as[mi] = __builtin_amdgcn_mfma_f32_16x16x32_bf16(ak, bq[ks], as[mi], 0, 0, 0);
      }
    }
    __builtin_amdgcn_s_setprio(0);

    float rmax = as[0][0];
#pragma unroll
    for (int mi = 0; mi < 4; ++mi) {
#pragma unroll
      for (int r = 0; r < 4; ++r) rmax = fmaxf(rmax, as[mi][r]);
    }
    rmax = fmaxf(rmax, __shfl_xor(rmax, 16));
    rmax = fmaxf(rmax, __shfl_xor(rmax, 32));
    const float mn = fmaxf(m, rmax);
    const float sc = __expf(m - mn);
    float p[4][4];
    float rsum = 0.f;
#pragma unroll
    for (int mi = 0; mi < 4; ++mi) {
#pragma unroll
      for (int r = 0; r < 4; ++r) { p[mi][r] = __expf(as[mi][r] - mn); rsum += p[mi][r]; }
    }
    rsum += __shfl_xor(rsum, 16);
    rsum += __shfl_xor(rsum, 32);
    l = l * sc + rsum;
    m = mn;
#pragma unroll
    for (int mi = 0; mi < 4; ++mi) {
#pragma unroll
      for (int r = 0; r < 4; ++r) po[mi][r] *= sc;
    }
#pragma unroll
    for (int mi = 0; mi < 4; ++mi) {
      s16x4 pk;
#pragma unroll
      for (int r = 0; r < 4; ++r) pk[r] = f2bfs(p[mi][r]);
      *(s16x4*)&sP[w][lr * 64 + ((mi ^ (lr & 3)) * 16 + kg * 4)] = pk;
    }
    __builtin_amdgcn_s_setprio(1);
#pragma unroll
    for (int ks = 0; ks < 2; ++ks) {
      short8 bp = *(const short8*)&sP[w][lr * 64 + (((ks * 2 + (kg >> 1)) ^ (lr & 3)) * 16 + (kg & 1) * 8)];
#pragma unroll
      for (int mi = 0; mi < 4; ++mi) {
        short8 av = *(const short8*)&sV[(mi * 16 + lr) * 64 + ((ks * 4 + kg) ^ (lr & 7)) * 8];
        po[mi] = __builtin_amdgcn_mfma_f32_16x16x32_bf16(av, bp, po[mi], 0, 0, 0);
      }
    }
    __builtin_amdgcn_s_setprio(0);
    __syncthreads();
  }

  const float inv = 1.f / l;
  const int t2 = q0 + w * 16 + lr;
  const int n = h * 1024 + t2;
  short* ob = out + ((long)b * 1024 + (n >> 3)) * 512 + (n & 7) * 64;
#pragma unroll
  for (int mi = 0; mi < 4; ++mi) {
    s16x4 o;
#pragma unroll
    for (int r = 0; r < 4; ++r) o[r] = f2bfs(po[mi][r] * inv);
    *(s16x4*)&ob[mi * 16 + kg * 4] = o;
  }
}

// ---------------------------------------------------------------------------
__global__ __launch_bounds__(256) void reduce_bn(
    const short* __restrict__ parts, long pstride,
    short* __restrict__ z, float* stats)
{
  const int r0 = blockIdx.x * 16;
  const int c = threadIdx.x * 2;
  float s0 = 0.f, s1 = 0.f, q0 = 0.f, q1 = 0.f;
#pragma unroll 4
  for (int r = 0; r < 16; ++r) {
    const long idx = (long)(r0 + r) * 512 + c;
    int p0 = *(const int*)&parts[idx];
    int p1 = *(const int*)&parts[idx + pstride];
    float a0 = bfs2f((short)(p0 & 0xffff)) + bfs2f((short)(p1 & 0xffff));
    float a1 = bfs2f((short)(p0 >> 16)) + bfs2f((short)(p1 >> 16));
    int zo = ((int)(unsigned short)f2bfs(a0)) | (((int)(unsigned short)f2bfs(a1)) << 16);
    *(int*)&z[idx] = zo;
    s0 += a0; s1 += a1; q0 += a0 * a0; q1 += a1 * a1;
  }
  atomicAdd(&stats[c], s0);
  atomicAdd(&stats[c + 1], s1);
  atomicAdd(&stats[512 + c], q0);
  atomicAdd(&stats[512 + c + 1], q1);
}

// ---------------------------------------------------------------------------
template<int ADDPE, int OUTF32>
__global__ __launch_bounds__(256) void ln_rows(
    const float* __restrict__ X, const float* __restrict__ g, const float* __restrict__ b,
    const float* __restrict__ pe, void* __restrict__ Y)
{
  const int row = blockIdx.x * 4 + (threadIdx.x >> 6);
  const int lane = threadIdx.x & 63;
  const int c0 = lane * 8;
  const float* src = X + (long)row * 512 + c0;
  f32x4 a = *(const f32x4*)src, c = *(const f32x4*)(src + 4);
  float x[8] = {a[0], a[1], a[2], a[3], c[0], c[1], c[2], c[3]};
  float s = 0.f, q = 0.f;
#pragma unroll
  for (int j = 0; j < 8; ++j) { s += x[j]; q += x[j] * x[j]; }
#pragma unroll
  for (int off = 32; off > 0; off >>= 1) { s += __shfl_xor(s, off); q += __shfl_xor(q, off); }
  const float mean = s * (1.f / 512.f);
  const float var = q * (1.f / 512.f) - mean * mean;
  const float rstd = rsqrtf(var + 1e-5f);
  f32x4 g0 = *(const f32x4*)(g + c0), g1 = *(const f32x4*)(g + c0 + 4);
  f32x4 b0 = *(const f32x4*)(b + c0), b1 = *(const f32x4*)(b + c0 + 4);
  float gg[8] = {g0[0], g0[1], g0[2], g0[3], g1[0], g1[1], g1[2], g1[3]};
  float bb[8] = {b0[0], b0[1], b0[2], b0[3], b1[0], b1[1], b1[2], b1[3]};
  float y[8];
#pragma unroll
  for (int j = 0; j < 8; ++j) {
    y[j] = (x[j] - mean) * rstd * gg[j] + bb[j];
    if (ADDPE) y[j] += pe[(long)(row & 1023) * 512 + c0 + j];
  }
  if (OUTF32) {
    float* dst = (float*)Y + (long)row * 512 + c0;
    *(f32x4*)dst = (f32x4){y[0], y[1], y[2], y[3]};
    *(f32x4*)(dst + 4) = (f32x4){y[4], y[5], y[6], y[7]};
  } else {
    short8 o;
#pragma unroll
    for (int j = 0; j < 8; ++j) o[j] = f2bfs(y[j]);
    *(short8*)((short*)Y + (long)row * 512 + c0) = o;
  }
}

// ---------------------------------------------------------------------------
// 64x64-tile bf16 transpose (V^T only now).
// ---------------------------------------------------------------------------
__global__ __launch_bounds__(256) void transpose64b(
    const short* __restrict__ in, int ldin, short* __restrict__ out, int ldout,
    int zshift, long zh_in, long zl_in, long z_out)
{
  __shared__ short t[64][72];
  const int z = blockIdx.z;
  const long inoff = (long)(z >> zshift) * zh_in + (long)(z & ((1 << zshift) - 1)) * zl_in;
  const int tr = blockIdx.x;
  const short* src = in + inoff + (long)(tr * 64) * ldin;
  short* dst = out + (long)z * z_out + tr * 64;
  const int tid = threadIdx.x;
#pragma unroll
  for (int p = 0; p < 2; ++p) {
    int idx = p * 256 + tid;
    int r = idx >> 3, c8 = (idx & 7) * 8;
    short8 v = *(const short8*)(src + (long)r * ldin + c8);
#pragma unroll
    for (int j = 0; j < 8; ++j) t[r][c8 + j] = v[j];
  }
  __syncthreads();
#pragma unroll
  for (int p = 0; p < 2; ++p) {
    int idx = p * 256 + tid;
    int c = idx >> 3, r8 = (idx & 7) * 8;
    short8 v;
#pragma unroll
    for (int j = 0; j < 8; ++j) v[j] = t[r8 + j][c];
    *(short8*)(dst + (long)c * ldout + r8) = v;
  }
}

// wdP fragment-packed, 32 taps; zeroes tap 31.
__global__ __launch_bounds__(256) void wd_pack(const float* __restrict__ wd, short* __restrict__ wdP)
{
  const int gid = blockIdx.x * 256 + threadIdx.x;
  const int e = gid >> 9, i = gid & 511;
  const float* src = wd + ((long)e * 512 + i) * 31;
  const long rowtile = (long)(e >> 4) * (512L * 512);
  const int inner = ((i >> 3) & 3) * 128 + (e & 15) * 8 + (i & 7);
#pragma unroll
  for (int KK = 0; KK < 31; ++KK)
    wdP[rowtile + (long)(KK * 16 + (i >> 5)) * 512 + inner] = f2bfs(src[KK]);
  wdP[rowtile + (long)(31 * 16 + (i >> 5)) * 512 + inner] = 0;
}

__global__ __launch_bounds__(256) void pe_init(float* __restrict__ pe)
{
  const int gid = blockIdx.x * 256 + threadIdx.x;
  const int t = gid >> 8, p = gid & 255;
  const float freq = __expf(-(float)p * (9.210340371976184f / 256.f));
  const float ang = (float)t * freq;
  pe[(long)t * 512 + 2 * p]     = sinf(ang);
  pe[(long)t * 512 + 2 * p + 1] = cosf(ang);
}

__global__ __launch_bounds__(256) void halo_zero(short* __restrict__ gp)
{
  const int gid = blockIdx.x * 256 + threadIdx.x;
  if (gid >= 16512) return;
  long row;
  int c8;
  if (gid < 16384) {
    const int b = gid >> 11;
    const int r = (gid >> 6) & 31;
    c8 = (gid & 63) * 8;
    row = (long)b * 1056 + ((r < 16) ? r : (1024 + r));
  } else {
    const int k = gid - 16384;
    c8 = (k & 63) * 8;
    row = 8448 + (k >> 6);
  }
  *(short8*)(gp + row * 512 + c8) = (short8){0, 0, 0, 0, 0, 0, 0, 0};
}

__global__ __launch_bounds__(256) void glu_kernel(const short* __restrict__ y1, short* __restrict__ gp)
{
  const int gid = blockIdx.x * 256 + threadIdx.x;
  const int row = gid >> 7;
  const int ci = (gid & 127) * 4;
  const short* base = y1 + (long)row * 1024;
  s16x4 a = *(const s16x4*)(base + ci);
  s16x4 g = *(const s16x4*)(base + 512 + ci);
  const int b = row >> 10, t = row & 1023;
  s16x4 o;
#pragma unroll
  for (int j = 0; j < 4; ++j) o[j] = f2bfs(bfs2f(a[j]) * sigmoidf_(bfs2f(g[j])));
  *(s16x4*)(gp + ((long)b * 1056 + 16 + t) * 512 + ci) = o;
}

__global__ void bn_stats(float* stats, const float* __restrict__ bn_g, const float* __restrict__ bn_b)
{
  const int c = blockIdx.x * 256 + threadIdx.x;
  if (c < 512) {
    float mean = stats[c] * (1.f / 8192.f);
    float var = stats[512 + c] * (1.f / 8192.f) - mean * mean;
    float sc = bn_g[c] * rsqrtf(var + 1e-5f);
    stats[1024 + c] = sc;
    stats[1536 + c] = bn_b[c] - mean * sc;
  }
}

__global__ __launch_bounds__(256) void bn_silu(const short* __restrict__ z, const float* __restrict__ stats,
                                               short* __restrict__ out)
{
  const long base = ((long)blockIdx.x * 256 + threadIdx.x) * 8;
  const int c0 = (int)(base & 511);
  short8 v = *(const short8*)(z + base);
  short8 o;
#pragma unroll
  for (int j = 0; j < 8; ++j) {
    const int c = c0 + j;
    float y = bfs2f(v[j]) * stats[1024 + c] + stats[1536 + c];
    o[j] = f2bfs(y * sigmoidf_(y));
  }
  *(short8*)(out + base) = o;
}

// ---------------------------------------------------------------------------
extern "C" void kernel_launch(void* const* d_in, const int* in_sizes, int n_in,
                              void* d_out, int out_size, void* d_ws, size_t ws_size,
                              hipStream_t stream)
{
  (void)in_sizes; (void)n_in; (void)out_size; (void)ws_size;
  const float* x_in   = (const float*)d_in[0];
  const float* ff1_g  = (const float*)d_in[1];
  const float* ff1_bb = (const float*)d_in[2];
  const float* ff1_w1 = (const float*)d_in[3];
  const float* ff1_b1 = (const float*)d_in[4];
  const float* ff1_w2 = (const float*)d_in[5];
  const float* ff1_b2 = (const float*)d_in[6];
  const float* mha_g  = (const float*)d_in[7];
  const float* mha_b  = (const float*)d_in[8];
  const float* wq     = (const float*)d_in[9];
  const float* bq     = (const float*)d_in[10];
  const float* wk     = (const float*)d_in[11];
  const float* bk     = (const float*)d_in[12];
  const float* wv     = (const float*)d_in[13];
  const float* bv     = (const float*)d_in[14];
  const float* wo     = (const float*)d_in[15];
  const float* bo     = (const float*)d_in[16];
  const float* cv_g   = (const float*)d_in[17];
  const float* cv_b   = (const float*)d_in[18];
  const float* cv_w1  = (const float*)d_in[19];
  const float* cv_b1  = (const float*)d_in[20];
  const float* cv_wd  = (const float*)d_in[21];
  const float* bn_g   = (const float*)d_in[22];
  const float* bn_b   = (const float*)d_in[23];
  const float* cv_w2  = (const float*)d_in[24];
  const float* cv_b2  = (const float*)d_in[25];
  const float* ff2_g  = (const float*)d_in[26];
  const float* ff2_b  = (const float*)d_in[27];
  const float* ff2_w1 = (const float*)d_in[28];
  const float* ff2_b1 = (const float*)d_in[29];
  const float* ff2_w2 = (const float*)d_in[30];
  const float* ff2_b2 = (const float*)d_in[31];
  const float* fin_g  = (const float*)d_in[32];
  const float* fin_b  = (const float*)d_in[33];

  size_t off = 0;
  char* wsb = (char*)d_ws;
  auto take = [&](size_t n) { char* p = wsb + off; off += (n + 255) & ~(size_t)255; return p; };
  short* ff1w1P = (short*)take(2048L * 512 * 2);   // frag-packed (bdw)
  short* ff1w2P = (short*)take(2048L * 512 * 2);   // frag-packed (bd)
  short* qkvP   = (short*)take(1536L * 512 * 2);   // frag-packed (bdw)
  short* woP    = (short*)take(512L * 512 * 2);    // frag-packed (bd)
  short* cw1P   = (short*)take(1024L * 512 * 2);   // frag-packed (bdw)
  short* cw2P   = (short*)take(512L * 512 * 2);    // frag-packed (bd)
  short* wdP    = (short*)take(32L * 512 * 512 * 2);
  short* ff2w1P = (short*)take(2048L * 512 * 2);   // frag-packed (bdw)
  short* ff2w2P = (short*)take(2048L * 512 * 2);   // frag-packed (bd)
  float* xcur   = (float*)take(8192L * 512 * 4);
  char*  Ra     = take(8192L * 2048 * 2);              // hid bf16 / qkv bf16 / y1 bf16
  short* Rb     = (short*)take(8192L * 512 * 2);       // ln out / att_o / conv z
  short* Rg     = (short*)take((8L * 1056 + 2) * 512 * 2);
  short* parts  = (short*)take(2L * 8192 * 512 * 2);
  short* vt     = (short*)take(64L * 64 * 1024 * 2);
  float* pe     = (float*)take(1024L * 512 * 4);
  float* stats  = (float*)take(2048L * 4);

  short* hid = (short*)Ra;
  short* qkv = (short*)Ra;
  short* y1  = (short*)Ra;

  // ---- weight packs (fp32 -> bf16 frag layout; per call) ----
  packB2<1, 11><<<4096, 256, 0, stream>>>(ff1_w1, ff1w1P);   // [512][2048] -> N=2048
  packB<1, 11><<<4096, 256, 0, stream>>>(ff1_w2, ff1w2P);    // [2048][512]
  packQKV<<<3072, 256, 0, stream>>>(wq, wk, wv, qkvP);
  packB<1, 9><<<1024, 256, 0, stream>>>(wo, woP);
  packB2<0, 0><<<2048, 256, 0, stream>>>(cv_w1, cw1P);       // [1024][512] -> N=1024
  packB<0, 9><<<1024, 256, 0, stream>>>(cv_w2, cw2P);
  wd_pack<<<1024, 256, 0, stream>>>(cv_wd, wdP);
  pe_init<<<1024, 256, 0, stream>>>(pe);

  // ---- FF1: x1 = 1.5 x + 0.5 (silu(ln(x) W1 + b1) W2 + b2) ----
  ln_rows<0, 0><<<2048, 256, 0, stream>>>(x_in, ff1_g, ff1_bb, nullptr, Rb);
  gemm_bdw<16, EPI_SILU><<<dim3(64, 16), 256, 0, stream>>>(
      Rb, ff1w1P, ff1_b1, nullptr, nullptr, hid);
  gemm_bd<64><<<512, 256, 0, stream>>>(hid, ff1w2P, ff1_b2, x_in, xcur, 1.5f, 0.5f);

  // ---- MHSA: x2 = 2 x1 + (scramble(attn) Wo + bo) ----
  ln_rows<1, 0><<<2048, 256, 0, stream>>>(xcur, mha_g, mha_b, pe, Rb);
  gemm_bdw<12, EPI_QKV><<<dim3(64, 12), 256, 0, stream>>>(
      Rb, qkvP, bq, bk, bv, qkv);
  transpose64b<<<dim3(16, 1, 64), 256, 0, stream>>>(qkv + 1024, 1536, vt, 1024, 3,
                                                    1024L * 1536, 64, 65536);
  flash_attn<<<dim3(16, 1, 64), 256, 0, stream>>>(qkv, vt, Rb);
  gemm_bd<16><<<512, 256, 0, stream>>>(Rb, woP, bo, xcur, xcur, 2.f, 1.f);

  // ---- Conv module: x3 = 2 x2 + (W2 silu(BN(conv(glu(W1 ln(x2) + b1)))) + b2) ----
  ln_rows<0, 0><<<2048, 256, 0, stream>>>(xcur, cv_g, cv_b, nullptr, Rb);
  gemm_bdw<8, EPI_BBIAS><<<dim3(64, 8), 256, 0, stream>>>(
      Rb, cw1P, cv_b1, nullptr, nullptr, y1);
  halo_zero<<<65, 256, 0, stream>>>(Rg);
  glu_kernel<<<4096, 256, 0, stream>>>(y1, Rg);
  (void)hipMemsetAsync(stats, 0, 1024 * sizeof(float), stream);
  conv_tap<<<512, 256, 0, stream>>>(Rg, wdP, parts);
  reduce_bn<<<512, 256, 0, stream>>>(parts, 8192L * 512, Rb, stats);
  bn_stats<<<2, 256, 0, stream>>>(stats, bn_g, bn_b);
  bn_silu<<<2048, 256, 0, stream>>>(Rb, stats, (short*)Rg);
  gemm_bd<16><<<512, 256, 0, stream>>>((short*)Rg, cw2P, cv_b2, xcur, xcur, 2.f, 1.f);

  // ---- FF2: x4 = 1.5 x3 + 0.5 (...) ----
  ln_rows<0, 0><<<2048, 256, 0, stream>>>(xcur, ff2_g, ff2_b, nullptr, Rb);
  gemm_bdw<16, EPI_SILU><<<dim3(64, 16), 256, 0, stream>>>(
      Rb, ff2w1P, ff2_b1, nullptr, nullptr, hid);
  gemm_bd<64><<<512, 256, 0, stream>>>(hid, ff2w2P, ff2_b2, xcur, xcur, 1.5f, 0.5f);

  // ---- final LN -> d_out (fp32) ----
  ln_rows<0, 1><<<2048, 256, 0, stream>>>(xcur, fin_g, fin_b, nullptr, (float*)d_out);
}

// Round 21
// 477.393 us; speedup vs baseline: 1.1551x; 1.0053x over previous
//
#include <hip/hip_runtime.h>

// ---------------------------------------------------------------------------
// Conformer block, MI355X gfx950. Inputs/outputs fp32; internal activations
// bf16 with fp32 accumulation via bf16 MFMA 16x16x32.
// Round 21: conv B-prefetch depth 3 (4-slot register rotation, slot = s&3
// static under kk-unroll). Covers L2 latency (~200cy) with 3x80cy of MFMA.
// Conv is grid-limited to 2 blocks/CU so +32 VGPR is free. vmcnt(12) at the
// ib barrier (3 in-flight prefetches x 4 loads). Rest frozen at round 20.
// ---------------------------------------------------------------------------

typedef __attribute__((ext_vector_type(4))) float f32x4;
typedef __attribute__((ext_vector_type(8))) short short8;
typedef __attribute__((ext_vector_type(4))) short s16x4;

__device__ __forceinline__ float bfs2f(short s) {
  unsigned u = ((unsigned)(unsigned short)s) << 16;
  float f; __builtin_memcpy(&f, &u, 4); return f;
}
__device__ __forceinline__ short f2bfs(float f) {
  unsigned u; __builtin_memcpy(&u, &f, 4);
  u = (u + 0x7FFFu + ((u >> 16) & 1u)) >> 16;   // RNE
  return (short)u;
}
__device__ __forceinline__ float sigmoidf_(float x) { return 1.f / (1.f + __expf(-x)); }

#define GLOADLDS(gsrc, ldst) \
  __builtin_amdgcn_global_load_lds((__attribute__((address_space(1))) void*)(gsrc), \
                                   (__attribute__((address_space(3))) void*)(ldst), 16, 0, 0)

#define VMCNT_ASM(n) asm volatile("s_waitcnt vmcnt(" #n ")" ::: "memory")
template<int N> __device__ __forceinline__ void vmcnt_wait() {
  if      constexpr (N == 0)  VMCNT_ASM(0);
  else if constexpr (N == 2)  VMCNT_ASM(2);
  else if constexpr (N == 3)  VMCNT_ASM(3);
  else if constexpr (N == 4)  VMCNT_ASM(4);
  else if constexpr (N == 5)  VMCNT_ASM(5);
  else if constexpr (N == 6)  VMCNT_ASM(6);
  else if constexpr (N == 8)  VMCNT_ASM(8);
  else if constexpr (N == 12) VMCNT_ASM(12);
  else                        VMCNT_ASM(0);
}
#define MEMFENCE asm volatile("" ::: "memory")

enum { EPI_SILU = 0, EPI_BBIAS = 1, EPI_QKV = 3 };

// ---------------------------------------------------------------------------
// B-direct wide GEMM (round 20, frozen): C[8192][NB*128] = f(A.B^T + bias).
// ---------------------------------------------------------------------------
template<int NB, int EPI>
__global__ __launch_bounds__(256) void gemm_bdw(
    const short* __restrict__ A,
    const short* __restrict__ wBP,
    const float* __restrict__ bias,
    const float* __restrict__ bias2,
    const float* __restrict__ bias3,
    short* __restrict__ C)
{
  constexpr int NT = 16;
  constexpr int LDC = NB * 128;
  __shared__ short sA[3][128 * 32];
  const int tid = threadIdx.x;
  const int m0 = (int)blockIdx.x * 128, n0 = (int)blockIdx.y * 128;
  const int lane = tid & 63, wid = tid >> 6;
  const int wm = wid >> 1, wn = wid & 1;
  const int lr = lane & 15, kgr = lane >> 4;
  const int aRow = wm * 64, bRow = wn * 64;
  const long NSTR = (long)NT * 512;
  const short* Bp = wBP + (long)((n0 + bRow) >> 4) * NSTR + lane * 8;

  auto stageA = [&](int buf, int t) {
#pragma unroll
    for (int it = 0; it < 2; ++it) {
      int idx = it * 256 + tid;
      GLOADLDS(A + (long)(m0 + (idx >> 2)) * 512 + t * 32 + (idx & 3) * 8, &sA[buf][idx * 8]);
    }
  };

  f32x4 acc[4][4];
#pragma unroll
  for (int i = 0; i < 4; ++i) {
#pragma unroll
    for (int j = 0; j < 4; ++j) acc[i][j] = (f32x4){0.f, 0.f, 0.f, 0.f};
  }
  short8 b0[4], b1[4];

  stageA(0, 0);
  stageA(1, 1);
  MEMFENCE;
#pragma unroll
  for (int ni = 0; ni < 4; ++ni)
    b0[ni] = *(const short8*)(Bp + ni * NSTR);
  MEMFENCE;
  vmcnt_wait<6>();
  __builtin_amdgcn_s_barrier();

  int rd = 0;
  for (int t = 0; t < NT; t += 2) {
    {
      int wr = rd - 1; if (wr < 0) wr += 3;
      if (t + 2 < NT) stageA(wr, t + 2);
      MEMFENCE;
#pragma unroll
      for (int ni = 0; ni < 4; ++ni)
        b1[ni] = *(const short8*)(Bp + (long)(t + 1) * 512 + ni * NSTR);
      MEMFENCE;
      short8 af[4];
#pragma unroll
      for (int mi = 0; mi < 4; ++mi)
        af[mi] = *(const short8*)&sA[rd][(aRow + mi * 16 + lr) * 32 + kgr * 8];
      __builtin_amdgcn_s_setprio(1);
#pragma unroll
      for (int mi = 0; mi < 4; ++mi) {
#pragma unroll
        for (int ni = 0; ni < 4; ++ni)
          acc[mi][ni] = __builtin_amdgcn_mfma_f32_16x16x32_bf16(af[mi], b0[ni], acc[mi][ni], 0, 0, 0);
      }
      __builtin_amdgcn_s_setprio(0);
      if (t + 2 < NT) vmcnt_wait<6>(); else vmcnt_wait<4>();
      __builtin_amdgcn_s_barrier();
      rd = (rd == 2) ? 0 : rd + 1;
    }
    {
      int wr = rd - 1; if (wr < 0) wr += 3;
      if (t + 3 < NT) stageA(wr, t + 3);
      MEMFENCE;
      if (t + 2 < NT) {
#pragma unroll
        for (int ni = 0; ni < 4; ++ni)
          b0[ni] = *(const short8*)(Bp + (long)(t + 2) * 512 + ni * NSTR);
      }
      MEMFENCE;
      short8 af[4];
#pragma unroll
      for (int mi = 0; mi < 4; ++mi)
        af[mi] = *(const short8*)&sA[rd][(aRow + mi * 16 + lr) * 32 + kgr * 8];
      __builtin_amdgcn_s_setprio(1);
#pragma unroll
      for (int mi = 0; mi < 4; ++mi) {
#pragma unroll
        for (int ni = 0; ni < 4; ++ni)
          acc[mi][ni] = __builtin_amdgcn_mfma_f32_16x16x32_bf16(af[mi], b1[ni], acc[mi][ni], 0, 0, 0);
      }
      __builtin_amdgcn_s_setprio(0);
      if (t + 3 < NT) vmcnt_wait<6>(); else vmcnt_wait<0>();
      __builtin_amdgcn_s_barrier();
      rd = (rd == 2) ? 0 : rd + 1;
    }
  }

  const int baseRow = m0 + aRow, baseCol = n0 + bRow;
#pragma unroll
  for (int mi = 0; mi < 4; ++mi) {
#pragma unroll
    for (int ni = 0; ni < 4; ++ni) {
      const int col = baseCol + ni * 16 + lr;
#pragma unroll
      for (int r = 0; r < 4; ++r) {
        const int row = baseRow + mi * 16 + kgr * 4 + r;
        float v = acc[mi][ni][r];
        if (EPI == EPI_SILU) {
          v += bias[col];
          v = v * sigmoidf_(v);
          C[(long)row * LDC + col] = f2bfs(v);
        } else if (EPI == EPI_BBIAS) {
          v += bias[col];
          C[(long)row * LDC + col] = f2bfs(v);
        } else if (EPI == EPI_QKV) {
          if (col < 512)       v = (v + bias[col]) * 0.125f;
          else if (col < 1024) v += bias2[col - 512];
          else                 v += bias3[col - 1024];
          C[(long)row * LDC + col] = f2bfs(v);
        }
      }
    }
  }
}

// ---------------------------------------------------------------------------
// B-direct GEMM for N=512 residual outputs (round 19, frozen).
// ---------------------------------------------------------------------------
template<int NT>
__global__ __launch_bounds__(256) void gemm_bd(
    const short* __restrict__ A,
    const short* __restrict__ wBP,
    const float* __restrict__ bias,
    const float* __restrict__ resid,
    float* __restrict__ C,
    float alpha, float beta)
{
  constexpr int K = NT * 32;
  __shared__ short sA[3][64 * 32];
  const int tid = threadIdx.x;
  const int x = (int)blockIdx.x >> 2, y = (int)blockIdx.x & 3;
  const int m0 = x * 64, n0 = y * 128;
  const int lane = tid & 63, wid = tid >> 6;
  const int wm = wid >> 1, wn = wid & 1;
  const int lr = lane & 15, kgr = lane >> 4;
  const int aRow = wm * 32, bRow = wn * 64;
  const long NSTR = (long)NT * 512;
  const short* Bp = wBP + (long)((n0 + bRow) >> 4) * NSTR + lane * 8;

  auto stageA = [&](int buf, int t) {
    GLOADLDS(A + (long)(m0 + (tid >> 2)) * K + t * 32 + (tid & 3) * 8, &sA[buf][tid * 8]);
  };

  f32x4 acc[2][4];
#pragma unroll
  for (int i = 0; i < 2; ++i) {
#pragma unroll
    for (int j = 0; j < 4; ++j) acc[i][j] = (f32x4){0.f, 0.f, 0.f, 0.f};
  }
  short8 b0[4], b1[4];

  stageA(0, 0);
  stageA(1, 1);
  MEMFENCE;
#pragma unroll
  for (int ni = 0; ni < 4; ++ni)
    b0[ni] = *(const short8*)(Bp + ni * NSTR);
  MEMFENCE;
  vmcnt_wait<5>();
  __builtin_amdgcn_s_barrier();

  int rd = 0;
  for (int t = 0; t < NT; t += 2) {
    {
      int wr = rd - 1; if (wr < 0) wr += 3;
      if (t + 2 < NT) stageA(wr, t + 2);
      MEMFENCE;
#pragma unroll
      for (int ni = 0; ni < 4; ++ni)
        b1[ni] = *(const short8*)(Bp + (long)(t + 1) * 512 + ni * NSTR);
      MEMFENCE;
      short8 af[2];
#pragma unroll
      for (int mi = 0; mi < 2; ++mi)
        af[mi] = *(const short8*)&sA[rd][(aRow + mi * 16 + lr) * 32 + kgr * 8];
      __builtin_amdgcn_s_setprio(1);
#pragma unroll
      for (int mi = 0; mi < 2; ++mi) {
#pragma unroll
        for (int ni = 0; ni < 4; ++ni)
          acc[mi][ni] = __builtin_amdgcn_mfma_f32_16x16x32_bf16(af[mi], b0[ni], acc[mi][ni], 0, 0, 0);
      }
      __builtin_amdgcn_s_setprio(0);
      if (t + 2 < NT) vmcnt_wait<5>(); else vmcnt_wait<4>();
      __builtin_amdgcn_s_barrier();
      rd = (rd == 2) ? 0 : rd + 1;
    }
    {
      int wr = rd - 1; if (wr < 0) wr += 3;
      if (t + 3 < NT) stageA(wr, t + 3);
      MEMFENCE;
      if (t + 2 < NT) {
#pragma unroll
        for (int ni = 0; ni < 4; ++ni)
          b0[ni] = *(const short8*)(Bp + (long)(t + 2) * 512 + ni * NSTR);
      }
      MEMFENCE;
      short8 af[2];
#pragma unroll
      for (int mi = 0; mi < 2; ++mi)
        af[mi] = *(const short8*)&sA[rd][(aRow + mi * 16 + lr) * 32 + kgr * 8];
      __builtin_amdgcn_s_setprio(1);
#pragma unroll
      for (int mi = 0; mi < 2; ++mi) {
#pragma unroll
        for (int ni = 0; ni < 4; ++ni)
          acc[mi][ni] = __builtin_amdgcn_mfma_f32_16x16x32_bf16(af[mi], b1[ni], acc[mi][ni], 0, 0, 0);
      }
      __builtin_amdgcn_s_setprio(0);
      if (t + 3 < NT) vmcnt_wait<5>(); else vmcnt_wait<0>();
      __builtin_amdgcn_s_barrier();
      rd = (rd == 2) ? 0 : rd + 1;
    }
  }

  const int baseRow = m0 + aRow, baseCol = n0 + bRow;
#pragma unroll
  for (int mi = 0; mi < 2; ++mi) {
#pragma unroll
    for (int ni = 0; ni < 4; ++ni) {
      const int col = baseCol + ni * 16 + lr;
#pragma unroll
      for (int r = 0; r < 4; ++r) {
        const int row = baseRow + mi * 16 + kgr * 4 + r;
        float v = acc[mi][ni][r] + bias[col];
        float rv = resid[(long)row * 512 + col];
        C[(long)row * 512 + col] = alpha * rv + beta * v;
      }
    }
  }
}

// ---------------------------------------------------------------------------
// Fragment-pack helpers (round 20, frozen).
// ---------------------------------------------------------------------------
template<int TRANS, int KSHIFT>
__global__ __launch_bounds__(256) void packB(const float* __restrict__ in, short* __restrict__ out)
{
  const int gid = blockIdx.x * 256 + threadIdx.x;
  const int n = gid >> KSHIFT;
  const int k = gid & ((1 << KSHIFT) - 1);
  const float v = TRANS ? in[(long)k * 512 + n] : in[((long)n << KSHIFT) | k];
  out[((long)((n >> 4) << (KSHIFT - 5)) + (k >> 5)) * 512 + ((k >> 3) & 3) * 128 + (n & 15) * 8 + (k & 7)] = f2bfs(v);
}

template<int TRANS, int NSHIFT>
__global__ __launch_bounds__(256) void packB2(const float* __restrict__ in, short* __restrict__ out)
{
  const int gid = blockIdx.x * 256 + threadIdx.x;
  const int n = gid >> 9;
  const int k = gid & 511;
  const float v = TRANS ? in[((long)k << NSHIFT) | n] : in[((long)n << 9) | k];
  out[((long)(n >> 4) * 16 + (k >> 5)) * 512 + ((k >> 3) & 3) * 128 + (n & 15) * 8 + (k & 7)] = f2bfs(v);
}

__global__ __launch_bounds__(256) void packQKV(
    const float* __restrict__ wq, const float* __restrict__ wk,
    const float* __restrict__ wv, short* __restrict__ out)
{
  const int gid = blockIdx.x * 256 + threadIdx.x;
  const int n = gid >> 9;
  const int k = gid & 511;
  const int sel = n >> 9;
  const int nn = n & 511;
  const float* w = (sel == 0) ? wq : (sel == 1) ? wk : wv;
  const float v = w[(long)(nn >> 6) * 32768 + (long)k * 64 + (nn & 63)];
  out[((long)(n >> 4) * 16 + (k >> 5)) * 512 + ((k >> 3) & 3) * 128 + (n & 15) * 8 + (k & 7)] = f2bfs(v);
}

// ---------------------------------------------------------------------------
// Conv, tap-tiled, B-prefetch DEPTH 3 (4-slot rotation, slot = s&3 static).
// Per i-chunk (32 ch) stage 144-row glu slab; 16 taps vs it. 2-way split-K,
// XCD-pinned flat grid 512 (2 blocks/CU -> extra VGPRs free). bf16 partials.
// ---------------------------------------------------------------------------
__global__ __launch_bounds__(256) void conv_tap(
    const short* __restrict__ glu,
    const short* __restrict__ wdP,
    short* __restrict__ parts)
{
  __shared__ short sA[2][144 * 32];
  const int tid = threadIdx.x;
  const int bid = blockIdx.x;
  const int cc = bid & 7, j = bid >> 3;
  const int y = cc >> 1, kg = cc & 1;
  const int x = j & 7, b = j >> 3;
  const int m0 = x * 128, n0 = y * 128;
  const short* Arow0 = glu + ((long)b * 1056 + m0 + 1 + kg * 16) * 512;
  short* cbase = parts + (long)kg * (8192L * 512) + (long)b * (1024L * 512);

  const int lane = tid & 63, wid = tid >> 6;
  const int wm = wid >> 1, wn = wid & 1;
  const int lr = lane & 15, kgr = lane >> 4;
  const int aRow = wm * 64, bRow = wn * 64;

  const short* Bp = wdP + (long)((n0 + bRow) >> 4) * (512L * 512)
                  + (long)(kg * 256) * 512 + lane * 8;
  const long NSTR = 512L * 512;

  auto stageA = [&](int buf, int ib) {
#pragma unroll
    for (int it = 0; it < 3; ++it) {
      int idx = it * 256 + tid;
      if (idx < 576) {
        GLOADLDS(Arow0 + (long)(idx >> 2) * 512 + ib * 32 + (idx & 3) * 8,
                 &sA[buf][idx * 8]);
      }
    }
  };

  f32x4 acc[4][4];
#pragma unroll
  for (int i = 0; i < 4; ++i) {
#pragma unroll
    for (int jj = 0; jj < 4; ++jj) acc[i][jj] = (f32x4){0.f, 0.f, 0.f, 0.f};
  }
  short8 bfr[4][4];   // [slot][frag], slot = s & 3 (static under kk unroll)

  // loadB for global sequence index s (s = ib*16 + kk; consumed at s).
  // B chunk for (kk2, ib2) lives at (kk2*16 + ib2)*512. Overshoot s<=258
  // stays in-bounds of wdP (chunk <= 304 < 512).
#define LOADB(slot_, s_)                                                     \
  {                                                                          \
    const int s2 = (s_);                                                     \
    const long noff = (long)(((s2 & 15) * 16 + (s2 >> 4))) * 512;            \
    _Pragma("unroll")                                                        \
    for (int ni = 0; ni < 4; ++ni)                                           \
      bfr[slot_][ni] = *(const short8*)(Bp + noff + ni * NSTR);              \
  }

  stageA(0, 0);
  MEMFENCE;
  LOADB(0, 0); LOADB(1, 1); LOADB(2, 2);
  MEMFENCE;
  vmcnt_wait<12>();             // stage(0) done; 3 B prefetches may be in flight
  __builtin_amdgcn_s_barrier();

  int cur = 0;
  for (int ib = 0; ib < 16; ++ib) {
    if (ib + 1 < 16) stageA(cur ^ 1, ib + 1);
    MEMFENCE;
#pragma unroll
    for (int kk = 0; kk < 16; ++kk) {
      const int s = ib * 16 + kk;
      LOADB((kk + 3) & 3, s + 3);   // prefetch distance 3
      MEMFENCE;
      short8 af[4];
#pragma unroll
      for (int mi = 0; mi < 4; ++mi)
        af[mi] = *(const short8*)&sA[cur][(kk + aRow + mi * 16 + lr) * 32 + kgr * 8];
      __builtin_amdgcn_s_setprio(1);
#pragma unroll
      for (int mi = 0; mi < 4; ++mi) {
#pragma unroll
        for (int ni = 0; ni < 4; ++ni)
          acc[mi][ni] = __builtin_amdgcn_mfma_f32_16x16x32_bf16(af[mi], bfr[kk & 3][ni], acc[mi][ni], 0, 0, 0);
      }
      __builtin_amdgcn_s_setprio(0);
    }
    vmcnt_wait<12>();           // 3 newest B prefetches in flight; A(ib+1) done
    __builtin_amdgcn_s_barrier();
    cur ^= 1;
  }
  vmcnt_wait<0>();
#undef LOADB

  const int baseRow = m0 + aRow, baseCol = n0 + bRow;
#pragma unroll
  for (int mi = 0; mi < 4; ++mi) {
#pragma unroll
    for (int ni = 0; ni < 4; ++ni) {
      const int col = baseCol + ni * 16 + lr;
#pragma unroll
      for (int r = 0; r < 4; ++r) {
        const int row = baseRow + mi * 16 + kgr * 4 + r;
        cbase[(long)row * 512 + col] = f2bfs(acc[mi][ni][r]);
      }
    }
  }
}

// ---------------------------------------------------------------------------
// Flash attention (round 17, frozen).
// ---------------------------------------------------------------------------
__global__ __launch_bounds__(256) void flash_attn(
    const short* __restrict__ qkv,
    const short* __restrict__ vt,
    short* __restrict__ out)
{
  __shared__ short sQ[64 * 64];
  __shared__ short sK[64 * 64];
  __shared__ short sV[64 * 64];
  __shared__ short sP[4][16 * 64];
  const int tid = threadIdx.x;
  const int lane = tid & 63, w = tid >> 6;
  const int lr = lane & 15, kg = lane >> 4;
  const int bh = (int)blockIdx.z;
  const int b = bh >> 3, h = bh & 7;
  const int q0 = blockIdx.x * 64;
  const short* qbase = qkv + (long)b * 1024 * 1536 + h * 64;
  const short* kbase = qbase + 512;
  const short* vtb = vt + (long)bh * 65536;

#pragma unroll
  for (int it = 0; it < 2; ++it) {
    int idx = it * 256 + tid;
    int row = idx >> 3, c = (idx & 7) ^ (row & 7);
    GLOADLDS(qbase + (long)(q0 + row) * 1536 + c * 8, &sQ[idx * 8]);
  }
  __syncthreads();
  short8 bq[2];
#pragma unroll
  for (int ks = 0; ks < 2; ++ks)
    bq[ks] = *(const short8*)&sQ[(w * 16 + lr) * 64 + ((ks * 4 + kg) ^ (lr & 7)) * 8];

  f32x4 po[4];
#pragma unroll
  for (int mi = 0; mi < 4; ++mi) po[mi] = (f32x4){0.f, 0.f, 0.f, 0.f};
  float m = -3.0e38f, l = 0.f;

  for (int s0 = 0; s0 < 1024; s0 += 64) {
#pragma unroll
    for (int it = 0; it < 2; ++it) {
      int idx = it * 256 + tid;
      int row = idx >> 3, c = (idx & 7) ^ (row & 7);
      GLOADLDS(kbase + (long)(s0 + row) * 1536 + c * 8, &sK[idx * 8]);
    }
#pragma unroll
    for (int it = 0; it < 2; ++it) {
      int idx = it * 256 + tid;
      int row = idx >> 3, c = (idx & 7) ^ (row & 7);
      GLOADLDS(vtb + (long)row * 1024 + s0 + c * 8, &sV[idx * 8]);
    }
    __syncthreads();

    f32x4 as[4];
#pragma unroll
    for (int mi = 0; mi < 4; ++mi) as[mi] = (f32x4){0.f, 0.f, 0.f, 0.f};
    __builtin_amdgcn_s_setprio(1);
#pragma unroll
    for (int ks = 0; ks < 2; ++ks) {
#pragma unroll
      for (int mi = 0; mi < 4; ++mi) {
        short8 ak = *(const short8*)&sK[(mi * 16 + lr) * 64 + ((ks * 4 + kg) ^ (lr & 7)) * 8];
        as[mi] = __builtin_amdgcn_mfma_f32_16x16x32_bf16(ak, bq[ks], as[mi], 0, 0, 0);
      }
    }
    __builtin_amdgcn_s_setprio(0);

    float rmax = as[0][0];
#pragma unroll
    for (int mi = 0; mi < 4; ++mi) {
#pragma unroll
      for (int r = 0; r < 4; ++r) rmax = fmaxf(rmax, as[mi][r]);
    }
    rmax = fmaxf(rmax, __shfl_xor(rmax, 16));
    rmax = fmaxf(rmax, __shfl_xor(rmax, 32));
    const float mn = fmaxf(m, rmax);
    const float sc = __expf(m - mn);
    float p[4][4];
    float rsum = 0.f;
#pragma unroll
    for (int mi = 0; mi < 4; ++mi) {
#pragma unroll
      for (int r = 0; r < 4; ++r) { p[mi][r] = __expf(as[mi][r] - mn); rsum += p[mi][r]; }
    }
    rsum += __shfl_xor(rsum, 16);
    rsum += __shfl_xor(rsum, 32);
    l = l * sc + rsum;
    m = mn;
#pragma unroll
    for (int mi = 0; mi < 4; ++mi) {
#pragma unroll
      for (int r = 0; r < 4; ++r) po[mi][r] *= sc;
    }
#pragma unroll
    for (int mi = 0; mi < 4; ++mi) {
      s16x4 pk;
#pragma unroll
      for (int r = 0; r < 4; ++r) pk[r] = f2bfs(p[mi][r]);
      *(s16x4*)&sP[w][lr * 64 + ((mi ^ (lr & 3)) * 16 + kg * 4)] = pk;
    }
    __builtin_amdgcn_s_setprio(1);
#pragma unroll
    for (int ks = 0; ks < 2; ++ks) {
      short8 bp = *(const short8*)&sP[w][lr * 64 + (((ks * 2 + (kg >> 1)) ^ (lr & 3)) * 16 + (kg & 1) * 8)];
#pragma unroll
      for (int mi = 0; mi < 4; ++mi) {
        short8 av = *(const short8*)&sV[(mi * 16 + lr) * 64 + ((ks * 4 + kg) ^ (lr & 7)) * 8];
        po[mi] = __builtin_amdgcn_mfma_f32_16x16x32_bf16(av, bp, po[mi], 0, 0, 0);
      }
    }
    __builtin_amdgcn_s_setprio(0);
    __syncthreads();
  }

  const float inv = 1.f / l;
  const int t2 = q0 + w * 16 + lr;
  const int n = h * 1024 + t2;
  short* ob = out + ((long)b * 1024 + (n >> 3)) * 512 + (n & 7) * 64;
#pragma unroll
  for (int mi = 0; mi < 4; ++mi) {
    s16x4 o;
#pragma unroll
    for (int r = 0; r < 4; ++r) o[r] = f2bfs(po[mi][r] * inv);
    *(s16x4*)&ob[mi * 16 + kg * 4] = o;
  }
}

// ---------------------------------------------------------------------------
__global__ __launch_bounds__(256) void reduce_bn(
    const short* __restrict__ parts, long pstride,
    short* __restrict__ z, float* stats)
{
  const int r0 = blockIdx.x * 16;
  const int c = threadIdx.x * 2;
  float s0 = 0.f, s1 = 0.f, q0 = 0.f, q1 = 0.f;
#pragma unroll 4
  for (int r = 0; r < 16; ++r) {
    const long idx = (long)(r0 + r) * 512 + c;
    int p0 = *(const int*)&parts[idx];
    int p1 = *(const int*)&parts[idx + pstride];
    float a0 = bfs2f((short)(p0 & 0xffff)) + bfs2f((short)(p1 & 0xffff));
    float a1 = bfs2f((short)(p0 >> 16)) + bfs2f((short)(p1 >> 16));
    int zo = ((int)(unsigned short)f2bfs(a0)) | (((int)(unsigned short)f2bfs(a1)) << 16);
    *(int*)&z[idx] = zo;
    s0 += a0; s1 += a1; q0 += a0 * a0; q1 += a1 * a1;
  }
  atomicAdd(&stats[c], s0);
  atomicAdd(&stats[c + 1], s1);
  atomicAdd(&stats[512 + c], q0);
  atomicAdd(&stats[512 + c + 1], q1);
}

// ---------------------------------------------------------------------------
template<int ADDPE, int OUTF32>
__global__ __launch_bounds__(256) void ln_rows(
    const float* __restrict__ X, const float* __restrict__ g, const float* __restrict__ b,
    const float* __restrict__ pe, void* __restrict__ Y)
{
  const int row = blockIdx.x * 4 + (threadIdx.x >> 6);
  const int lane = threadIdx.x & 63;
  const int c0 = lane * 8;
  const float* src = X + (long)row * 512 + c0;
  f32x4 a = *(const f32x4*)src, c = *(const f32x4*)(src + 4);
  float x[8] = {a[0], a[1], a[2], a[3], c[0], c[1], c[2], c[3]};
  float s = 0.f, q = 0.f;
#pragma unroll
  for (int j = 0; j < 8; ++j) { s += x[j]; q += x[j] * x[j]; }
#pragma unroll
  for (int off = 32; off > 0; off >>= 1) { s += __shfl_xor(s, off); q += __shfl_xor(q, off); }
  const float mean = s * (1.f / 512.f);
  const float var = q * (1.f / 512.f) - mean * mean;
  const float rstd = rsqrtf(var + 1e-5f);
  f32x4 g0 = *(const f32x4*)(g + c0), g1 = *(const f32x4*)(g + c0 + 4);
  f32x4 b0 = *(const f32x4*)(b + c0), b1 = *(const f32x4*)(b + c0 + 4);
  float gg[8] = {g0[0], g0[1], g0[2], g0[3], g1[0], g1[1], g1[2], g1[3]};
  float bb[8] = {b0[0], b0[1], b0[2], b0[3], b1[0], b1[1], b1[2], b1[3]};
  float y[8];
#pragma unroll
  for (int j = 0; j < 8; ++j) {
    y[j] = (x[j] - mean) * rstd * gg[j] + bb[j];
    if (ADDPE) y[j] += pe[(long)(row & 1023) * 512 + c0 + j];
  }
  if (OUTF32) {
    float* dst = (float*)Y + (long)row * 512 + c0;
    *(f32x4*)dst = (f32x4){y[0], y[1], y[2], y[3]};
    *(f32x4*)(dst + 4) = (f32x4){y[4], y[5], y[6], y[7]};
  } else {
    short8 o;
#pragma unroll
    for (int j = 0; j < 8; ++j) o[j] = f2bfs(y[j]);
    *(short8*)((short*)Y + (long)row * 512 + c0) = o;
  }
}

// ---------------------------------------------------------------------------
__global__ __launch_bounds__(256) void transpose64b(
    const short* __restrict__ in, int ldin, short* __restrict__ out, int ldout,
    int zshift, long zh_in, long zl_in, long z_out)
{
  __shared__ short t[64][72];
  const int z = blockIdx.z;
  const long inoff = (long)(z >> zshift) * zh_in + (long)(z & ((1 << zshift) - 1)) * zl_in;
  const int tr = blockIdx.x;
  const short* src = in + inoff + (long)(tr * 64) * ldin;
  short* dst = out + (long)z * z_out + tr * 64;
  const int tid = threadIdx.x;
#pragma unroll
  for (int p = 0; p < 2; ++p) {
    int idx = p * 256 + tid;
    int r = idx >> 3, c8 = (idx & 7) * 8;
    short8 v = *(const short8*)(src + (long)r * ldin + c8);
#pragma unroll
    for (int j = 0; j < 8; ++j) t[r][c8 + j] = v[j];
  }
  __syncthreads();
#pragma unroll
  for (int p = 0; p < 2; ++p) {
    int idx = p * 256 + tid;
    int c = idx >> 3, r8 = (idx & 7) * 8;
    short8 v;
#pragma unroll
    for (int j = 0; j < 8; ++j) v[j] = t[r8 + j][c];
    *(short8*)(dst + (long)c * ldout + r8) = v;
  }
}

__global__ __launch_bounds__(256) void wd_pack(const float* __restrict__ wd, short* __restrict__ wdP)
{
  const int gid = blockIdx.x * 256 + threadIdx.x;
  const int e = gid >> 9, i = gid & 511;
  const float* src = wd + ((long)e * 512 + i) * 31;
  const long rowtile = (long)(e >> 4) * (512L * 512);
  const int inner = ((i >> 3) & 3) * 128 + (e & 15) * 8 + (i & 7);
#pragma unroll
  for (int KK = 0; KK < 31; ++KK)
    wdP[rowtile + (long)(KK * 16 + (i >> 5)) * 512 + inner] = f2bfs(src[KK]);
  wdP[rowtile + (long)(31 * 16 + (i >> 5)) * 512 + inner] = 0;
}

__global__ __launch_bounds__(256) void pe_init(float* __restrict__ pe)
{
  const int gid = blockIdx.x * 256 + threadIdx.x;
  const int t = gid >> 8, p = gid & 255;
  const float freq = __expf(-(float)p * (9.210340371976184f / 256.f));
  const float ang = (float)t * freq;
  pe[(long)t * 512 + 2 * p]     = sinf(ang);
  pe[(long)t * 512 + 2 * p + 1] = cosf(ang);
}

__global__ __launch_bounds__(256) void halo_zero(short* __restrict__ gp)
{
  const int gid = blockIdx.x * 256 + threadIdx.x;
  if (gid >= 16512) return;
  long row;
  int c8;
  if (gid < 16384) {
    const int b = gid >> 11;
    const int r = (gid >> 6) & 31;
    c8 = (gid & 63) * 8;
    row = (long)b * 1056 + ((r < 16) ? r : (1024 + r));
  } else {
    const int k = gid - 16384;
    c8 = (k & 63) * 8;
    row = 8448 + (k >> 6);
  }
  *(short8*)(gp + row * 512 + c8) = (short8){0, 0, 0, 0, 0, 0, 0, 0};
}

__global__ __launch_bounds__(256) void glu_kernel(const short* __restrict__ y1, short* __restrict__ gp)
{
  const int gid = blockIdx.x * 256 + threadIdx.x;
  const int row = gid >> 7;
  const int ci = (gid & 127) * 4;
  const short* base = y1 + (long)row * 1024;
  s16x4 a = *(const s16x4*)(base + ci);
  s16x4 g = *(const s16x4*)(base + 512 + ci);
  const int b = row >> 10, t = row & 1023;
  s16x4 o;
#pragma unroll
  for (int j = 0; j < 4; ++j) o[j] = f2bfs(bfs2f(a[j]) * sigmoidf_(bfs2f(g[j])));
  *(s16x4*)(gp + ((long)b * 1056 + 16 + t) * 512 + ci) = o;
}

__global__ void bn_stats(float* stats, const float* __restrict__ bn_g, const float* __restrict__ bn_b)
{
  const int c = blockIdx.x * 256 + threadIdx.x;
  if (c < 512) {
    float mean = stats[c] * (1.f / 8192.f);
    float var = stats[512 + c] * (1.f / 8192.f) - mean * mean;
    float sc = bn_g[c] * rsqrtf(var + 1e-5f);
    stats[1024 + c] = sc;
    stats[1536 + c] = bn_b[c] - mean * sc;
  }
}

__global__ __launch_bounds__(256) void bn_silu(const short* __restrict__ z, const float* __restrict__ stats,
                                               short* __restrict__ out)
{
  const long base = ((long)blockIdx.x * 256 + threadIdx.x) * 8;
  const int c0 = (int)(base & 511);
  short8 v = *(const short8*)(z + base);
  short8 o;
#pragma unroll
  for (int j = 0; j < 8; ++j) {
    const int c = c0 + j;
    float y = bfs2f(v[j]) * stats[1024 + c] + stats[1536 + c];
    o[j] = f2bfs(y * sigmoidf_(y));
  }
  *(short8*)(out + base) = o;
}

// ---------------------------------------------------------------------------
extern "C" void kernel_launch(void* const* d_in, const int* in_sizes, int n_in,
                              void* d_out, int out_size, void* d_ws, size_t ws_size,
                              hipStream_t stream)
{
  (void)in_sizes; (void)n_in; (void)out_size; (void)ws_size;
  const float* x_in   = (const float*)d_in[0];
  const float* ff1_g  = (const float*)d_in[1];
  const float* ff1_bb = (const float*)d_in[2];
  const float* ff1_w1 = (const float*)d_in[3];
  const float* ff1_b1 = (const float*)d_in[4];
  const float* ff1_w2 = (const float*)d_in[5];
  const float* ff1_b2 = (const float*)d_in[6];
  const float* mha_g  = (const float*)d_in[7];
  const float* mha_b  = (const float*)d_in[8];
  const float* wq     = (const float*)d_in[9];
  const float* bq     = (const float*)d_in[10];
  const float* wk     = (const float*)d_in[11];
  const float* bk     = (const float*)d_in[12];
  const float* wv     = (const float*)d_in[13];
  const float* bv     = (const float*)d_in[14];
  const float* wo     = (const float*)d_in[15];
  const float* bo     = (const float*)d_in[16];
  const float* cv_g   = (const float*)d_in[17];
  const float* cv_b   = (const float*)d_in[18];
  const float* cv_w1  = (const float*)d_in[19];
  const float* cv_b1  = (const float*)d_in[20];
  const float* cv_wd  = (const float*)d_in[21];
  const float* bn_g   = (const float*)d_in[22];
  const float* bn_b   = (const float*)d_in[23];
  const float* cv_w2  = (const float*)d_in[24];
  const float* cv_b2  = (const float*)d_in[25];
  const float* ff2_g  = (const float*)d_in[26];
  const float* ff2_b  = (const float*)d_in[27];
  const float* ff2_w1 = (const float*)d_in[28];
  const float* ff2_b1 = (const float*)d_in[29];
  const float* ff2_w2 = (const float*)d_in[30];
  const float* ff2_b2 = (const float*)d_in[31];
  const float* fin_g  = (const float*)d_in[32];
  const float* fin_b  = (const float*)d_in[33];

  size_t off = 0;
  char* wsb = (char*)d_ws;
  auto take = [&](size_t n) { char* p = wsb + off; off += (n + 255) & ~(size_t)255; return p; };
  short* ff1w1P = (short*)take(2048L * 512 * 2);
  short* ff1w2P = (short*)take(2048L * 512 * 2);
  short* qkvP   = (short*)take(1536L * 512 * 2);
  short* woP    = (short*)take(512L * 512 * 2);
  short* cw1P   = (short*)take(1024L * 512 * 2);
  short* cw2P   = (short*)take(512L * 512 * 2);
  short* wdP    = (short*)take(32L * 512 * 512 * 2);
  short* ff2w1P = (short*)take(2048L * 512 * 2);
  short* ff2w2P = (short*)take(2048L * 512 * 2);
  float* xcur   = (float*)take(8192L * 512 * 4);
  char*  Ra     = take(8192L * 2048 * 2);
  short* Rb     = (short*)take(8192L * 512 * 2);
  short* Rg     = (short*)take((8L * 1056 + 2) * 512 * 2);
  short* parts  = (short*)take(2L * 8192 * 512 * 2);
  short* vt     = (short*)take(64L * 64 * 1024 * 2);
  float* pe     = (float*)take(1024L * 512 * 4);
  float* stats  = (float*)take(2048L * 4);

  short* hid = (short*)Ra;
  short* qkv = (short*)Ra;
  short* y1  = (short*)Ra;

  // ---- weight packs (fp32 -> bf16 frag layout; per call) ----
  packB2<1, 11><<<4096, 256, 0, stream>>>(ff1_w1, ff1w1P);
  packB<1, 11><<<4096, 256, 0, stream>>>(ff1_w2, ff1w2P);
  packQKV<<<3072, 256, 0, stream>>>(wq, wk, wv, qkvP);
  packB<1, 9><<<1024, 256, 0, stream>>>(wo, woP);
  packB2<0, 0><<<2048, 256, 0, stream>>>(cv_w1, cw1P);
  packB<0, 9><<<1024, 256, 0, stream>>>(cv_w2, cw2P);
  wd_pack<<<1024, 256, 0, stream>>>(cv_wd, wdP);
  pe_init<<<1024, 256, 0, stream>>>(pe);

  // ---- FF1: x1 = 1.5 x + 0.5 (silu(ln(x) W1 + b1) W2 + b2) ----
  ln_rows<0, 0><<<2048, 256, 0, stream>>>(x_in, ff1_g, ff1_bb, nullptr, Rb);
  gemm_bdw<16, EPI_SILU><<<dim3(64, 16), 256, 0, stream>>>(
      Rb, ff1w1P, ff1_b1, nullptr, nullptr, hid);
  gemm_bd<64><<<512, 256, 0, stream>>>(hid, ff1w2P, ff1_b2, x_in, xcur, 1.5f, 0.5f);

  // ---- MHSA: x2 = 2 x1 + (scramble(attn) Wo + bo) ----
  ln_rows<1, 0><<<2048, 256, 0, stream>>>(xcur, mha_g, mha_b, pe, Rb);
  gemm_bdw<12, EPI_QKV><<<dim3(64, 12), 256, 0, stream>>>(
      Rb, qkvP, bq, bk, bv, qkv);
  transpose64b<<<dim3(16, 1, 64), 256, 0, stream>>>(qkv + 1024, 1536, vt, 1024, 3,
                                                    1024L * 1536, 64, 65536);
  flash_attn<<<dim3(16, 1, 64), 256, 0, stream>>>(qkv, vt, Rb);
  gemm_bd<16><<<512, 256, 0, stream>>>(Rb, woP, bo, xcur, xcur, 2.f, 1.f);

  // ---- Conv module ----
  ln_rows<0, 0><<<2048, 256, 0, stream>>>(xcur, cv_g, cv_b, nullptr, Rb);
  gemm_bdw<8, EPI_BBIAS><<<dim3(64, 8), 256, 0, stream>>>(
      Rb, cw1P, cv_b1, nullptr, nullptr, y1);
  halo_zero<<<65, 256, 0, stream>>>(Rg);
  glu_kernel<<<4096, 256, 0, stream>>>(y1, Rg);
  (void)hipMemsetAsync(stats, 0, 1024 * sizeof(float), stream);
  conv_tap<<<512, 256, 0, stream>>>(Rg, wdP, parts);
  reduce_bn<<<512, 256, 0, stream>>>(parts, 8192L * 512, Rb, stats);
  bn_stats<<<2, 256, 0, stream>>>(stats, bn_g, bn_b);
  bn_silu<<<2048, 256, 0, stream>>>(Rb, stats, (short*)Rg);
  gemm_bd<16><<<512, 256, 0, stream>>>((short*)Rg, cw2P, cv_b2, xcur, xcur, 2.f, 1.f);

  // ---- FF2 ----
  ln_rows<0, 0><<<2048, 256, 0, stream>>>(xcur, ff2_g, ff2_b, nullptr, Rb);
  gemm_bdw<16, EPI_SILU><<<dim3(64, 16), 256, 0, stream>>>(
      Rb, ff2w1P, ff2_b1, nullptr, nullptr, hid);
  gemm_bd<64><<<512, 256, 0, stream>>>(hid, ff2w2P, ff2_b2, xcur, xcur, 1.5f, 0.5f);

  // ---- final LN -> d_out (fp32) ----
  ln_rows<0, 1><<<2048, 256, 0, stream>>>(xcur, fin_g, fin_b, nullptr, (float*)d_out);
}